// Round 7
// baseline (358.920 us; speedup 1.0000x reference)
//
#include <hip/hip_runtime.h>
#include <math.h>

#define PI_D 3.14159265358979323846

#define BATCH 128
#define F1 20
#define F2 40
#define FOUT 10
#define NS1 100   // sum_{l<10} (2l+1)
#define NS2 286   // sum_{l<6} (2l+1)^2
#define NH2 146   // Hermitian half count of NS2

__constant__ int ZB10c[11] = {0,1,10,35,84,165,286,455,680,969,1330};
__constant__ int B2OFFc[7] = {0,1,10,35,84,165,286};
__constant__ int HOFFc[7]  = {0,1,6,19,44,85,146};
// E8c[q] = exp(-2*pi*i*q/8)
__constant__ float2 E8c[8] = {
  { 1.f, 0.f}, { 0.70710678118654752f,-0.70710678118654752f},
  { 0.f,-1.f}, {-0.70710678118654752f,-0.70710678118654752f},
  {-1.f, 0.f}, {-0.70710678118654752f, 0.70710678118654752f},
  { 0.f, 1.f}, { 0.70710678118654752f, 0.70710678118654752f}};

// wave-synchronous phase fence
#define WFENCE do{ __builtin_amdgcn_sched_barrier(0); \
  asm volatile("s_waitcnt lgkmcnt(0)" ::: "memory"); \
  __builtin_amdgcn_sched_barrier(0); }while(0)

// half-space H = { (m,n): n>0 } U { (m,n): n==0 && m>=0 }
__device__ inline void h_decode(int h, int& l, int& m, int& n){
  l=0; while(HOFFc[l+1]<=h) ++l;
  int r=h-HOFFc[l], L=2*l+1;
  if(r<l+1){ n=0; m=r; }
  else { int q=r-(l+1); n=q/L+1; m=q%L-l; }
}

// ---------------- double-precision table generation helpers ----------------
__device__ inline double ipow_d(double x, int n){ double r=1.0; for(int i=0;i<n;++i) r*=x; return r; }
__device__ inline double dfact(int n){ double r=1.0; for(int i=2;i<=n;++i) r*=(double)i; return r; }

__device__ double wigd(int l, int mp, int m, double beta){
  double cb=cos(0.5*beta), sb=sin(0.5*beta);
  double pref=sqrt(dfact(l+mp)*dfact(l-mp)*dfact(l+m)*dfact(l-m));
  int s0 = (m-mp>0) ? (m-mp) : 0;
  int s1 = (l+m < l-mp) ? (l+m) : (l-mp);
  double acc=0.0;
  for(int s=s0;s<=s1;++s){
    double den=dfact(l+m-s)*dfact(s)*dfact(mp-m+s)*dfact(l-mp-s);
    double t=ipow_d(cb,2*l+m-mp-2*s)*ipow_d(sb,mp-m+2*s)/den;
    acc += ((mp-m+s)&1)? -t : t;
  }
  return pref*acc;
}

__device__ double dhw(int b, int j){
  double beta=PI_D*(2*j+1)/(4.0*b);
  double s=0.0;
  for(int k=0;k<b;++k) s += sin((2*k+1)*beta)/(2*k+1);
  return (2.0/b)*sin(beta)*s;
}

__device__ inline float2 cmulc(float2 a, float2 b){ // a * conj(b)
  return make_float2(a.x*b.x + a.y*b.y, a.y*b.x - a.x*b.y);
}

// ---------------- single merged table-generation kernel ----------------
__global__ void gen_all(float* A1, float* D1SJ, float* W3H, float* D2SJ,
                        float* D3_2, float* D3_1, float* WINT,
                        float2* E60, float2* E20, float2* E12,
                        unsigned* zLUT, unsigned* xh2LUT, unsigned* h2LUT,
                        unsigned short* fhLUT){
  int blk=blockIdx.x, t=threadIdx.x;
  if(blk<24){                     // A1: [j][s1], 60x100
    int idx=blk*256+t; if(idx>=6000) return;
    int j=idx/NS1, s=idx%NS1;
    int l=0; while((l+1)*(l+1)<=s) ++l;
    int m=s-l*l-l;
    double beta=PI_D*(2*j+1)/120.0;
    A1[idx]=(float)(wigd(l,m,0,beta)*dhw(30,j)*(2.0*PI_D/60.0));
  } else if(blk<128){             // D1SJ: [j][1330]
    int idx=(blk-24)*256+t; if(idx>=26600) return;
    int j=idx/1330, s=idx%1330;
    int l=0; while(ZB10c[l+1]<=s) ++l;
    int r=s-ZB10c[l]; int L=2*l+1;
    int mi=r/L, ni=r%L;
    double beta=PI_D*(2*j+1)/40.0;
    D1SJ[idx]=(float)((2*l+1)*wigd(l,mi-l,ni-l,beta));
  } else if(blk<140){             // W3H: [j][146]
    int idx=(blk-128)*256+t; if(idx>=20*NH2) return;
    int j=idx/NH2, h=idx%NH2;
    int l,m,n; h_decode(h,l,m,n);
    double beta=PI_D*(2*j+1)/40.0;
    double c=2.0*PI_D/20.0;
    W3H[idx]=(float)(wigd(l,m,n,beta)*dhw(10,j)*c*c);
  } else if(blk<154){             // D2SJ: [j][286]
    int idx=(blk-140)*256+t; if(idx>=3432) return;
    int j=idx/286, s=idx%286;
    int l=0; while(B2OFFc[l+1]<=s) ++l;
    int r=s-B2OFFc[l]; int L=2*l+1;
    int mi=r/L, ni=r%L;
    double beta=PI_D*(2*j+1)/24.0;
    D2SJ[idx]=(float)((2*l+1)*wigd(l,mi-l,ni-l,beta));
  } else if(blk<158){             // D3_2: [bi][286]
    int idx=(blk-154)*256+t; if(idx>=3*286) return;
    int bi=idx/286, s=idx%286;
    int l=0; while(B2OFFc[l+1]<=s) ++l;
    int r=s-B2OFFc[l]; int L=2*l+1;
    int mi=r/L, ni=r%L;
    double beta=(bi+1)*(PI_D/8.0)/3.0;
    D3_2[idx]=(float)wigd(l,mi-l,ni-l,beta);
  } else if(blk<160){             // D3_1: [bi][100]
    int idx=(blk-158)*256+t; if(idx>=3*100) return;
    int bi=idx/100, s=idx%100;
    int l=0; while((l+1)*(l+1)<=s) ++l;
    int m=s-l*l-l;
    double beta=(bi+1)*(PI_D/8.0)/3.0;
    D3_1[idx]=(float)wigd(l,m,0,beta);
  } else if(blk==160){            // misc
    if(t<12){ double c=2.0*PI_D/12.0; WINT[t]=(float)(dhw(6,t)*c*c); }
    if(t<60){ double a=2.0*PI_D*t/60.0; E60[t]=make_float2((float)cos(a),(float)sin(a)); }
    if(t<20){ double a=2.0*PI_D*t/20.0; E20[t]=make_float2((float)cos(a),(float)sin(a)); }
    if(t<12){ double a=2.0*PI_D*t/12.0; E12[t]=make_float2((float)cos(a),(float)sin(a)); }
  } else if(blk<167){             // zLUT[1330]: packed s1x | s1k<<16
    int idx=(blk-161)*256+t; if(idx>=1330) return;
    int l=0; while(ZB10c[l+1]<=idx) ++l;
    int r=idx-ZB10c[l], L=2*l+1;
    int mi=r/L, ni=r%L;
    unsigned s1x=(unsigned)(l*l+mi), s1k=(unsigned)(l*l+ni);
    zLUT[idx]=s1x|(s1k<<16);
  } else {                        // blk==167: xh2LUT, h2LUT, fhLUT
    if(t<146){
      int l,m,n; h_decode(t,l,m,n);
      int L=2*l+1;
      int s2 =B2OFFc[l]+(m+l)*L+(n+l);
      int s2p=B2OFFc[l]+(l-m)*L+(l-n);
      unsigned sg=(unsigned)((m+n)&1);
      xh2LUT[t]=(unsigned)s2 | ((unsigned)s2p<<10) | (sg<<20);
      h2LUT[t]=(unsigned)l | ((unsigned)(m+l)<<4) | ((unsigned)(n+l)<<8) | ((unsigned)s2<<12);
      fhLUT[t]=(unsigned short)((n==0)? m : 6+(n-1)*11+(m+5));
    }
  }
}

// ---------------- front: per-b DFT+S2 analysis | k1h | KA (k2 gamma-DFT) ----------------
__global__ __launch_bounds__(256) void front_k(const float* __restrict__ x,
    const float* __restrict__ k1, const float* __restrict__ k2,
    const float2* __restrict__ E60, const float* __restrict__ A1,
    const float* __restrict__ D3_1,
    float2* __restrict__ XHAT, float2* __restrict__ K1H, float2* __restrict__ KA){
  __shared__ float2 E8s[8];
  int blk=blockIdx.x, t=threadIdx.x;
  if(blk<128){
    __shared__ float xs[3600];
    __shared__ float2 E60s[60];
    __shared__ float2 XFs[1140];     // [j][mi], mi = m+9
    if(t<60) E60s[t]=E60[t];
    {
      const float4* src=(const float4*)(x+blk*3600);
      float4* dst=(float4*)xs;
      for(int i=t;i<900;i+=256) dst[i]=src[i];
    }
    __syncthreads();
    for(int idx=t; idx<1140; idx+=256){
      int j=idx/19, mi=idx%19;
      int step=(mi<9)? mi+51 : mi-9;
      const float* xr=xs+j*60;
      float2 acc=make_float2(0.f,0.f);
      int k=0;
      for(int a=0;a<60;++a){
        float2 e=E60s[k]; float xv=xr[a];
        acc.x+=xv*e.x; acc.y-=xv*e.y;
        k+=step; if(k>=60)k-=60;
      }
      XFs[idx]=acc;
    }
    __syncthreads();
    for(int s=t; s<100; s+=256){
      int l=0; while((l+1)*(l+1)<=s) ++l;
      int m=s-l*l-l;
      const float2* xf=&XFs[m+9];
      float2 acc=make_float2(0.f,0.f);
      for(int j=0;j<60;++j){
        float a1=A1[j*NS1+s];
        float2 v=xf[j*19];
        acc.x+=a1*v.x; acc.y+=a1*v.y;
      }
      XHAT[blk*NS1+s]=acc;
    }
  } else if(blk<136){
    if(t<8) E8s[t]=E8c[t];
    __syncthreads();
    int idx=(blk-128)*256+t;
    if(idx<F1*NS1){
      int o=idx/NS1, s=idx%NS1;
      int l=0; while((l+1)*(l+1)<=s) ++l;
      int m=s-l*l-l;
      int mm=m&7;
      float2 acc=make_float2(0.f,0.f);
      for(int bi=0;bi<3;++bi){
        float2 sum=make_float2(0.f,0.f);
        int q=0;
        #pragma unroll
        for(int ai=0;ai<8;++ai){
          float kv=k1[o*24+bi*8+ai];
          float2 e=E8s[q];
          sum.x+=kv*e.x; sum.y+=kv*e.y;
          q=(q+mm)&7;
        }
        float dv=D3_1[bi*100+s];
        acc.x+=dv*sum.x; acc.y+=dv*sum.y;
      }
      const float SC1f = 0.06123724356957945f;
      K1H[idx]=make_float2(acc.x*SC1f, acc.y*SC1f);
    }
  } else {
    // KA[io*192 + bi*64 + q*8 + ai] = sum_gi k2[io*192+bi*64+ai*8+gi]*e8[(gi*q)&7]
    if(t<8) E8s[t]=E8c[t];
    __syncthreads();
    int idx=(blk-136)*256+t;
    if(idx<153600){
      int ai=idx&7, q=(idx>>3)&7;
      int r2=idx>>6;
      int bi=r2%3, io=r2/3;
      const float* kp=k2+(size_t)io*192+bi*64+ai*8;
      float2 acc=make_float2(0.f,0.f);
      int ph=0;
      #pragma unroll
      for(int gi=0;gi<8;++gi){
        float kv=kp[gi];
        float2 e=E8s[ph];
        acc.x+=kv*e.x; acc.y+=kv*e.y;
        ph=(ph+q)&7;
      }
      KA[(size_t)io*192+bi*64+q*8+ai]=acc;
    }
  }
}

// fused1: wave-per-j-pair barrier-free pipeline (3 passes). XH2 layout: [b][s2][i]
__global__ __launch_bounds__(256,4) void fused1(
    const float2* __restrict__ XHAT, const float2* __restrict__ K1H,
    const float* __restrict__ D1SJ, const float* __restrict__ W3H,
    const float2* __restrict__ E20, const float* __restrict__ bias1,
    const unsigned* __restrict__ zLUT, const unsigned* __restrict__ xh2LUT,
    const unsigned short* __restrict__ fhLUT,
    float2* __restrict__ XH2){
  const int b=blockIdx.x, o=blockIdx.y, t=threadIdx.x;
  const int ln=t&63, w=t>>6;
  __shared__ float2 zS[1330];
  __shared__ float2 TWE2[400];       // [r][k] = e^{i r k th}, 20x20
  __shared__ float2 regA[4][2][200]; // per wave, per j: G[10][19] -> v(f[400]) -> Fq[61]
  __shared__ float2 regB[4][2][190]; // per wave, per j: S[9][20]+T0(f[20]) -> U_T[6][20]

  for(int idx=t; idx<400; idx+=256){
    int r=idx/20, c=idx%20;
    TWE2[idx]=E20[(r*c)%20];
  }
  for(int idx=t; idx<1330; idx+=256){
    unsigned u=zLUT[idx];
    float2 xa=XHAT[b*NS1 + (u&0xffff)];
    float2 kb=K1H[o*NS1 + (u>>16)];
    zS[idx]=cmulc(xa,kb);
  }
  __syncthreads();

  const float bb1=bias1[o];
  float2 fa0=make_float2(0.f,0.f), fa1=fa0, fa2=fa0;

  // B-phase twiddle rows: n=c-9 -> row (c+11)%20
  const int BROW[19]={11,12,13,14,15,16,17,18,19,0,1,2,3,4,5,6,7,8,9};

  for(int q=0;q<3;++q){
    const int j0=w*5+2*q;
    const int j1=(q<2)? j0+1 : j0;
    const bool dup=(q==2);
    const float* Dg0=D1SJ + j0*1330;
    const float* Dg1=D1SJ + j1*1330;
    float2* G0=regA[w][0]; float2* G1=regA[w][1];
    float*  vb0=(float*)regA[w][0]; float* vb1=(float*)regA[w][1];
    float2* Fq0=regA[w][0]; float2* Fq1=regA[w][1];
    float2* S0=regB[w][0]; float2* S1=regB[w][1];
    float*  T00=(float*)(regB[w][0]+180); float* T01=(float*)(regB[w][1]+180);
    float2* U0=regB[w][0]; float2* U1=regB[w][1];

    // A: Wigner-beta contraction, half-space (181 items, 3 passes)
    for(int idx=ln; idx<181; idx+=64){
      int m,n;
      if(idx<10){ m=0; n=idx; } else { int qq=idx-10; m=qq/19+1; n=qq%19-9; }
      int an=n<0?-n:n;
      int l=m>an?m:an;
      int L=2*l+1;
      int zi=ZB10c[l]+(m+l)*L+(n+l);
      int m2=2*m+2;
      float2 a0=make_float2(0.f,0.f), a1=a0;
      for(; l<10; ++l){
        float2 zv=zS[zi];
        float d0=Dg0[zi], d1=Dg1[zi];
        a0.x+=zv.x*d0; a0.y+=zv.y*d0;
        a1.x+=zv.x*d1; a1.y+=zv.y*d1;
        zi += L*L + 2*L + m2; L += 2;
      }
      int gi=m*19+(n+9);
      G0[gi]=a0; G1[gi]=a1;
    }
    WFENCE;
    // B: S_m(g4) + T0 quads (50 items), both j's
    if(ln<45){
      int mb=ln/5+1, g0=(ln%5)*4;
      const float2* Gr0=&G0[mb*19];
      const float2* Gr1=&G1[mb*19];
      float2 s00=make_float2(0.f,0.f),s01=s00,s02=s00,s03=s00;
      float2 s10=s00,s11=s00,s12=s00,s13=s00;
      #pragma unroll
      for(int c=0;c<19;++c){
        float2 g0v=Gr0[c], g1v=Gr1[c];
        const float2* tw=&TWE2[BROW[c]*20+g0];
        float2 e0=tw[0],e1=tw[1],e2=tw[2],e3=tw[3];
        s00.x+=g0v.x*e0.x-g0v.y*e0.y; s00.y+=g0v.x*e0.y+g0v.y*e0.x;
        s01.x+=g0v.x*e1.x-g0v.y*e1.y; s01.y+=g0v.x*e1.y+g0v.y*e1.x;
        s02.x+=g0v.x*e2.x-g0v.y*e2.y; s02.y+=g0v.x*e2.y+g0v.y*e2.x;
        s03.x+=g0v.x*e3.x-g0v.y*e3.y; s03.y+=g0v.x*e3.y+g0v.y*e3.x;
        s10.x+=g1v.x*e0.x-g1v.y*e0.y; s10.y+=g1v.x*e0.y+g1v.y*e0.x;
        s11.x+=g1v.x*e1.x-g1v.y*e1.y; s11.y+=g1v.x*e1.y+g1v.y*e1.x;
        s12.x+=g1v.x*e2.x-g1v.y*e2.y; s12.y+=g1v.x*e2.y+g1v.y*e2.x;
        s13.x+=g1v.x*e3.x-g1v.y*e3.y; s13.y+=g1v.x*e3.y+g1v.y*e3.x;
      }
      float2* Sp0=&S0[(mb-1)*20+g0];
      float2* Sp1=&S1[(mb-1)*20+g0];
      Sp0[0]=make_float2(2.f*s00.x,2.f*s00.y); Sp0[1]=make_float2(2.f*s01.x,2.f*s01.y);
      Sp0[2]=make_float2(2.f*s02.x,2.f*s02.y); Sp0[3]=make_float2(2.f*s03.x,2.f*s03.y);
      Sp1[0]=make_float2(2.f*s10.x,2.f*s10.y); Sp1[1]=make_float2(2.f*s11.x,2.f*s11.y);
      Sp1[2]=make_float2(2.f*s12.x,2.f*s12.y); Sp1[3]=make_float2(2.f*s13.x,2.f*s13.y);
    } else if(ln<50){
      int g0=(ln-45)*4;
      float r00=G0[9].x, r01=r00, r02=r00, r03=r00;
      float r10=G1[9].x, r11=r10, r12=r10, r13=r10;
      #pragma unroll
      for(int n=1;n<10;++n){
        float2 g0v=G0[9+n], g1v=G1[9+n];
        const float2* tw=&TWE2[n*20+g0];
        float2 e0=tw[0],e1=tw[1],e2=tw[2],e3=tw[3];
        r00+=2.f*(g0v.x*e0.x-g0v.y*e0.y); r01+=2.f*(g0v.x*e1.x-g0v.y*e1.y);
        r02+=2.f*(g0v.x*e2.x-g0v.y*e2.y); r03+=2.f*(g0v.x*e3.x-g0v.y*e3.y);
        r10+=2.f*(g1v.x*e0.x-g1v.y*e0.y); r11+=2.f*(g1v.x*e1.x-g1v.y*e1.y);
        r12+=2.f*(g1v.x*e2.x-g1v.y*e2.y); r13+=2.f*(g1v.x*e3.x-g1v.y*e3.y);
      }
      T00[g0]=r00; T00[g0+1]=r01; T00[g0+2]=r02; T00[g0+3]=r03;
      T01[g0]=r10; T01[g0+1]=r11; T01[g0+2]=r12; T01[g0+3]=r13;
    }
    WFENCE;
    // C: v(a,g), bias, relu; 2-a x 4-g, both j's (50 items)
    if(ln<50){
      int ap=ln/5, g0=(ln%5)*4;
      int a0=2*ap, a1=a0+1;
      float t00=T00[g0]+bb1, t01=T00[g0+1]+bb1, t02=T00[g0+2]+bb1, t03=T00[g0+3]+bb1;
      float t10=T01[g0]+bb1, t11=T01[g0+1]+bb1, t12=T01[g0+2]+bb1, t13=T01[g0+3]+bb1;
      float va00=t00,va01=t01,va02=t02,va03=t03, vb00=t00,vb01=t01,vb02=t02,vb03=t03;
      float va10=t10,va11=t11,va12=t12,va13=t13, vb10=t10,vb11=t11,vb12=t12,vb13=t13;
      const float2* E0=&TWE2[a0*20];
      const float2* E1=&TWE2[a1*20];
      #pragma unroll
      for(int m=1;m<10;++m){
        float2 e0=E0[m], e1=E1[m];
        const float2* Sp0=&S0[(m-1)*20+g0];
        const float2* Sp1=&S1[(m-1)*20+g0];
        float2 x0=Sp0[0],x1=Sp0[1],x2=Sp0[2],x3=Sp0[3];
        float2 y0=Sp1[0],y1=Sp1[1],y2=Sp1[2],y3=Sp1[3];
        va00+=x0.x*e0.x-x0.y*e0.y; va01+=x1.x*e0.x-x1.y*e0.y;
        va02+=x2.x*e0.x-x2.y*e0.y; va03+=x3.x*e0.x-x3.y*e0.y;
        vb00+=x0.x*e1.x-x0.y*e1.y; vb01+=x1.x*e1.x-x1.y*e1.y;
        vb02+=x2.x*e1.x-x2.y*e1.y; vb03+=x3.x*e1.x-x3.y*e1.y;
        va10+=y0.x*e0.x-y0.y*e0.y; va11+=y1.x*e0.x-y1.y*e0.y;
        va12+=y2.x*e0.x-y2.y*e0.y; va13+=y3.x*e0.x-y3.y*e0.y;
        vb10+=y0.x*e1.x-y0.y*e1.y; vb11+=y1.x*e1.x-y1.y*e1.y;
        vb12+=y2.x*e1.x-y2.y*e1.y; vb13+=y3.x*e1.x-y3.y*e1.y;
      }
      float* p0=&vb0[a0*20+g0]; float* p1=&vb0[a1*20+g0];
      p0[0]=va00>0.f?va00:0.f; p0[1]=va01>0.f?va01:0.f;
      p0[2]=va02>0.f?va02:0.f; p0[3]=va03>0.f?va03:0.f;
      p1[0]=vb00>0.f?vb00:0.f; p1[1]=vb01>0.f?vb01:0.f;
      p1[2]=vb02>0.f?vb02:0.f; p1[3]=vb03>0.f?vb03:0.f;
      float* q0=&vb1[a0*20+g0]; float* q1=&vb1[a1*20+g0];
      q0[0]=va10>0.f?va10:0.f; q0[1]=va11>0.f?va11:0.f;
      q0[2]=va12>0.f?va12:0.f; q0[3]=va13>0.f?va13:0.f;
      q1[0]=vb10>0.f?vb10:0.f; q1[1]=vb11>0.f?vb11:0.f;
      q1[2]=vb12>0.f?vb12:0.f; q1[3]=vb13>0.f?vb13:0.f;
    }
    WFENCE;
    // D: U_T[nu][a], 2-nu batch, both j's (60 items)
    if(ln<60){
      int a=ln/3, np=ln%3;
      int nu0=2*np, nu1=2*np+1;
      int r0=(np==0)?0:(20-2*np);
      int r1=19-2*np;
      const float* vp0=&vb0[a*20];
      const float* vp1=&vb1[a*20];
      const float2* T0r=&TWE2[r0*20];
      const float2* T1r=&TWE2[r1*20];
      float2 u00=make_float2(0.f,0.f), u01=u00, u10=u00, u11=u00;
      #pragma unroll
      for(int g=0;g<20;++g){
        float x0=vp0[g], x1=vp1[g];
        float2 e0=T0r[g], e1=T1r[g];
        u00.x+=x0*e0.x; u00.y+=x0*e0.y;
        u01.x+=x0*e1.x; u01.y+=x0*e1.y;
        u10.x+=x1*e0.x; u10.y+=x1*e0.y;
        u11.x+=x1*e1.x; u11.y+=x1*e1.y;
      }
      U0[nu0*20+a]=u00; U0[nu1*20+a]=u01;
      U1[nu0*20+a]=u10; U1[nu1*20+a]=u11;
    }
    WFENCE;
    // E: Fq(mu,nu), 61 half items, both j's
    if(ln<61){
      int mu,nu;
      if(ln<6){ mu=ln; nu=0; } else { int qq=ln-6; nu=qq/11+1; mu=qq%11-5; }
      int mm=(mu+20)%20;
      int rm=(20-mm)%20;
      const float2* Ur0=&U0[nu*20];
      const float2* Ur1=&U1[nu*20];
      const float2* Er=&TWE2[rm*20];
      float2 f0=make_float2(0.f,0.f), f1=f0;
      #pragma unroll
      for(int a=0;a<20;++a){
        float2 u0=Ur0[a], u1=Ur1[a], e=Er[a];
        f0.x+=u0.x*e.x-u0.y*e.y; f0.y+=u0.x*e.y+u0.y*e.x;
        f1.x+=u1.x*e.x-u1.y*e.y; f1.y+=u1.x*e.y+u1.y*e.x;
      }
      Fq0[ln]=f0; Fq1[ln]=f1;
    }
    WFENCE;
    // F: accumulate half-s2 with W3H into registers, both j's
    {
      const float* W30=W3H + j0*NH2;
      const float* W31=W3H + j1*NH2;
      {
        int fh=fhLUT[ln];
        float2 f0=Fq0[fh];
        fa0.x+=W30[ln]*f0.x; fa0.y+=W30[ln]*f0.y;
        if(!dup){ float2 f1=Fq1[fh]; fa0.x+=W31[ln]*f1.x; fa0.y+=W31[ln]*f1.y; }
      }
      {
        int fh=fhLUT[64+ln];
        float2 f0=Fq0[fh];
        fa1.x+=W30[64+ln]*f0.x; fa1.y+=W30[64+ln]*f0.y;
        if(!dup){ float2 f1=Fq1[fh]; fa1.x+=W31[64+ln]*f1.x; fa1.y+=W31[64+ln]*f1.y; }
      }
      if(ln<18){
        int fh=fhLUT[128+ln];
        float2 f0=Fq0[fh];
        fa2.x+=W30[128+ln]*f0.x; fa2.y+=W30[128+ln]*f0.y;
        if(!dup){ float2 f1=Fq1[fh]; fa2.x+=W31[128+ln]*f1.x; fa2.y+=W31[128+ln]*f1.y; }
      }
    }
    WFENCE;
  }
  // spill register accumulators, merge 4 waves, expand half->full by conjugation
  regB[w][0][ln]=fa0; regB[w][0][64+ln]=fa1;
  if(ln<18) regB[w][0][128+ln]=fa2;
  __syncthreads();
  for(int h=t; h<146; h+=256){
    unsigned u=xh2LUT[h];
    int s2=u&1023, s2p=(u>>10)&1023;
    float sg=((u>>20)&1)? -1.f : 1.f;
    float2 a0=regB[0][0][h], a1=regB[1][0][h], a2=regB[2][0][h], a3=regB[3][0][h];
    float2 a=make_float2(a0.x+a1.x+a2.x+a3.x, a0.y+a1.y+a2.y+a3.y);
    XH2[(b*286+s2 )*F1+o]=a;
    XH2[(b*286+s2p)*F1+o]=make_float2(sg*a.x, -sg*a.y);
  }
}

// K2H: gather from KA (ai-DFT) + beta contraction; Hermitian half + conj fill
__global__ void k2h_k(const float2* __restrict__ KA, const float* __restrict__ D3_2,
                      const unsigned* __restrict__ h2LUT, const unsigned* __restrict__ xh2LUT,
                      float2* __restrict__ K2H){
  __shared__ float2 E8s[8];
  if(threadIdx.x<8) E8s[threadIdx.x]=E8c[threadIdx.x];
  __syncthreads();
  int idx=blockIdx.x*blockDim.x+threadIdx.x;
  if(idx>=NH2*F1*F2) return;
  int o=idx/(NH2*F1); int r=idx%(NH2*F1); int h=r/F1, i=r%F1;
  unsigned hu=h2LUT[h];
  int l=hu&15, mi=(hu>>4)&15, ni=(hu>>8)&15, s2=hu>>12;
  int m=mi-l, n=ni-l;
  unsigned xu=xh2LUT[h];
  int s2p=(xu>>10)&1023;
  float sg=((xu>>20)&1)? -1.f : 1.f;
  int q=n&7, p=(m-n)&7;
  const float2* kab=KA+(size_t)(i*F2+o)*192+q*8;
  float2 acc=make_float2(0.f,0.f);
  for(int bi=0;bi<3;++bi){
    const float2* kp=kab+bi*64;
    float2 s=make_float2(0.f,0.f);
    int ph=0;
    #pragma unroll
    for(int ai=0;ai<8;++ai){
      float2 ka=kp[ai], e=E8s[ph];
      s.x+=ka.x*e.x-ka.y*e.y; s.y+=ka.x*e.y+ka.y*e.x;
      ph=(ph+p)&7;
    }
    float dv=D3_2[bi*286+s2];
    acc.x+=dv*s.x; acc.y+=dv*s.y;
  }
  const float SC2f = 0.034722222222222224f;
  acc.x*=SC2f; acc.y*=SC2f;
  K2H[((size_t)o*286+s2)*F1+i]=acc;
  K2H[((size_t)o*286+s2p)*F1+i]=make_float2(sg*acc.x,-sg*acc.y);
}

// fused2: cooperative z2 build, then wave-per-3j single-pass synthesis+integrate
__global__ __launch_bounds__(256,3) void fused2(
    const float2* __restrict__ XH2, const float2* __restrict__ K2H,
    const float* __restrict__ D2SJ, const float* __restrict__ WINT,
    const float2* __restrict__ E12, const float* __restrict__ bias2,
    const unsigned* __restrict__ h2LUT, const unsigned* __restrict__ xh2LUT,
    float* __restrict__ FEAT){
  const int b=blockIdx.x, o=blockIdx.y, t=threadIdx.x;
  const int ln=t&63, w=t>>6;
  __shared__ __align__(16) float2 Xs[2420];
  __shared__ __align__(16) float2 Ks[2420];
  __shared__ float2 zpS[1144];
  __shared__ float2 z2S[286];
  __shared__ float  redS[256];
  float2* alias=(float2*)Xs;       // reused after z-build
  float2* TWE12=alias;             // [12][12]: e^{i r c th12}

  const int gb[4]={0,84,165,286};
  const int hb[4]={0,44,85,146};
  for(int grp=0; grp<3; ++grp){
    int row0=gb[grp], rows=gb[grp+1]-row0;
    {
      int cnt4=rows*10;
      const float4* xsrc=(const float4*)(XH2+(size_t)(b*286+row0)*F1);
      const float4* ksrc=(const float4*)(K2H+(size_t)(o*286+row0)*F1);
      float4* xd=(float4*)Xs; float4* kd=(float4*)Ks;
      for(int i=t;i<cnt4;i+=256){ xd[i]=xsrc[i]; kd[i]=ksrc[i]; }
    }
    __syncthreads();
    int nh=hb[grp+1]-hb[grp];
    for(int idx=t; idx<4*nh; idx+=256){
      int hl=idx>>2, iq=idx&3;
      int h=hb[grp]+hl;
      unsigned hu=h2LUT[h];
      int l=hu&15, mi=(hu>>4)&15, ni=(hu>>8)&15, s2=hu>>12;
      int L=2*l+1;
      int xr0=(B2OFFc[l]-row0)+mi*L;
      int kr0=(B2OFFc[l]-row0)+ni*L;
      float2 acc=make_float2(0.f,0.f);
      for(int k=0;k<L;++k){
        const float2* xp=Xs+(xr0+k)*F1+iq*5;
        const float2* kp=Ks+(kr0+k)*F1+iq*5;
        #pragma unroll
        for(int i=0;i<5;++i){
          float2 xa=xp[i], kb=kp[i];
          acc.x += xa.x*kb.x + xa.y*kb.y;
          acc.y += xa.y*kb.x - xa.x*kb.y;
        }
      }
      zpS[iq*286+s2]=acc;
    }
    __syncthreads();
  }
  for(int idx=t; idx<146; idx+=256){
    unsigned xu=xh2LUT[idx];
    int s2=xu&1023, s2p=(xu>>10)&1023;
    float sg=((xu>>20)&1)? -1.f : 1.f;
    float2 a;
    a.x=zpS[0*286+s2].x+zpS[1*286+s2].x+zpS[2*286+s2].x+zpS[3*286+s2].x;
    a.y=zpS[0*286+s2].y+zpS[1*286+s2].y+zpS[2*286+s2].y+zpS[3*286+s2].y;
    z2S[s2]=a;
    z2S[s2p]=make_float2(sg*a.x,-sg*a.y);
  }
  __syncthreads();
  for(int idx=t; idx<144; idx+=256){
    int r=idx/12, c=idx%12;
    TWE12[idx]=E12[(r*c)%12];
  }
  __syncthreads();

  float2* base=alias+144+w*400;
  float2* G2_0=base;      float2* G2_1=base+66;  float2* G2_2=base+132;
  float2* S2_0=base+198;  float2* S2_1=base+258; float2* S2_2=base+318;
  float*  T02=(float*)(base+378);   // [3][12]
  float personal=0.f;
  const float b2v=bias2[o];
  const int j0=3*w, j1=3*w+1, j2=3*w+2;
  const float* Dg0=D2SJ + j0*286;
  const float* Dg1=D2SJ + j1*286;
  const float* Dg2=D2SJ + j2*286;
  const int BR12[11]={7,8,9,10,11,0,1,2,3,4,5};

  // A2: 61 half items, 3 j's
  if(ln<61){
    int m,n;
    if(ln<6){m=0;n=ln;} else {int qq=ln-6;m=qq/11+1;n=qq%11-5;}
    int an=n<0?-n:n; int l=m>an?m:an; int L=2*l+1;
    int zi=B2OFFc[l]+(m+l)*L+(n+l); int m2=2*m+2;
    float2 a0=make_float2(0.f,0.f), a1=a0, a2=a0;
    for(;l<6;++l){
      float2 zv=z2S[zi];
      float d0=Dg0[zi], d1=Dg1[zi], d2=Dg2[zi];
      a0.x+=zv.x*d0; a0.y+=zv.y*d0;
      a1.x+=zv.x*d1; a1.y+=zv.y*d1;
      a2.x+=zv.x*d2; a2.y+=zv.y*d2;
      zi+=L*L+2*L+m2; L+=2;
    }
    int gi=m*11+(n+5);
    G2_0[gi]=a0; G2_1[gi]=a1; G2_2[gi]=a2;
  }
  WFENCE;
  // B2: 42 items (30 S-pairs + 12 T0), 3 j's
  if(ln<30){
    int m=ln/6+1, g=(ln%6)*2;
    const float2* Gr0=&G2_0[m*11];
    const float2* Gr1=&G2_1[m*11];
    const float2* Gr2=&G2_2[m*11];
    float2 s00=make_float2(0.f,0.f),s01=s00, s10=s00,s11=s00, s20=s00,s21=s00;
    #pragma unroll
    for(int c=0;c<11;++c){
      const float2* tw=&TWE12[BR12[c]*12+g];
      float2 e0=tw[0], e1=tw[1];
      float2 g0=Gr0[c], g1=Gr1[c], g2=Gr2[c];
      s00.x+=g0.x*e0.x-g0.y*e0.y; s00.y+=g0.x*e0.y+g0.y*e0.x;
      s01.x+=g0.x*e1.x-g0.y*e1.y; s01.y+=g0.x*e1.y+g0.y*e1.x;
      s10.x+=g1.x*e0.x-g1.y*e0.y; s10.y+=g1.x*e0.y+g1.y*e0.x;
      s11.x+=g1.x*e1.x-g1.y*e1.y; s11.y+=g1.x*e1.y+g1.y*e1.x;
      s20.x+=g2.x*e0.x-g2.y*e0.y; s20.y+=g2.x*e0.y+g2.y*e0.x;
      s21.x+=g2.x*e1.x-g2.y*e1.y; s21.y+=g2.x*e1.y+g2.y*e1.x;
    }
    int si=(m-1)*12+g;
    S2_0[si]=make_float2(2.f*s00.x,2.f*s00.y); S2_0[si+1]=make_float2(2.f*s01.x,2.f*s01.y);
    S2_1[si]=make_float2(2.f*s10.x,2.f*s10.y); S2_1[si+1]=make_float2(2.f*s11.x,2.f*s11.y);
    S2_2[si]=make_float2(2.f*s20.x,2.f*s20.y); S2_2[si+1]=make_float2(2.f*s21.x,2.f*s21.y);
  } else if(ln<42){
    int g=ln-30;
    float r0=G2_0[5].x, r1=G2_1[5].x, r2=G2_2[5].x;
    #pragma unroll
    for(int n=1;n<6;++n){
      float2 e=TWE12[n*12+g];
      float2 g0=G2_0[5+n], g1=G2_1[5+n], g2=G2_2[5+n];
      r0+=2.f*(g0.x*e.x-g0.y*e.y);
      r1+=2.f*(g1.x*e.x-g1.y*e.y);
      r2+=2.f*(g2.x*e.x-g2.y*e.y);
    }
    T02[g]=r0; T02[12+g]=r1; T02[24+g]=r2;
  }
  WFENCE;
  // C2: 36 items, 4-g batch, fused relu+integrate, 3 j's
  if(ln<36){
    float w0=WINT[j0], w1=WINT[j1], w2=WINT[j2];
    int a=ln/3, g4=(ln%3)*4;
    float v00=T02[g4]+b2v,    v01=T02[g4+1]+b2v,    v02=T02[g4+2]+b2v,    v03=T02[g4+3]+b2v;
    float v10=T02[12+g4]+b2v, v11=T02[12+g4+1]+b2v, v12=T02[12+g4+2]+b2v, v13=T02[12+g4+3]+b2v;
    float v20=T02[24+g4]+b2v, v21=T02[24+g4+1]+b2v, v22=T02[24+g4+2]+b2v, v23=T02[24+g4+3]+b2v;
    #pragma unroll
    for(int m=1;m<6;++m){
      float2 e=TWE12[a*12+m];
      const float2* p0=&S2_0[(m-1)*12+g4];
      const float2* p1=&S2_1[(m-1)*12+g4];
      const float2* p2=&S2_2[(m-1)*12+g4];
      float2 x0=p0[0],x1=p0[1],x2=p0[2],x3=p0[3];
      float2 y0=p1[0],y1=p1[1],y2=p1[2],y3=p1[3];
      float2 z0=p2[0],z1=p2[1],z2=p2[2],z3=p2[3];
      v00+=x0.x*e.x-x0.y*e.y; v01+=x1.x*e.x-x1.y*e.y;
      v02+=x2.x*e.x-x2.y*e.y; v03+=x3.x*e.x-x3.y*e.y;
      v10+=y0.x*e.x-y0.y*e.y; v11+=y1.x*e.x-y1.y*e.y;
      v12+=y2.x*e.x-y2.y*e.y; v13+=y3.x*e.x-y3.y*e.y;
      v20+=z0.x*e.x-z0.y*e.y; v21+=z1.x*e.x-z1.y*e.y;
      v22+=z2.x*e.x-z2.y*e.y; v23+=z3.x*e.x-z3.y*e.y;
    }
    personal += w0*((v00>0.f?v00:0.f)+(v01>0.f?v01:0.f)+(v02>0.f?v02:0.f)+(v03>0.f?v03:0.f))
              + w1*((v10>0.f?v10:0.f)+(v11>0.f?v11:0.f)+(v12>0.f?v12:0.f)+(v13>0.f?v13:0.f))
              + w2*((v20>0.f?v20:0.f)+(v21>0.f?v21:0.f)+(v22>0.f?v22:0.f)+(v23>0.f?v23:0.f));
  }
  redS[t]=personal;
  __syncthreads();
  for(int s=128;s>0;s>>=1){
    if(t<s) redS[t]+=redS[t+s];
    __syncthreads();
  }
  if(t==0) FEAT[b*F2+o]=redS[0];
}

__global__ void head_k(const float* __restrict__ FEAT, const float* __restrict__ w_out,
                       const float* __restrict__ b_lin, float* __restrict__ out){
  int idx=blockIdx.x*blockDim.x+threadIdx.x;
  if(idx>=BATCH*FOUT) return;
  int b=idx/FOUT, q=idx%FOUT;
  float acc=b_lin[q];
  for(int f=0;f<F2;++f) acc += FEAT[b*F2+f]*w_out[q*F2+f];
  out[idx]=acc;
}

extern "C" void kernel_launch(void* const* d_in, const int* in_sizes, int n_in,
                              void* d_out, int out_size, void* d_ws, size_t ws_size,
                              hipStream_t stream) {
  const float* x    =(const float*)d_in[0];
  const float* k1   =(const float*)d_in[1];
  const float* bias1=(const float*)d_in[2];
  const float* k2   =(const float*)d_in[3];
  const float* bias2=(const float*)d_in[4];
  const float* w_out=(const float*)d_in[5];
  const float* b_lin=(const float*)d_in[6];
  float* out=(float*)d_out;

  char* ws=(char*)d_ws;
  float*  A1   =(float* )(ws+0);        //  6000 f
  float*  D1SJ =(float* )(ws+24000);    //  26600 f
  float*  W3H  =(float* )(ws+130400);   //  2920 f
  float*  D2SJ =(float* )(ws+142080);   //  3432 f
  float*  D3_2 =(float* )(ws+155808);   //  858 f (+pad)
  float*  D3_1 =(float* )(ws+159248);   //  300 f
  float*  WINT =(float* )(ws+160448);   //  12 f
  float2* E60  =(float2*)(ws+160496);   //  60 c
  float2* E20  =(float2*)(ws+160976);   //  20 c
  float2* E12  =(float2*)(ws+161136);   //  12 c (+pad)
  unsigned* zLUT=(unsigned*)(ws+161248);//  1330 u32 (+pad)
  unsigned* xh2LUT=(unsigned*)(ws+166576); // 146 u32
  unsigned* h2LUT =(unsigned*)(ws+167160); // 146 u32
  unsigned short* fhLUT=(unsigned short*)(ws+167744); // 146 u16 (+pad)
  float2* XHAT =(float2*)(ws+168048);   //  [b][100] c
  float2* K1H  =(float2*)(ws+270448);   //  [o][100] c
  float2* KA   =(float2*)(ws+286448);   //  153600 c (1.2MB)
  float2* XH2  =(float2*)(ws+1515248);  //  [b][286][20] c
  float2* K2H  =(float2*)(ws+7372528);  //  [o][286][20] c
  float*  FEAT =(float* )(ws+9202928);  //  128*40 f -> 9223408 total

  (void)in_sizes; (void)n_in; (void)out_size; (void)ws_size;

  gen_all<<<168,256,0,stream>>>(A1,D1SJ,W3H,D2SJ,D3_2,D3_1,WINT,E60,E20,E12,
                                zLUT,xh2LUT,h2LUT,fhLUT);
  front_k<<<736,256,0,stream>>>(x,k1,k2,E60,A1,D3_1,XHAT,K1H,KA);
  dim3 g1(BATCH,F1);
  fused1<<<g1,256,0,stream>>>(XHAT,K1H,D1SJ,W3H,E20,bias1,zLUT,xh2LUT,fhLUT,XH2);
  k2h_k<<<(NH2*F1*F2+255)/256,256,0,stream>>>(KA,D3_2,h2LUT,xh2LUT,K2H);
  dim3 g2(BATCH,F2);
  fused2<<<g2,256,0,stream>>>(XH2,K2H,D2SJ,WINT,E12,bias2,h2LUT,xh2LUT,FEAT);
  head_k<<<(BATCH*FOUT+255)/256,256,0,stream>>>(FEAT,w_out,b_lin,out);
}

// Round 8
// 289.740 us; speedup vs baseline: 1.2388x; 1.2388x over previous
//
#include <hip/hip_runtime.h>
#include <math.h>

#define PI_D 3.14159265358979323846

#define BATCH 128
#define F1 20
#define F2 40
#define FOUT 10
#define NS1 100   // sum_{l<10} (2l+1)
#define NS2 286   // sum_{l<6} (2l+1)^2
#define NH2 146   // Hermitian half count of NS2

__constant__ int ZB10c[11] = {0,1,10,35,84,165,286,455,680,969,1330};
__constant__ int B2OFFc[7] = {0,1,10,35,84,165,286};
__constant__ int HOFFc[7]  = {0,1,6,19,44,85,146};
// E8c[q] = exp(-2*pi*i*q/8)
__constant__ float2 E8c[8] = {
  { 1.f, 0.f}, { 0.70710678118654752f,-0.70710678118654752f},
  { 0.f,-1.f}, {-0.70710678118654752f,-0.70710678118654752f},
  {-1.f, 0.f}, {-0.70710678118654752f, 0.70710678118654752f},
  { 0.f, 1.f}, { 0.70710678118654752f, 0.70710678118654752f}};

// wave-synchronous phase fence
#define WFENCE do{ __builtin_amdgcn_sched_barrier(0); \
  asm volatile("s_waitcnt lgkmcnt(0)" ::: "memory"); \
  __builtin_amdgcn_sched_barrier(0); }while(0)

// half-space H = { (m,n): n>0 } U { (m,n): n==0 && m>=0 }
__device__ inline void h_decode(int h, int& l, int& m, int& n){
  l=0; while(HOFFc[l+1]<=h) ++l;
  int r=h-HOFFc[l], L=2*l+1;
  if(r<l+1){ n=0; m=r; }
  else { int q=r-(l+1); n=q/L+1; m=q%L-l; }
}

// ---------------- double-precision table generation helpers ----------------
__device__ inline double ipow_d(double x, int n){ double r=1.0; for(int i=0;i<n;++i) r*=x; return r; }
__device__ inline double dfact(int n){ double r=1.0; for(int i=2;i<=n;++i) r*=(double)i; return r; }

__device__ double wigd(int l, int mp, int m, double beta){
  double cb=cos(0.5*beta), sb=sin(0.5*beta);
  double pref=sqrt(dfact(l+mp)*dfact(l-mp)*dfact(l+m)*dfact(l-m));
  int s0 = (m-mp>0) ? (m-mp) : 0;
  int s1 = (l+m < l-mp) ? (l+m) : (l-mp);
  double acc=0.0;
  for(int s=s0;s<=s1;++s){
    double den=dfact(l+m-s)*dfact(s)*dfact(mp-m+s)*dfact(l-mp-s);
    double t=ipow_d(cb,2*l+m-mp-2*s)*ipow_d(sb,mp-m+2*s)/den;
    acc += ((mp-m+s)&1)? -t : t;
  }
  return pref*acc;
}

__device__ double dhw(int b, int j){
  double beta=PI_D*(2*j+1)/(4.0*b);
  double s=0.0;
  for(int k=0;k<b;++k) s += sin((2*k+1)*beta)/(2*k+1);
  return (2.0/b)*sin(beta)*s;
}

__device__ inline float2 cmulc(float2 a, float2 b){ // a * conj(b)
  return make_float2(a.x*b.x + a.y*b.y, a.y*b.x - a.x*b.y);
}

// ---------------- single merged table-generation kernel ----------------
__global__ void gen_all(float* A1, float* D1SJ, float* W3H, float* D2SJ,
                        float* D3_2, float* D3_1, float* WINT,
                        float2* E60, float2* E20, float2* E12,
                        unsigned* zLUT, unsigned* xh2LUT, unsigned* h2LUT,
                        unsigned short* fhLUT){
  int blk=blockIdx.x, t=threadIdx.x;
  if(blk<24){                     // A1: [j][s1], 60x100
    int idx=blk*256+t; if(idx>=6000) return;
    int j=idx/NS1, s=idx%NS1;
    int l=0; while((l+1)*(l+1)<=s) ++l;
    int m=s-l*l-l;
    double beta=PI_D*(2*j+1)/120.0;
    A1[idx]=(float)(wigd(l,m,0,beta)*dhw(30,j)*(2.0*PI_D/60.0));
  } else if(blk<128){             // D1SJ: [j][1330]
    int idx=(blk-24)*256+t; if(idx>=26600) return;
    int j=idx/1330, s=idx%1330;
    int l=0; while(ZB10c[l+1]<=s) ++l;
    int r=s-ZB10c[l]; int L=2*l+1;
    int mi=r/L, ni=r%L;
    double beta=PI_D*(2*j+1)/40.0;
    D1SJ[idx]=(float)((2*l+1)*wigd(l,mi-l,ni-l,beta));
  } else if(blk<140){             // W3H: [j][146]
    int idx=(blk-128)*256+t; if(idx>=20*NH2) return;
    int j=idx/NH2, h=idx%NH2;
    int l,m,n; h_decode(h,l,m,n);
    double beta=PI_D*(2*j+1)/40.0;
    double c=2.0*PI_D/20.0;
    W3H[idx]=(float)(wigd(l,m,n,beta)*dhw(10,j)*c*c);
  } else if(blk<154){             // D2SJ: [j][286]
    int idx=(blk-140)*256+t; if(idx>=3432) return;
    int j=idx/286, s=idx%286;
    int l=0; while(B2OFFc[l+1]<=s) ++l;
    int r=s-B2OFFc[l]; int L=2*l+1;
    int mi=r/L, ni=r%L;
    double beta=PI_D*(2*j+1)/24.0;
    D2SJ[idx]=(float)((2*l+1)*wigd(l,mi-l,ni-l,beta));
  } else if(blk<158){             // D3_2: [bi][286]
    int idx=(blk-154)*256+t; if(idx>=3*286) return;
    int bi=idx/286, s=idx%286;
    int l=0; while(B2OFFc[l+1]<=s) ++l;
    int r=s-B2OFFc[l]; int L=2*l+1;
    int mi=r/L, ni=r%L;
    double beta=(bi+1)*(PI_D/8.0)/3.0;
    D3_2[idx]=(float)wigd(l,mi-l,ni-l,beta);
  } else if(blk<160){             // D3_1: [bi][100]
    int idx=(blk-158)*256+t; if(idx>=3*100) return;
    int bi=idx/100, s=idx%100;
    int l=0; while((l+1)*(l+1)<=s) ++l;
    int m=s-l*l-l;
    double beta=(bi+1)*(PI_D/8.0)/3.0;
    D3_1[idx]=(float)wigd(l,m,0,beta);
  } else if(blk==160){            // misc
    if(t<12){ double c=2.0*PI_D/12.0; WINT[t]=(float)(dhw(6,t)*c*c); }
    if(t<60){ double a=2.0*PI_D*t/60.0; E60[t]=make_float2((float)cos(a),(float)sin(a)); }
    if(t<20){ double a=2.0*PI_D*t/20.0; E20[t]=make_float2((float)cos(a),(float)sin(a)); }
    if(t<12){ double a=2.0*PI_D*t/12.0; E12[t]=make_float2((float)cos(a),(float)sin(a)); }
  } else if(blk<167){             // zLUT[1330]: packed s1x | s1k<<16
    int idx=(blk-161)*256+t; if(idx>=1330) return;
    int l=0; while(ZB10c[l+1]<=idx) ++l;
    int r=idx-ZB10c[l], L=2*l+1;
    int mi=r/L, ni=r%L;
    unsigned s1x=(unsigned)(l*l+mi), s1k=(unsigned)(l*l+ni);
    zLUT[idx]=s1x|(s1k<<16);
  } else {                        // blk==167: xh2LUT, h2LUT, fhLUT
    if(t<146){
      int l,m,n; h_decode(t,l,m,n);
      int L=2*l+1;
      int s2 =B2OFFc[l]+(m+l)*L+(n+l);
      int s2p=B2OFFc[l]+(l-m)*L+(l-n);
      unsigned sg=(unsigned)((m+n)&1);
      xh2LUT[t]=(unsigned)s2 | ((unsigned)s2p<<10) | (sg<<20);
      h2LUT[t]=(unsigned)l | ((unsigned)(m+l)<<4) | ((unsigned)(n+l)<<8) | ((unsigned)s2<<12);
      fhLUT[t]=(unsigned short)((n==0)? m : 6+(n-1)*11+(m+5));
    }
  }
}

// ---------------- front: per-b DFT+S2 analysis | k1h | KA (k2 gamma-DFT) ----------------
__global__ __launch_bounds__(256) void front_k(const float* __restrict__ x,
    const float* __restrict__ k1, const float* __restrict__ k2,
    const float2* __restrict__ E60, const float* __restrict__ A1,
    const float* __restrict__ D3_1,
    float2* __restrict__ XHAT, float2* __restrict__ K1H, float2* __restrict__ KA){
  __shared__ float2 E8s[8];
  int blk=blockIdx.x, t=threadIdx.x;
  if(blk<128){
    __shared__ float xs[3600];
    __shared__ float2 E60s[60];
    __shared__ float2 XFs[1140];     // [j][mi], mi = m+9
    if(t<60) E60s[t]=E60[t];
    {
      const float4* src=(const float4*)(x+blk*3600);
      float4* dst=(float4*)xs;
      for(int i=t;i<900;i+=256) dst[i]=src[i];
    }
    __syncthreads();
    for(int idx=t; idx<1140; idx+=256){
      int j=idx/19, mi=idx%19;
      int step=(mi<9)? mi+51 : mi-9;
      const float* xr=xs+j*60;
      float2 acc=make_float2(0.f,0.f);
      int k=0;
      for(int a=0;a<60;++a){
        float2 e=E60s[k]; float xv=xr[a];
        acc.x+=xv*e.x; acc.y-=xv*e.y;
        k+=step; if(k>=60)k-=60;
      }
      XFs[idx]=acc;
    }
    __syncthreads();
    for(int s=t; s<100; s+=256){
      int l=0; while((l+1)*(l+1)<=s) ++l;
      int m=s-l*l-l;
      const float2* xf=&XFs[m+9];
      float2 acc=make_float2(0.f,0.f);
      for(int j=0;j<60;++j){
        float a1=A1[j*NS1+s];
        float2 v=xf[j*19];
        acc.x+=a1*v.x; acc.y+=a1*v.y;
      }
      XHAT[blk*NS1+s]=acc;
    }
  } else if(blk<136){
    if(t<8) E8s[t]=E8c[t];
    __syncthreads();
    int idx=(blk-128)*256+t;
    if(idx<F1*NS1){
      int o=idx/NS1, s=idx%NS1;
      int l=0; while((l+1)*(l+1)<=s) ++l;
      int m=s-l*l-l;
      int mm=m&7;
      float2 acc=make_float2(0.f,0.f);
      for(int bi=0;bi<3;++bi){
        float2 sum=make_float2(0.f,0.f);
        int q=0;
        #pragma unroll
        for(int ai=0;ai<8;++ai){
          float kv=k1[o*24+bi*8+ai];
          float2 e=E8s[q];
          sum.x+=kv*e.x; sum.y+=kv*e.y;
          q=(q+mm)&7;
        }
        float dv=D3_1[bi*100+s];
        acc.x+=dv*sum.x; acc.y+=dv*sum.y;
      }
      const float SC1f = 0.06123724356957945f;
      K1H[idx]=make_float2(acc.x*SC1f, acc.y*SC1f);
    }
  } else {
    // KA[io*192 + bi*64 + q*8 + ai] = sum_gi k2[io*192+bi*64+ai*8+gi]*e8[(gi*q)&7]
    if(t<8) E8s[t]=E8c[t];
    __syncthreads();
    int idx=(blk-136)*256+t;
    if(idx<153600){
      int ai=idx&7, q=(idx>>3)&7;
      int r2=idx>>6;
      int bi=r2%3, io=r2/3;
      const float* kp=k2+(size_t)io*192+bi*64+ai*8;
      float2 acc=make_float2(0.f,0.f);
      int ph=0;
      #pragma unroll
      for(int gi=0;gi<8;++gi){
        float kv=kp[gi];
        float2 e=E8s[ph];
        acc.x+=kv*e.x; acc.y+=kv*e.y;
        ph=(ph+q)&7;
      }
      KA[(size_t)io*192+bi*64+q*8+ai]=acc;
    }
  }
}

// fused1: wave-per-j barrier-free pipeline (round-6 structure), LUT decodes.
// XH2 layout: [b][s2][i]
__global__ __launch_bounds__(256,4) void fused1(
    const float2* __restrict__ XHAT, const float2* __restrict__ K1H,
    const float* __restrict__ D1SJ, const float* __restrict__ W3H,
    const float2* __restrict__ E20, const float* __restrict__ bias1,
    const unsigned* __restrict__ zLUT, const unsigned* __restrict__ xh2LUT,
    const unsigned short* __restrict__ fhLUT,
    float2* __restrict__ XH2){
  const int b=blockIdx.x, o=blockIdx.y, t=threadIdx.x;
  const int ln=t&63, w=t>>6;
  __shared__ float2 zS[1330];
  __shared__ float2 TWE2[400];       // [r][k] = e^{i r k th}, 20x20
  __shared__ float2 regA[4][200];    // G[10][19] -> v(float[400]) -> Fq[61]
  __shared__ float2 regB[4][190];    // S[9][20]+T0(float[20]) -> U_T[6][20] -> final acc

  for(int idx=t; idx<400; idx+=256){
    int r=idx/20, c=idx%20;
    TWE2[idx]=E20[(r*c)%20];
  }
  for(int idx=t; idx<1330; idx+=256){
    unsigned u=zLUT[idx];
    float2 xa=XHAT[b*NS1 + (u&0xffff)];
    float2 kb=K1H[o*NS1 + (u>>16)];
    zS[idx]=cmulc(xa,kb);
  }
  __syncthreads();

  const float bb1=bias1[o];
  float2* G  = regA[w];
  float*  vb = (float*)regA[w];
  float2* Fq = regA[w];
  float2* S  = regB[w];
  float*  T0 = (float*)(regB[w]+180);
  float2* U_T= regB[w];
  float2 fa0=make_float2(0.f,0.f), fa1=fa0, fa2=fa0;

  // B-phase twiddle rows: n=c-9 -> row (c+11)%20
  const int BROW[19]={11,12,13,14,15,16,17,18,19,0,1,2,3,4,5,6,7,8,9};

  for(int jq=0;jq<5;++jq){
    const int j=jq*4+w;
    const float* Dg=D1SJ + j*1330;
    // A: Wigner-beta contraction, half-space (181 items, 3 passes)
    for(int idx=ln; idx<181; idx+=64){
      int m,n;
      if(idx<10){ m=0; n=idx; } else { int q=idx-10; m=q/19+1; n=q%19-9; }
      int an=n<0?-n:n;
      int l=m>an?m:an;
      int L=2*l+1;
      int zi=ZB10c[l]+(m+l)*L+(n+l);
      int m2=2*m+2;
      float2 a0=make_float2(0.f,0.f);
      for(; l<10; ++l){
        float2 zv=zS[zi]; float d=Dg[zi];
        a0.x+=zv.x*d; a0.y+=zv.y*d;
        zi += L*L + 2*L + m2; L += 2;
      }
      G[m*19+(n+9)]=a0;
    }
    WFENCE;
    // B: S_m(g4)=2*sum_n G(m,n)e^{ing} (45 items) + T0 quads (5 items), single pass
    if(ln<45){
      int mb=ln/5+1, g0=(ln%5)*4;
      const float2* Gr=&G[mb*19];
      float2 s0=make_float2(0.f,0.f), s1=s0, s2=s0, s3=s0;
      #pragma unroll
      for(int c=0;c<19;++c){
        float2 gv=Gr[c];
        const float2* tw=&TWE2[BROW[c]*20+g0];
        float2 e0=tw[0],e1=tw[1],e2=tw[2],e3=tw[3];
        s0.x+=gv.x*e0.x-gv.y*e0.y; s0.y+=gv.x*e0.y+gv.y*e0.x;
        s1.x+=gv.x*e1.x-gv.y*e1.y; s1.y+=gv.x*e1.y+gv.y*e1.x;
        s2.x+=gv.x*e2.x-gv.y*e2.y; s2.y+=gv.x*e2.y+gv.y*e2.x;
        s3.x+=gv.x*e3.x-gv.y*e3.y; s3.y+=gv.x*e3.y+gv.y*e3.x;
      }
      float2* Sp=&S[(mb-1)*20+g0];
      Sp[0]=make_float2(2.f*s0.x,2.f*s0.y);
      Sp[1]=make_float2(2.f*s1.x,2.f*s1.y);
      Sp[2]=make_float2(2.f*s2.x,2.f*s2.y);
      Sp[3]=make_float2(2.f*s3.x,2.f*s3.y);
    } else if(ln<50){
      int g0=(ln-45)*4;
      float r0=G[9].x, r1=r0, r2=r0, r3=r0;   // n=0 term
      #pragma unroll
      for(int n=1;n<10;++n){
        float2 gv=G[9+n];
        const float2* tw=&TWE2[n*20+g0];
        float2 e0=tw[0],e1=tw[1],e2=tw[2],e3=tw[3];
        r0+=2.f*(gv.x*e0.x-gv.y*e0.y);
        r1+=2.f*(gv.x*e1.x-gv.y*e1.y);
        r2+=2.f*(gv.x*e2.x-gv.y*e2.y);
        r3+=2.f*(gv.x*e3.x-gv.y*e3.y);
      }
      T0[g0]=r0; T0[g0+1]=r1; T0[g0+2]=r2; T0[g0+3]=r3;
    }
    WFENCE;
    // C: v(a,g)=T0+sum_m Re[S e^{ima}], bias, relu; 2-a x 4-g batch (50 items)
    if(ln<50){
      int ap=ln/5, g0=(ln%5)*4;
      int a0=2*ap, a1=a0+1;
      float t0=T0[g0]+bb1, t1=T0[g0+1]+bb1, t2=T0[g0+2]+bb1, t3=T0[g0+3]+bb1;
      float v00=t0,v01=t1,v02=t2,v03=t3;
      float v10=t0,v11=t1,v12=t2,v13=t3;
      const float2* E0=&TWE2[a0*20];
      const float2* E1=&TWE2[a1*20];
      #pragma unroll
      for(int m=1;m<10;++m){
        float2 e0=E0[m], e1=E1[m];
        const float2* Sp=&S[(m-1)*20+g0];
        float2 s0=Sp[0],s1=Sp[1],s2=Sp[2],s3=Sp[3];
        v00+=s0.x*e0.x-s0.y*e0.y; v01+=s1.x*e0.x-s1.y*e0.y;
        v02+=s2.x*e0.x-s2.y*e0.y; v03+=s3.x*e0.x-s3.y*e0.y;
        v10+=s0.x*e1.x-s0.y*e1.y; v11+=s1.x*e1.x-s1.y*e1.y;
        v12+=s2.x*e1.x-s2.y*e1.y; v13+=s3.x*e1.x-s3.y*e1.y;
      }
      float* vp0=&vb[a0*20+g0];
      float* vp1=&vb[a1*20+g0];
      vp0[0]=v00>0.f?v00:0.f; vp0[1]=v01>0.f?v01:0.f;
      vp0[2]=v02>0.f?v02:0.f; vp0[3]=v03>0.f?v03:0.f;
      vp1[0]=v10>0.f?v10:0.f; vp1[1]=v11>0.f?v11:0.f;
      vp1[2]=v12>0.f?v12:0.f; vp1[3]=v13>0.f?v13:0.f;
    }
    WFENCE;
    // D: U_T[nu][a]=sum_g v(a,g) e^{-i nu g} via rows (20-nu)%20; 2-nu batch (60 items)
    if(ln<60){
      int a=ln/3, np=ln%3;
      int nu0=2*np, nu1=2*np+1;
      int r0=(np==0)?0:(20-2*np);
      int r1=19-2*np;
      const float* vp=&vb[a*20];
      const float2* T0r=&TWE2[r0*20];
      const float2* T1r=&TWE2[r1*20];
      float2 u0=make_float2(0.f,0.f), u1=u0;
      #pragma unroll
      for(int g=0;g<20;++g){
        float xv=vp[g];
        float2 e0=T0r[g], e1=T1r[g];
        u0.x+=xv*e0.x; u0.y+=xv*e0.y;
        u1.x+=xv*e1.x; u1.y+=xv*e1.y;
      }
      U_T[nu0*20+a]=u0; U_T[nu1*20+a]=u1;
    }
    WFENCE;
    // E: Fq(mu,nu)=sum_a U_T[nu][a] e^{-i mu a}; 61 half items
    if(ln<61){
      int mu,nu;
      if(ln<6){ mu=ln; nu=0; } else { int q=ln-6; nu=q/11+1; mu=q%11-5; }
      int mm=(mu+20)%20;
      int rm=(20-mm)%20;
      const float2* Ur=&U_T[nu*20];
      const float2* Er=&TWE2[rm*20];
      float2 f=make_float2(0.f,0.f);
      #pragma unroll
      for(int a=0;a<20;++a){
        float2 u=Ur[a], e=Er[a];
        f.x+=u.x*e.x-u.y*e.y; f.y+=u.x*e.y+u.y*e.x;
      }
      Fq[ln]=f;
    }
    WFENCE;
    // F: accumulate half-s2 with W3H into registers
    {
      const float* W3r=W3H + j*NH2;
      float wv; float2 f;
      wv=W3r[ln];     f=Fq[fhLUT[ln]];     fa0.x+=wv*f.x; fa0.y+=wv*f.y;
      wv=W3r[64+ln];  f=Fq[fhLUT[64+ln]];  fa1.x+=wv*f.x; fa1.y+=wv*f.y;
      if(ln<18){ wv=W3r[128+ln]; f=Fq[fhLUT[128+ln]]; fa2.x+=wv*f.x; fa2.y+=wv*f.y; }
    }
    WFENCE;
  }
  // spill register accumulators, merge 4 waves, expand half->full by conjugation
  regB[w][ln]=fa0; regB[w][64+ln]=fa1;
  if(ln<18) regB[w][128+ln]=fa2;
  __syncthreads();
  for(int h=t; h<146; h+=256){
    unsigned u=xh2LUT[h];
    int s2=u&1023, s2p=(u>>10)&1023;
    float sg=((u>>20)&1)? -1.f : 1.f;
    float2 a0=regB[0][h], a1=regB[1][h], a2=regB[2][h], a3=regB[3][h];
    float2 a=make_float2(a0.x+a1.x+a2.x+a3.x, a0.y+a1.y+a2.y+a3.y);
    XH2[(b*286+s2 )*F1+o]=a;
    XH2[(b*286+s2p)*F1+o]=make_float2(sg*a.x, -sg*a.y);
  }
}

// K2H: gather from KA (ai-DFT) + beta contraction; Hermitian half + conj fill
__global__ void k2h_k(const float2* __restrict__ KA, const float* __restrict__ D3_2,
                      const unsigned* __restrict__ h2LUT, const unsigned* __restrict__ xh2LUT,
                      float2* __restrict__ K2H){
  __shared__ float2 E8s[8];
  if(threadIdx.x<8) E8s[threadIdx.x]=E8c[threadIdx.x];
  __syncthreads();
  int idx=blockIdx.x*blockDim.x+threadIdx.x;
  if(idx>=NH2*F1*F2) return;
  int o=idx/(NH2*F1); int r=idx%(NH2*F1); int h=r/F1, i=r%F1;
  unsigned hu=h2LUT[h];
  int l=hu&15, mi=(hu>>4)&15, ni=(hu>>8)&15, s2=hu>>12;
  int m=mi-l, n=ni-l;
  unsigned xu=xh2LUT[h];
  int s2p=(xu>>10)&1023;
  float sg=((xu>>20)&1)? -1.f : 1.f;
  int q=n&7, p=(m-n)&7;
  const float2* kab=KA+(size_t)(i*F2+o)*192+q*8;
  float2 acc=make_float2(0.f,0.f);
  for(int bi=0;bi<3;++bi){
    const float2* kp=kab+bi*64;
    float2 s=make_float2(0.f,0.f);
    int ph=0;
    #pragma unroll
    for(int ai=0;ai<8;++ai){
      float2 ka=kp[ai], e=E8s[ph];
      s.x+=ka.x*e.x-ka.y*e.y; s.y+=ka.x*e.y+ka.y*e.x;
      ph=(ph+p)&7;
    }
    float dv=D3_2[bi*286+s2];
    acc.x+=dv*s.x; acc.y+=dv*s.y;
  }
  const float SC2f = 0.034722222222222224f;
  acc.x*=SC2f; acc.y*=SC2f;
  K2H[((size_t)o*286+s2)*F1+i]=acc;
  K2H[((size_t)o*286+s2p)*F1+i]=make_float2(sg*acc.x,-sg*acc.y);
}

// fused2: cooperative z2 build, then wave-per-3j single-pass synthesis+integrate
__global__ __launch_bounds__(256,3) void fused2(
    const float2* __restrict__ XH2, const float2* __restrict__ K2H,
    const float* __restrict__ D2SJ, const float* __restrict__ WINT,
    const float2* __restrict__ E12, const float* __restrict__ bias2,
    const unsigned* __restrict__ h2LUT, const unsigned* __restrict__ xh2LUT,
    float* __restrict__ FEAT){
  const int b=blockIdx.x, o=blockIdx.y, t=threadIdx.x;
  const int ln=t&63, w=t>>6;
  __shared__ __align__(16) float2 Xs[2420];
  __shared__ __align__(16) float2 Ks[2420];
  __shared__ float2 zpS[1144];
  __shared__ float2 z2S[286];
  __shared__ float  redS[256];
  float2* alias=(float2*)Xs;       // reused after z-build
  float2* TWE12=alias;             // [12][12]: e^{i r c th12}

  const int gb[4]={0,84,165,286};
  const int hb[4]={0,44,85,146};
  for(int grp=0; grp<3; ++grp){
    int row0=gb[grp], rows=gb[grp+1]-row0;
    {
      int cnt4=rows*10;
      const float4* xsrc=(const float4*)(XH2+(size_t)(b*286+row0)*F1);
      const float4* ksrc=(const float4*)(K2H+(size_t)(o*286+row0)*F1);
      float4* xd=(float4*)Xs; float4* kd=(float4*)Ks;
      for(int i=t;i<cnt4;i+=256){ xd[i]=xsrc[i]; kd[i]=ksrc[i]; }
    }
    __syncthreads();
    int nh=hb[grp+1]-hb[grp];
    for(int idx=t; idx<4*nh; idx+=256){
      int hl=idx>>2, iq=idx&3;
      int h=hb[grp]+hl;
      unsigned hu=h2LUT[h];
      int l=hu&15, mi=(hu>>4)&15, ni=(hu>>8)&15, s2=hu>>12;
      int L=2*l+1;
      int xr0=(B2OFFc[l]-row0)+mi*L;
      int kr0=(B2OFFc[l]-row0)+ni*L;
      float2 acc=make_float2(0.f,0.f);
      for(int k=0;k<L;++k){
        const float2* xp=Xs+(xr0+k)*F1+iq*5;
        const float2* kp=Ks+(kr0+k)*F1+iq*5;
        #pragma unroll
        for(int i=0;i<5;++i){
          float2 xa=xp[i], kb=kp[i];
          acc.x += xa.x*kb.x + xa.y*kb.y;
          acc.y += xa.y*kb.x - xa.x*kb.y;
        }
      }
      zpS[iq*286+s2]=acc;
    }
    __syncthreads();
  }
  for(int idx=t; idx<146; idx+=256){
    unsigned xu=xh2LUT[idx];
    int s2=xu&1023, s2p=(xu>>10)&1023;
    float sg=((xu>>20)&1)? -1.f : 1.f;
    float2 a;
    a.x=zpS[0*286+s2].x+zpS[1*286+s2].x+zpS[2*286+s2].x+zpS[3*286+s2].x;
    a.y=zpS[0*286+s2].y+zpS[1*286+s2].y+zpS[2*286+s2].y+zpS[3*286+s2].y;
    z2S[s2]=a;
    z2S[s2p]=make_float2(sg*a.x,-sg*a.y);
  }
  __syncthreads();
  for(int idx=t; idx<144; idx+=256){
    int r=idx/12, c=idx%12;
    TWE12[idx]=E12[(r*c)%12];
  }
  __syncthreads();

  float2* base=alias+144+w*400;
  float2* G2_0=base;      float2* G2_1=base+66;  float2* G2_2=base+132;
  float2* S2_0=base+198;  float2* S2_1=base+258; float2* S2_2=base+318;
  float*  T02=(float*)(base+378);   // [3][12]
  float personal=0.f;
  const float b2v=bias2[o];
  const int j0=3*w, j1=3*w+1, j2=3*w+2;
  const float* Dg0=D2SJ + j0*286;
  const float* Dg1=D2SJ + j1*286;
  const float* Dg2=D2SJ + j2*286;
  const int BR12[11]={7,8,9,10,11,0,1,2,3,4,5};

  // A2: 61 half items, 3 j's
  if(ln<61){
    int m,n;
    if(ln<6){m=0;n=ln;} else {int qq=ln-6;m=qq/11+1;n=qq%11-5;}
    int an=n<0?-n:n; int l=m>an?m:an; int L=2*l+1;
    int zi=B2OFFc[l]+(m+l)*L+(n+l); int m2=2*m+2;
    float2 a0=make_float2(0.f,0.f), a1=a0, a2=a0;
    for(;l<6;++l){
      float2 zv=z2S[zi];
      float d0=Dg0[zi], d1=Dg1[zi], d2=Dg2[zi];
      a0.x+=zv.x*d0; a0.y+=zv.y*d0;
      a1.x+=zv.x*d1; a1.y+=zv.y*d1;
      a2.x+=zv.x*d2; a2.y+=zv.y*d2;
      zi+=L*L+2*L+m2; L+=2;
    }
    int gi=m*11+(n+5);
    G2_0[gi]=a0; G2_1[gi]=a1; G2_2[gi]=a2;
  }
  WFENCE;
  // B2: 42 items (30 S-pairs + 12 T0), 3 j's
  if(ln<30){
    int m=ln/6+1, g=(ln%6)*2;
    const float2* Gr0=&G2_0[m*11];
    const float2* Gr1=&G2_1[m*11];
    const float2* Gr2=&G2_2[m*11];
    float2 s00=make_float2(0.f,0.f),s01=s00, s10=s00,s11=s00, s20=s00,s21=s00;
    #pragma unroll
    for(int c=0;c<11;++c){
      const float2* tw=&TWE12[BR12[c]*12+g];
      float2 e0=tw[0], e1=tw[1];
      float2 g0=Gr0[c], g1=Gr1[c], g2=Gr2[c];
      s00.x+=g0.x*e0.x-g0.y*e0.y; s00.y+=g0.x*e0.y+g0.y*e0.x;
      s01.x+=g0.x*e1.x-g0.y*e1.y; s01.y+=g0.x*e1.y+g0.y*e1.x;
      s10.x+=g1.x*e0.x-g1.y*e0.y; s10.y+=g1.x*e0.y+g1.y*e0.x;
      s11.x+=g1.x*e1.x-g1.y*e1.y; s11.y+=g1.x*e1.y+g1.y*e1.x;
      s20.x+=g2.x*e0.x-g2.y*e0.y; s20.y+=g2.x*e0.y+g2.y*e0.x;
      s21.x+=g2.x*e1.x-g2.y*e1.y; s21.y+=g2.x*e1.y+g2.y*e1.x;
    }
    int si=(m-1)*12+g;
    S2_0[si]=make_float2(2.f*s00.x,2.f*s00.y); S2_0[si+1]=make_float2(2.f*s01.x,2.f*s01.y);
    S2_1[si]=make_float2(2.f*s10.x,2.f*s10.y); S2_1[si+1]=make_float2(2.f*s11.x,2.f*s11.y);
    S2_2[si]=make_float2(2.f*s20.x,2.f*s20.y); S2_2[si+1]=make_float2(2.f*s21.x,2.f*s21.y);
  } else if(ln<42){
    int g=ln-30;
    float r0=G2_0[5].x, r1=G2_1[5].x, r2=G2_2[5].x;
    #pragma unroll
    for(int n=1;n<6;++n){
      float2 e=TWE12[n*12+g];
      float2 g0=G2_0[5+n], g1=G2_1[5+n], g2=G2_2[5+n];
      r0+=2.f*(g0.x*e.x-g0.y*e.y);
      r1+=2.f*(g1.x*e.x-g1.y*e.y);
      r2+=2.f*(g2.x*e.x-g2.y*e.y);
    }
    T02[g]=r0; T02[12+g]=r1; T02[24+g]=r2;
  }
  WFENCE;
  // C2: 36 items, 4-g batch, fused relu+integrate, 3 j's
  if(ln<36){
    float w0=WINT[j0], w1=WINT[j1], w2=WINT[j2];
    int a=ln/3, g4=(ln%3)*4;
    float v00=T02[g4]+b2v,    v01=T02[g4+1]+b2v,    v02=T02[g4+2]+b2v,    v03=T02[g4+3]+b2v;
    float v10=T02[12+g4]+b2v, v11=T02[12+g4+1]+b2v, v12=T02[12+g4+2]+b2v, v13=T02[12+g4+3]+b2v;
    float v20=T02[24+g4]+b2v, v21=T02[24+g4+1]+b2v, v22=T02[24+g4+2]+b2v, v23=T02[24+g4+3]+b2v;
    #pragma unroll
    for(int m=1;m<6;++m){
      float2 e=TWE12[a*12+m];
      const float2* p0=&S2_0[(m-1)*12+g4];
      const float2* p1=&S2_1[(m-1)*12+g4];
      const float2* p2=&S2_2[(m-1)*12+g4];
      float2 x0=p0[0],x1=p0[1],x2=p0[2],x3=p0[3];
      float2 y0=p1[0],y1=p1[1],y2=p1[2],y3=p1[3];
      float2 z0=p2[0],z1=p2[1],z2=p2[2],z3=p2[3];
      v00+=x0.x*e.x-x0.y*e.y; v01+=x1.x*e.x-x1.y*e.y;
      v02+=x2.x*e.x-x2.y*e.y; v03+=x3.x*e.x-x3.y*e.y;
      v10+=y0.x*e.x-y0.y*e.y; v11+=y1.x*e.x-y1.y*e.y;
      v12+=y2.x*e.x-y2.y*e.y; v13+=y3.x*e.x-y3.y*e.y;
      v20+=z0.x*e.x-z0.y*e.y; v21+=z1.x*e.x-z1.y*e.y;
      v22+=z2.x*e.x-z2.y*e.y; v23+=z3.x*e.x-z3.y*e.y;
    }
    personal += w0*((v00>0.f?v00:0.f)+(v01>0.f?v01:0.f)+(v02>0.f?v02:0.f)+(v03>0.f?v03:0.f))
              + w1*((v10>0.f?v10:0.f)+(v11>0.f?v11:0.f)+(v12>0.f?v12:0.f)+(v13>0.f?v13:0.f))
              + w2*((v20>0.f?v20:0.f)+(v21>0.f?v21:0.f)+(v22>0.f?v22:0.f)+(v23>0.f?v23:0.f));
  }
  redS[t]=personal;
  __syncthreads();
  for(int s=128;s>0;s>>=1){
    if(t<s) redS[t]+=redS[t+s];
    __syncthreads();
  }
  if(t==0) FEAT[b*F2+o]=redS[0];
}

__global__ void head_k(const float* __restrict__ FEAT, const float* __restrict__ w_out,
                       const float* __restrict__ b_lin, float* __restrict__ out){
  int idx=blockIdx.x*blockDim.x+threadIdx.x;
  if(idx>=BATCH*FOUT) return;
  int b=idx/FOUT, q=idx%FOUT;
  float acc=b_lin[q];
  for(int f=0;f<F2;++f) acc += FEAT[b*F2+f]*w_out[q*F2+f];
  out[idx]=acc;
}

extern "C" void kernel_launch(void* const* d_in, const int* in_sizes, int n_in,
                              void* d_out, int out_size, void* d_ws, size_t ws_size,
                              hipStream_t stream) {
  const float* x    =(const float*)d_in[0];
  const float* k1   =(const float*)d_in[1];
  const float* bias1=(const float*)d_in[2];
  const float* k2   =(const float*)d_in[3];
  const float* bias2=(const float*)d_in[4];
  const float* w_out=(const float*)d_in[5];
  const float* b_lin=(const float*)d_in[6];
  float* out=(float*)d_out;

  char* ws=(char*)d_ws;
  float*  A1   =(float* )(ws+0);        //  6000 f
  float*  D1SJ =(float* )(ws+24000);    //  26600 f
  float*  W3H  =(float* )(ws+130400);   //  2920 f
  float*  D2SJ =(float* )(ws+142080);   //  3432 f
  float*  D3_2 =(float* )(ws+155808);   //  858 f (+pad)
  float*  D3_1 =(float* )(ws+159248);   //  300 f
  float*  WINT =(float* )(ws+160448);   //  12 f
  float2* E60  =(float2*)(ws+160496);   //  60 c
  float2* E20  =(float2*)(ws+160976);   //  20 c
  float2* E12  =(float2*)(ws+161136);   //  12 c (+pad)
  unsigned* zLUT=(unsigned*)(ws+161248);//  1330 u32 (+pad)
  unsigned* xh2LUT=(unsigned*)(ws+166576); // 146 u32
  unsigned* h2LUT =(unsigned*)(ws+167160); // 146 u32
  unsigned short* fhLUT=(unsigned short*)(ws+167744); // 146 u16 (+pad)
  float2* XHAT =(float2*)(ws+168048);   //  [b][100] c
  float2* K1H  =(float2*)(ws+270448);   //  [o][100] c
  float2* KA   =(float2*)(ws+286448);   //  153600 c (1.2MB)
  float2* XH2  =(float2*)(ws+1515248);  //  [b][286][20] c
  float2* K2H  =(float2*)(ws+7372528);  //  [o][286][20] c
  float*  FEAT =(float* )(ws+9202928);  //  128*40 f -> 9223408 total

  (void)in_sizes; (void)n_in; (void)out_size; (void)ws_size;

  gen_all<<<168,256,0,stream>>>(A1,D1SJ,W3H,D2SJ,D3_2,D3_1,WINT,E60,E20,E12,
                                zLUT,xh2LUT,h2LUT,fhLUT);
  front_k<<<736,256,0,stream>>>(x,k1,k2,E60,A1,D3_1,XHAT,K1H,KA);
  dim3 g1(BATCH,F1);
  fused1<<<g1,256,0,stream>>>(XHAT,K1H,D1SJ,W3H,E20,bias1,zLUT,xh2LUT,fhLUT,XH2);
  k2h_k<<<(NH2*F1*F2+255)/256,256,0,stream>>>(KA,D3_2,h2LUT,xh2LUT,K2H);
  dim3 g2(BATCH,F2);
  fused2<<<g2,256,0,stream>>>(XH2,K2H,D2SJ,WINT,E12,bias2,h2LUT,xh2LUT,FEAT);
  head_k<<<(BATCH*FOUT+255)/256,256,0,stream>>>(FEAT,w_out,b_lin,out);
}

// Round 9
// 257.753 us; speedup vs baseline: 1.3925x; 1.1241x over previous
//
#include <hip/hip_runtime.h>
#include <math.h>

#define PI_D 3.14159265358979323846

#define BATCH 128
#define F1 20
#define F2 40
#define FOUT 10
#define NS1 100   // sum_{l<10} (2l+1)
#define NS2 286   // sum_{l<6} (2l+1)^2
#define NH2 146   // Hermitian half count of NS2

typedef float v2f __attribute__((ext_vector_type(2)));
#define PKFMA(a,b,c) __builtin_elementwise_fma((a),(b),(c))
#define SW(v) __builtin_shufflevector((v),(v),1,0)
static __device__ __forceinline__ v2f bc2(float s){ return (v2f){s,s}; }
static __device__ __forceinline__ v2f ldv(const float2* p){ return *(const v2f*)p; }

__constant__ int ZB10c[11] = {0,1,10,35,84,165,286,455,680,969,1330};
__constant__ int B2OFFc[7] = {0,1,10,35,84,165,286};
__constant__ int HOFFc[7]  = {0,1,6,19,44,85,146};
// E8c[q] = exp(-2*pi*i*q/8)
__constant__ float2 E8c[8] = {
  { 1.f, 0.f}, { 0.70710678118654752f,-0.70710678118654752f},
  { 0.f,-1.f}, {-0.70710678118654752f,-0.70710678118654752f},
  {-1.f, 0.f}, {-0.70710678118654752f, 0.70710678118654752f},
  { 0.f, 1.f}, { 0.70710678118654752f, 0.70710678118654752f}};

// wave-synchronous phase fence
#define WFENCE do{ __builtin_amdgcn_sched_barrier(0); \
  asm volatile("s_waitcnt lgkmcnt(0)" ::: "memory"); \
  __builtin_amdgcn_sched_barrier(0); }while(0)

// half-space H = { (m,n): n>0 } U { (m,n): n==0 && m>=0 }
__device__ inline void h_decode(int h, int& l, int& m, int& n){
  l=0; while(HOFFc[l+1]<=h) ++l;
  int r=h-HOFFc[l], L=2*l+1;
  if(r<l+1){ n=0; m=r; }
  else { int q=r-(l+1); n=q/L+1; m=q%L-l; }
}

// ---------------- double-precision table generation helpers ----------------
__device__ inline double ipow_d(double x, int n){ double r=1.0; for(int i=0;i<n;++i) r*=x; return r; }
__device__ inline double dfact(int n){ double r=1.0; for(int i=2;i<=n;++i) r*=(double)i; return r; }

__device__ double wigd(int l, int mp, int m, double beta){
  double cb=cos(0.5*beta), sb=sin(0.5*beta);
  double pref=sqrt(dfact(l+mp)*dfact(l-mp)*dfact(l+m)*dfact(l-m));
  int s0 = (m-mp>0) ? (m-mp) : 0;
  int s1 = (l+m < l-mp) ? (l+m) : (l-mp);
  double acc=0.0;
  for(int s=s0;s<=s1;++s){
    double den=dfact(l+m-s)*dfact(s)*dfact(mp-m+s)*dfact(l-mp-s);
    double t=ipow_d(cb,2*l+m-mp-2*s)*ipow_d(sb,mp-m+2*s)/den;
    acc += ((mp-m+s)&1)? -t : t;
  }
  return pref*acc;
}

__device__ double dhw(int b, int j){
  double beta=PI_D*(2*j+1)/(4.0*b);
  double s=0.0;
  for(int k=0;k<b;++k) s += sin((2*k+1)*beta)/(2*k+1);
  return (2.0/b)*sin(beta)*s;
}

__device__ inline float2 cmulc(float2 a, float2 b){ // a * conj(b)
  return make_float2(a.x*b.x + a.y*b.y, a.y*b.x - a.x*b.y);
}

// ---------------- single merged table-generation kernel ----------------
__global__ void gen_all(float* A1, float* D1SJ, float* W3H, float* D2SJ,
                        float* D3_2, float* D3_1, float* WINT,
                        float2* E60, float2* E20, float2* E12,
                        unsigned* zLUT, unsigned* xh2LUT, unsigned* h2LUT,
                        unsigned short* fhLUT){
  int blk=blockIdx.x, t=threadIdx.x;
  if(blk<24){                     // A1: [j][s1], 60x100
    int idx=blk*256+t; if(idx>=6000) return;
    int j=idx/NS1, s=idx%NS1;
    int l=0; while((l+1)*(l+1)<=s) ++l;
    int m=s-l*l-l;
    double beta=PI_D*(2*j+1)/120.0;
    A1[idx]=(float)(wigd(l,m,0,beta)*dhw(30,j)*(2.0*PI_D/60.0));
  } else if(blk<128){             // D1SJ: [j][1330]
    int idx=(blk-24)*256+t; if(idx>=26600) return;
    int j=idx/1330, s=idx%1330;
    int l=0; while(ZB10c[l+1]<=s) ++l;
    int r=s-ZB10c[l]; int L=2*l+1;
    int mi=r/L, ni=r%L;
    double beta=PI_D*(2*j+1)/40.0;
    D1SJ[idx]=(float)((2*l+1)*wigd(l,mi-l,ni-l,beta));
  } else if(blk<140){             // W3H: [j][146]
    int idx=(blk-128)*256+t; if(idx>=20*NH2) return;
    int j=idx/NH2, h=idx%NH2;
    int l,m,n; h_decode(h,l,m,n);
    double beta=PI_D*(2*j+1)/40.0;
    double c=2.0*PI_D/20.0;
    W3H[idx]=(float)(wigd(l,m,n,beta)*dhw(10,j)*c*c);
  } else if(blk<154){             // D2SJ: [j][286]
    int idx=(blk-140)*256+t; if(idx>=3432) return;
    int j=idx/286, s=idx%286;
    int l=0; while(B2OFFc[l+1]<=s) ++l;
    int r=s-B2OFFc[l]; int L=2*l+1;
    int mi=r/L, ni=r%L;
    double beta=PI_D*(2*j+1)/24.0;
    D2SJ[idx]=(float)((2*l+1)*wigd(l,mi-l,ni-l,beta));
  } else if(blk<158){             // D3_2: [bi][286]
    int idx=(blk-154)*256+t; if(idx>=3*286) return;
    int bi=idx/286, s=idx%286;
    int l=0; while(B2OFFc[l+1]<=s) ++l;
    int r=s-B2OFFc[l]; int L=2*l+1;
    int mi=r/L, ni=r%L;
    double beta=(bi+1)*(PI_D/8.0)/3.0;
    D3_2[idx]=(float)wigd(l,mi-l,ni-l,beta);
  } else if(blk<160){             // D3_1: [bi][100]
    int idx=(blk-158)*256+t; if(idx>=3*100) return;
    int bi=idx/100, s=idx%100;
    int l=0; while((l+1)*(l+1)<=s) ++l;
    int m=s-l*l-l;
    double beta=(bi+1)*(PI_D/8.0)/3.0;
    D3_1[idx]=(float)wigd(l,m,0,beta);
  } else if(blk==160){            // misc
    if(t<12){ double c=2.0*PI_D/12.0; WINT[t]=(float)(dhw(6,t)*c*c); }
    if(t<60){ double a=2.0*PI_D*t/60.0; E60[t]=make_float2((float)cos(a),(float)sin(a)); }
    if(t<20){ double a=2.0*PI_D*t/20.0; E20[t]=make_float2((float)cos(a),(float)sin(a)); }
    if(t<12){ double a=2.0*PI_D*t/12.0; E12[t]=make_float2((float)cos(a),(float)sin(a)); }
  } else if(blk<167){             // zLUT[1330]: packed s1x | s1k<<16
    int idx=(blk-161)*256+t; if(idx>=1330) return;
    int l=0; while(ZB10c[l+1]<=idx) ++l;
    int r=idx-ZB10c[l], L=2*l+1;
    int mi=r/L, ni=r%L;
    unsigned s1x=(unsigned)(l*l+mi), s1k=(unsigned)(l*l+ni);
    zLUT[idx]=s1x|(s1k<<16);
  } else {                        // blk==167: xh2LUT, h2LUT, fhLUT
    if(t<146){
      int l,m,n; h_decode(t,l,m,n);
      int L=2*l+1;
      int s2 =B2OFFc[l]+(m+l)*L+(n+l);
      int s2p=B2OFFc[l]+(l-m)*L+(l-n);
      unsigned sg=(unsigned)((m+n)&1);
      xh2LUT[t]=(unsigned)s2 | ((unsigned)s2p<<10) | (sg<<20);
      h2LUT[t]=(unsigned)l | ((unsigned)(m+l)<<4) | ((unsigned)(n+l)<<8) | ((unsigned)s2<<12);
      fhLUT[t]=(unsigned short)((n==0)? m : 6+(n-1)*11+(m+5));
    }
  }
}

// ---------------- front: per-b DFT+S2 analysis | k1h | KA (k2 gamma-DFT) ----------------
__global__ __launch_bounds__(256) void front_k(const float* __restrict__ x,
    const float* __restrict__ k1, const float* __restrict__ k2,
    const float2* __restrict__ E60, const float* __restrict__ A1,
    const float* __restrict__ D3_1,
    float2* __restrict__ XHAT, float2* __restrict__ K1H, float2* __restrict__ KA){
  __shared__ float2 E8s[8];
  int blk=blockIdx.x, t=threadIdx.x;
  if(blk<128){
    __shared__ float xs[3600];
    __shared__ float2 E60s[60];
    __shared__ float2 XFs[1140];     // [j][mi], mi = m+9
    if(t<60) E60s[t]=E60[t];
    {
      const float4* src=(const float4*)(x+blk*3600);
      float4* dst=(float4*)xs;
      for(int i=t;i<900;i+=256) dst[i]=src[i];
    }
    __syncthreads();
    for(int idx=t; idx<1140; idx+=256){
      int j=idx/19, mi=idx%19;
      int step=(mi<9)? mi+51 : mi-9;
      const float* xr=xs+j*60;
      float2 acc=make_float2(0.f,0.f);
      int k=0;
      for(int a=0;a<60;++a){
        float2 e=E60s[k]; float xv=xr[a];
        acc.x+=xv*e.x; acc.y-=xv*e.y;
        k+=step; if(k>=60)k-=60;
      }
      XFs[idx]=acc;
    }
    __syncthreads();
    for(int s=t; s<100; s+=256){
      int l=0; while((l+1)*(l+1)<=s) ++l;
      int m=s-l*l-l;
      const float2* xf=&XFs[m+9];
      float2 acc=make_float2(0.f,0.f);
      for(int j=0;j<60;++j){
        float a1=A1[j*NS1+s];
        float2 v=xf[j*19];
        acc.x+=a1*v.x; acc.y+=a1*v.y;
      }
      XHAT[blk*NS1+s]=acc;
    }
  } else if(blk<136){
    if(t<8) E8s[t]=E8c[t];
    __syncthreads();
    int idx=(blk-128)*256+t;
    if(idx<F1*NS1){
      int o=idx/NS1, s=idx%NS1;
      int l=0; while((l+1)*(l+1)<=s) ++l;
      int m=s-l*l-l;
      int mm=m&7;
      float2 acc=make_float2(0.f,0.f);
      for(int bi=0;bi<3;++bi){
        float2 sum=make_float2(0.f,0.f);
        int q=0;
        #pragma unroll
        for(int ai=0;ai<8;++ai){
          float kv=k1[o*24+bi*8+ai];
          float2 e=E8s[q];
          sum.x+=kv*e.x; sum.y+=kv*e.y;
          q=(q+mm)&7;
        }
        float dv=D3_1[bi*100+s];
        acc.x+=dv*sum.x; acc.y+=dv*sum.y;
      }
      const float SC1f = 0.06123724356957945f;
      K1H[idx]=make_float2(acc.x*SC1f, acc.y*SC1f);
    }
  } else {
    // KA[io*192 + bi*64 + q*8 + ai] = sum_gi k2[io*192+bi*64+ai*8+gi]*e8[(gi*q)&7]
    if(t<8) E8s[t]=E8c[t];
    __syncthreads();
    int idx=(blk-136)*256+t;
    if(idx<153600){
      int ai=idx&7, q=(idx>>3)&7;
      int r2=idx>>6;
      int bi=r2%3, io=r2/3;
      const float* kp=k2+(size_t)io*192+bi*64+ai*8;
      float2 acc=make_float2(0.f,0.f);
      int ph=0;
      #pragma unroll
      for(int gi=0;gi<8;++gi){
        float kv=kp[gi];
        float2 e=E8s[ph];
        acc.x+=kv*e.x; acc.y+=kv*e.y;
        ph=(ph+q)&7;
      }
      KA[(size_t)io*192+bi*64+q*8+ai]=acc;
    }
  }
}

// fused1: wave-per-j barrier-free pipeline, packed-fp32 math.
// XH2 layout: [b][s2][i]
__global__ __launch_bounds__(256,4) void fused1(
    const float2* __restrict__ XHAT, const float2* __restrict__ K1H,
    const float* __restrict__ D1SJ, const float* __restrict__ W3H,
    const float2* __restrict__ E20, const float* __restrict__ bias1,
    const unsigned* __restrict__ zLUT, const unsigned* __restrict__ xh2LUT,
    const unsigned short* __restrict__ fhLUT,
    float2* __restrict__ XH2){
  const int b=blockIdx.x, o=blockIdx.y, t=threadIdx.x;
  const int ln=t&63, w=t>>6;
  __shared__ __align__(16) float2 zS[1330];
  __shared__ __align__(16) float2 TWE2[400];  // [r][k] = e^{i r k th}, 20x20
  __shared__ __align__(16) float2 regA[4][200];
  __shared__ __align__(16) float2 regB[4][190];

  for(int idx=t; idx<400; idx+=256){
    int r=idx/20, c=idx%20;
    TWE2[idx]=E20[(r*c)%20];
  }
  for(int idx=t; idx<1330; idx+=256){
    unsigned u=zLUT[idx];
    v2f xa=ldv(&XHAT[b*NS1 + (u&0xffff)]);
    v2f kb=ldv(&K1H[o*NS1 + (u>>16)]);
    v2f p1=xa*kb, p2=xa*SW(kb);
    zS[idx]=make_float2(p1.x+p1.y, p2.y-p2.x);   // xa*conj(kb)
  }
  __syncthreads();

  const float bb1=bias1[o];
  float2* G  = regA[w];
  float*  vbF= (float*)regA[w];
  float2* Fq = regA[w];
  float*  RB = (float*)regB[w];   // Sx[0..180) Sy[180..360) T0[360..380)
  float*  Sx = RB;
  float*  Sy = RB+180;
  float*  T0f= RB+360;
  float2* U_T= regB[w];           // reuse after C
  v2f fa0={0.f,0.f}, fa1=fa0, fa2=fa0;

  // B-phase twiddle rows: n=c-9 -> row (c+11)%20
  const int BROW[19]={11,12,13,14,15,16,17,18,19,0,1,2,3,4,5,6,7,8,9};

  for(int jq=0;jq<5;++jq){
    const int j=jq*4+w;
    const float* Dg=D1SJ + j*1330;
    // A: Wigner-beta contraction, half-space (181 items)
    for(int idx=ln; idx<181; idx+=64){
      int m,n;
      if(idx<10){ m=0; n=idx; } else { int q=idx-10; m=q/19+1; n=q%19-9; }
      int an=n<0?-n:n;
      int l=m>an?m:an;
      int L=2*l+1;
      int zi=ZB10c[l]+(m+l)*L+(n+l);
      int m2=2*m+2;
      v2f a0={0.f,0.f};
      for(; l<10; ++l){
        a0=PKFMA(ldv(&zS[zi]), bc2(Dg[zi]), a0);
        zi += L*L + 2*L + m2; L += 2;
      }
      *(v2f*)&G[m*19+(n+9)]=a0;
    }
    WFENCE;
    // B: S_m(g quad) via split-accumulator dot trick (45 items) + T0 quads (5)
    if(ln<45){
      int mb=ln/5+1, g0=(ln%5)*4;
      const float2* Gr=&G[mb*19];
      v2f p10={0.f,0.f},p20=p10,p11=p10,p21=p10,p12=p10,p22=p10,p13=p10,p23=p10;
      #pragma unroll
      for(int c=0;c<19;++c){
        v2f gv=ldv(&Gr[c]);
        const float* er=(const float*)&TWE2[BROW[c]*20+g0];
        float4 e01=*(const float4*)er, e23=*(const float4*)(er+4);
        v2f e0={e01.x,e01.y}, e1={e01.z,e01.w}, e2={e23.x,e23.y}, e3={e23.z,e23.w};
        p10=PKFMA(gv,e0,p10); p20=PKFMA(gv,SW(e0),p20);
        p11=PKFMA(gv,e1,p11); p21=PKFMA(gv,SW(e1),p21);
        p12=PKFMA(gv,e2,p12); p22=PKFMA(gv,SW(e2),p22);
        p13=PKFMA(gv,e3,p13); p23=PKFMA(gv,SW(e3),p23);
      }
      int si=(mb-1)*20+g0;
      *(v2f*)&Sx[si]  =(v2f){2.f*(p10.x-p10.y), 2.f*(p11.x-p11.y)};
      *(v2f*)&Sx[si+2]=(v2f){2.f*(p12.x-p12.y), 2.f*(p13.x-p13.y)};
      *(v2f*)&Sy[si]  =(v2f){2.f*(p20.x+p20.y), 2.f*(p21.x+p21.y)};
      *(v2f*)&Sy[si+2]=(v2f){2.f*(p22.x+p22.y), 2.f*(p23.x+p23.y)};
    } else if(ln<50){
      int g0=(ln-45)*4;
      float r0=G[9].x, r1=r0, r2=r0, r3=r0;   // n=0 term
      #pragma unroll
      for(int n=1;n<10;++n){
        float2 gv=G[9+n];
        const float2* tw=&TWE2[n*20+g0];
        float2 e0=tw[0],e1=tw[1],e2=tw[2],e3=tw[3];
        r0+=2.f*(gv.x*e0.x-gv.y*e0.y);
        r1+=2.f*(gv.x*e1.x-gv.y*e1.y);
        r2+=2.f*(gv.x*e2.x-gv.y*e2.y);
        r3+=2.f*(gv.x*e3.x-gv.y*e3.y);
      }
      T0f[g0]=r0; T0f[g0+1]=r1; T0f[g0+2]=r2; T0f[g0+3]=r3;
    }
    WFENCE;
    // C: v(a,g)=T0+sum_m Re[S e^{ima}], bias, relu; packed over g-pairs (50 items)
    if(ln<50){
      int ap=ln/5, g0=(ln%5)*4;
      int a0=2*ap, a1=a0+1;
      v2f i01={T0f[g0]+bb1, T0f[g0+1]+bb1};
      v2f i23={T0f[g0+2]+bb1, T0f[g0+3]+bb1};
      v2f vA01=i01, vA23=i23, vB01=i01, vB23=i23;
      #pragma unroll
      for(int m=1;m<10;++m){
        float2 e0=TWE2[a0*20+m], e1=TWE2[a1*20+m];
        v2f sx01=*(const v2f*)&Sx[(m-1)*20+g0];
        v2f sx23=*(const v2f*)&Sx[(m-1)*20+g0+2];
        v2f sy01=*(const v2f*)&Sy[(m-1)*20+g0];
        v2f sy23=*(const v2f*)&Sy[(m-1)*20+g0+2];
        vA01=PKFMA(bc2(e0.x),sx01,vA01); vA01=PKFMA(bc2(-e0.y),sy01,vA01);
        vA23=PKFMA(bc2(e0.x),sx23,vA23); vA23=PKFMA(bc2(-e0.y),sy23,vA23);
        vB01=PKFMA(bc2(e1.x),sx01,vB01); vB01=PKFMA(bc2(-e1.y),sy01,vB01);
        vB23=PKFMA(bc2(e1.x),sx23,vB23); vB23=PKFMA(bc2(-e1.y),sy23,vB23);
      }
      v2f z2={0.f,0.f};
      *(v2f*)&vbF[a0*20+g0]  =__builtin_elementwise_max(vA01,z2);
      *(v2f*)&vbF[a0*20+g0+2]=__builtin_elementwise_max(vA23,z2);
      *(v2f*)&vbF[a1*20+g0]  =__builtin_elementwise_max(vB01,z2);
      *(v2f*)&vbF[a1*20+g0+2]=__builtin_elementwise_max(vB23,z2);
    }
    WFENCE;
    // D: U_T[nu][a]=sum_g v(a,g) e^{-i nu g}; 2-nu batch (60 items)
    if(ln<60){
      int a=ln/3, np=ln%3;
      int nu0=2*np, nu1=2*np+1;
      int r0=(np==0)?0:(20-2*np);
      int r1=19-2*np;
      const float* vp=&vbF[a*20];
      const float2* T0r=&TWE2[r0*20];
      const float2* T1r=&TWE2[r1*20];
      v2f u0={0.f,0.f}, u1=u0;
      #pragma unroll
      for(int g=0;g<20;++g){
        v2f xb=bc2(vp[g]);
        u0=PKFMA(xb, ldv(&T0r[g]), u0);
        u1=PKFMA(xb, ldv(&T1r[g]), u1);
      }
      *(v2f*)&U_T[nu0*20+a]=u0; *(v2f*)&U_T[nu1*20+a]=u1;
    }
    WFENCE;
    // E: Fq(mu,nu)=sum_a U_T[nu][a] e^{-i mu a}; dot trick (61 items)
    if(ln<61){
      int mu,nu;
      if(ln<6){ mu=ln; nu=0; } else { int q=ln-6; nu=q/11+1; mu=q%11-5; }
      int mm=(mu+20)%20;
      int rm=(20-mm)%20;
      const float2* Ur=&U_T[nu*20];
      const float2* Er=&TWE2[rm*20];
      v2f p1={0.f,0.f}, p2=p1;
      #pragma unroll
      for(int a=0;a<20;++a){
        v2f u=ldv(&Ur[a]), e=ldv(&Er[a]);
        p1=PKFMA(u,e,p1);
        p2=PKFMA(u,SW(e),p2);
      }
      Fq[ln]=make_float2(p1.x-p1.y, p2.x+p2.y);
    }
    WFENCE;
    // F: accumulate half-s2 with W3H into registers
    {
      const float* W3r=W3H + j*NH2;
      fa0=PKFMA(bc2(W3r[ln]),    ldv(&Fq[fhLUT[ln]]),    fa0);
      fa1=PKFMA(bc2(W3r[64+ln]), ldv(&Fq[fhLUT[64+ln]]), fa1);
      if(ln<18) fa2=PKFMA(bc2(W3r[128+ln]), ldv(&Fq[fhLUT[128+ln]]), fa2);
    }
    WFENCE;
  }
  // spill register accumulators, merge 4 waves, expand half->full by conjugation
  regB[w][ln]=make_float2(fa0.x,fa0.y);
  regB[w][64+ln]=make_float2(fa1.x,fa1.y);
  if(ln<18) regB[w][128+ln]=make_float2(fa2.x,fa2.y);
  __syncthreads();
  for(int h=t; h<146; h+=256){
    unsigned u=xh2LUT[h];
    int s2=u&1023, s2p=(u>>10)&1023;
    float sg=((u>>20)&1)? -1.f : 1.f;
    float2 a0=regB[0][h], a1=regB[1][h], a2=regB[2][h], a3=regB[3][h];
    float2 a=make_float2(a0.x+a1.x+a2.x+a3.x, a0.y+a1.y+a2.y+a3.y);
    XH2[(b*286+s2 )*F1+o]=a;
    XH2[(b*286+s2p)*F1+o]=make_float2(sg*a.x, -sg*a.y);
  }
}

// K2H: gather from KA (ai-DFT) + beta contraction; Hermitian half + conj fill
__global__ void k2h_k(const float2* __restrict__ KA, const float* __restrict__ D3_2,
                      const unsigned* __restrict__ h2LUT, const unsigned* __restrict__ xh2LUT,
                      float2* __restrict__ K2H){
  __shared__ float2 E8s[8];
  if(threadIdx.x<8) E8s[threadIdx.x]=E8c[threadIdx.x];
  __syncthreads();
  int idx=blockIdx.x*blockDim.x+threadIdx.x;
  if(idx>=NH2*F1*F2) return;
  int o=idx/(NH2*F1); int r=idx%(NH2*F1); int h=r/F1, i=r%F1;
  unsigned hu=h2LUT[h];
  int l=hu&15, mi=(hu>>4)&15, ni=(hu>>8)&15, s2=hu>>12;
  int m=mi-l, n=ni-l;
  unsigned xu=xh2LUT[h];
  int s2p=(xu>>10)&1023;
  float sg=((xu>>20)&1)? -1.f : 1.f;
  int q=n&7, p=(m-n)&7;
  const float2* kab=KA+(size_t)(i*F2+o)*192+q*8;
  float2 acc=make_float2(0.f,0.f);
  for(int bi=0;bi<3;++bi){
    const float2* kp=kab+bi*64;
    float2 s=make_float2(0.f,0.f);
    int ph=0;
    #pragma unroll
    for(int ai=0;ai<8;++ai){
      float2 ka=kp[ai], e=E8s[ph];
      s.x+=ka.x*e.x-ka.y*e.y; s.y+=ka.x*e.y+ka.y*e.x;
      ph=(ph+p)&7;
    }
    float dv=D3_2[bi*286+s2];
    acc.x+=dv*s.x; acc.y+=dv*s.y;
  }
  const float SC2f = 0.034722222222222224f;
  acc.x*=SC2f; acc.y*=SC2f;
  K2H[((size_t)o*286+s2)*F1+i]=acc;
  K2H[((size_t)o*286+s2p)*F1+i]=make_float2(sg*acc.x,-sg*acc.y);
}

// fused2: cooperative z2 build, then wave-per-3j single-pass synthesis+integrate
__global__ __launch_bounds__(256,3) void fused2(
    const float2* __restrict__ XH2, const float2* __restrict__ K2H,
    const float* __restrict__ D2SJ, const float* __restrict__ WINT,
    const float2* __restrict__ E12, const float* __restrict__ bias2,
    const unsigned* __restrict__ h2LUT, const unsigned* __restrict__ xh2LUT,
    float* __restrict__ FEAT){
  const int b=blockIdx.x, o=blockIdx.y, t=threadIdx.x;
  const int ln=t&63, w=t>>6;
  __shared__ __align__(16) float2 Xs[2420];
  __shared__ __align__(16) float2 Ks[2420];
  __shared__ float2 zpS[1144];
  __shared__ float2 z2S[286];
  __shared__ float  redS[256];
  float2* alias=(float2*)Xs;       // reused after z-build
  float2* TWE12=alias;             // [12][12]: e^{i r c th12}

  const int gb[4]={0,84,165,286};
  const int hb[4]={0,44,85,146};
  for(int grp=0; grp<3; ++grp){
    int row0=gb[grp], rows=gb[grp+1]-row0;
    {
      int cnt4=rows*10;
      const float4* xsrc=(const float4*)(XH2+(size_t)(b*286+row0)*F1);
      const float4* ksrc=(const float4*)(K2H+(size_t)(o*286+row0)*F1);
      float4* xd=(float4*)Xs; float4* kd=(float4*)Ks;
      for(int i=t;i<cnt4;i+=256){ xd[i]=xsrc[i]; kd[i]=ksrc[i]; }
    }
    __syncthreads();
    int nh=hb[grp+1]-hb[grp];
    for(int idx=t; idx<4*nh; idx+=256){
      int hl=idx>>2, iq=idx&3;
      int h=hb[grp]+hl;
      unsigned hu=h2LUT[h];
      int l=hu&15, mi=(hu>>4)&15, ni=(hu>>8)&15, s2=hu>>12;
      int L=2*l+1;
      int xr0=(B2OFFc[l]-row0)+mi*L;
      int kr0=(B2OFFc[l]-row0)+ni*L;
      v2f p1={0.f,0.f}, p2=p1;
      for(int k=0;k<L;++k){
        const float2* xp=Xs+(xr0+k)*F1+iq*5;
        const float2* kp=Ks+(kr0+k)*F1+iq*5;
        #pragma unroll
        for(int i=0;i<5;++i){
          v2f xa=ldv(&xp[i]), kb=ldv(&kp[i]);
          p1=PKFMA(xa,kb,p1);
          p2=PKFMA(xa,SW(kb),p2);
        }
      }
      zpS[iq*286+s2]=make_float2(p1.x+p1.y, p2.y-p2.x);
    }
    __syncthreads();
  }
  for(int idx=t; idx<146; idx+=256){
    unsigned xu=xh2LUT[idx];
    int s2=xu&1023, s2p=(xu>>10)&1023;
    float sg=((xu>>20)&1)? -1.f : 1.f;
    float2 a;
    a.x=zpS[0*286+s2].x+zpS[1*286+s2].x+zpS[2*286+s2].x+zpS[3*286+s2].x;
    a.y=zpS[0*286+s2].y+zpS[1*286+s2].y+zpS[2*286+s2].y+zpS[3*286+s2].y;
    z2S[s2]=a;
    z2S[s2p]=make_float2(sg*a.x,-sg*a.y);
  }
  __syncthreads();
  for(int idx=t; idx<144; idx+=256){
    int r=idx/12, c=idx%12;
    TWE12[idx]=E12[(r*c)%12];
  }
  __syncthreads();

  float2* base2=alias+144+w*400;
  float2* G2_0=base2; float2* G2_1=base2+66; float2* G2_2=base2+132;
  float*  SP=(float*)(base2+198);
  float*  S2x0=SP, *S2x1=SP+60, *S2x2=SP+120;
  float*  S2y0=SP+180, *S2y1=SP+240, *S2y2=SP+300;
  float*  T02=SP+360;               // [3][12]
  float personal=0.f;
  const float b2v=bias2[o];
  const int j0=3*w, j1=3*w+1, j2=3*w+2;
  const float* Dg0=D2SJ + j0*286;
  const float* Dg1=D2SJ + j1*286;
  const float* Dg2=D2SJ + j2*286;
  const int BR12[11]={7,8,9,10,11,0,1,2,3,4,5};

  // A2: 61 half items, 3 j's
  if(ln<61){
    int m,n;
    if(ln<6){m=0;n=ln;} else {int qq=ln-6;m=qq/11+1;n=qq%11-5;}
    int an=n<0?-n:n; int l=m>an?m:an; int L=2*l+1;
    int zi=B2OFFc[l]+(m+l)*L+(n+l); int m2=2*m+2;
    v2f a0={0.f,0.f}, a1=a0, a2=a0;
    for(;l<6;++l){
      v2f zv=ldv(&z2S[zi]);
      a0=PKFMA(zv, bc2(Dg0[zi]), a0);
      a1=PKFMA(zv, bc2(Dg1[zi]), a1);
      a2=PKFMA(zv, bc2(Dg2[zi]), a2);
      zi+=L*L+2*L+m2; L+=2;
    }
    int gi=m*11+(n+5);
    *(v2f*)&G2_0[gi]=a0; *(v2f*)&G2_1[gi]=a1; *(v2f*)&G2_2[gi]=a2;
  }
  WFENCE;
  // B2: 42 items (30 S-pairs + 12 T0), 3 j's, dot trick
  if(ln<30){
    int m=ln/6+1, g=(ln%6)*2;
    v2f p10={0.f,0.f},p20=p10,p11=p10,p21=p10;
    v2f q10=p10,q20=p10,q11=p10,q21=p10;
    v2f r10=p10,r20=p10,r11=p10,r21=p10;
    #pragma unroll
    for(int c=0;c<11;++c){
      float4 eq=*(const float4*)&TWE12[BR12[c]*12+g];
      v2f e0={eq.x,eq.y}, e1={eq.z,eq.w};
      v2f g0=ldv(&G2_0[m*11+c]), g1=ldv(&G2_1[m*11+c]), g2=ldv(&G2_2[m*11+c]);
      p10=PKFMA(g0,e0,p10); p20=PKFMA(g0,SW(e0),p20);
      p11=PKFMA(g0,e1,p11); p21=PKFMA(g0,SW(e1),p21);
      q10=PKFMA(g1,e0,q10); q20=PKFMA(g1,SW(e0),q20);
      q11=PKFMA(g1,e1,q11); q21=PKFMA(g1,SW(e1),q21);
      r10=PKFMA(g2,e0,r10); r20=PKFMA(g2,SW(e0),r20);
      r11=PKFMA(g2,e1,r11); r21=PKFMA(g2,SW(e1),r21);
    }
    int si=(m-1)*12+g;
    S2x0[si]=2.f*(p10.x-p10.y); S2x0[si+1]=2.f*(p11.x-p11.y);
    S2y0[si]=2.f*(p20.x+p20.y); S2y0[si+1]=2.f*(p21.x+p21.y);
    S2x1[si]=2.f*(q10.x-q10.y); S2x1[si+1]=2.f*(q11.x-q11.y);
    S2y1[si]=2.f*(q20.x+q20.y); S2y1[si+1]=2.f*(q21.x+q21.y);
    S2x2[si]=2.f*(r10.x-r10.y); S2x2[si+1]=2.f*(r11.x-r11.y);
    S2y2[si]=2.f*(r20.x+r20.y); S2y2[si+1]=2.f*(r21.x+r21.y);
  } else if(ln<42){
    int g=ln-30;
    float r0=G2_0[5].x, r1=G2_1[5].x, r2=G2_2[5].x;
    #pragma unroll
    for(int n=1;n<6;++n){
      float2 e=TWE12[n*12+g];
      float2 g0=G2_0[5+n], g1=G2_1[5+n], g2=G2_2[5+n];
      r0+=2.f*(g0.x*e.x-g0.y*e.y);
      r1+=2.f*(g1.x*e.x-g1.y*e.y);
      r2+=2.f*(g2.x*e.x-g2.y*e.y);
    }
    T02[g]=r0; T02[12+g]=r1; T02[24+g]=r2;
  }
  WFENCE;
  // C2: 36 items, packed g-pairs, fused relu+integrate, 3 j's
  if(ln<36){
    float w0=WINT[j0], w1=WINT[j1], w2=WINT[j2];
    int a=ln/3, g4=(ln%3)*4;
    v2f iA0={T02[g4]+b2v, T02[g4+1]+b2v},       iB0={T02[g4+2]+b2v, T02[g4+3]+b2v};
    v2f iA1={T02[12+g4]+b2v, T02[12+g4+1]+b2v}, iB1={T02[12+g4+2]+b2v, T02[12+g4+3]+b2v};
    v2f iA2={T02[24+g4]+b2v, T02[24+g4+1]+b2v}, iB2={T02[24+g4+2]+b2v, T02[24+g4+3]+b2v};
    #pragma unroll
    for(int m=1;m<6;++m){
      float2 e=TWE12[a*12+m];
      v2f ex=bc2(e.x), eny=bc2(-e.y);
      int si=(m-1)*12+g4;
      v2f sx, sy;
      sx=*(const v2f*)&S2x0[si];   sy=*(const v2f*)&S2y0[si];
      iA0=PKFMA(ex,sx,iA0); iA0=PKFMA(eny,sy,iA0);
      sx=*(const v2f*)&S2x0[si+2]; sy=*(const v2f*)&S2y0[si+2];
      iB0=PKFMA(ex,sx,iB0); iB0=PKFMA(eny,sy,iB0);
      sx=*(const v2f*)&S2x1[si];   sy=*(const v2f*)&S2y1[si];
      iA1=PKFMA(ex,sx,iA1); iA1=PKFMA(eny,sy,iA1);
      sx=*(const v2f*)&S2x1[si+2]; sy=*(const v2f*)&S2y1[si+2];
      iB1=PKFMA(ex,sx,iB1); iB1=PKFMA(eny,sy,iB1);
      sx=*(const v2f*)&S2x2[si];   sy=*(const v2f*)&S2y2[si];
      iA2=PKFMA(ex,sx,iA2); iA2=PKFMA(eny,sy,iA2);
      sx=*(const v2f*)&S2x2[si+2]; sy=*(const v2f*)&S2y2[si+2];
      iB2=PKFMA(ex,sx,iB2); iB2=PKFMA(eny,sy,iB2);
    }
    v2f z2={0.f,0.f};
    v2f rA0=__builtin_elementwise_max(iA0,z2), rB0=__builtin_elementwise_max(iB0,z2);
    v2f rA1=__builtin_elementwise_max(iA1,z2), rB1=__builtin_elementwise_max(iB1,z2);
    v2f rA2=__builtin_elementwise_max(iA2,z2), rB2=__builtin_elementwise_max(iB2,z2);
    personal += w0*(rA0.x+rA0.y+rB0.x+rB0.y)
              + w1*(rA1.x+rA1.y+rB1.x+rB1.y)
              + w2*(rA2.x+rA2.y+rB2.x+rB2.y);
  }
  redS[t]=personal;
  __syncthreads();
  for(int s=128;s>0;s>>=1){
    if(t<s) redS[t]+=redS[t+s];
    __syncthreads();
  }
  if(t==0) FEAT[b*F2+o]=redS[0];
}

__global__ void head_k(const float* __restrict__ FEAT, const float* __restrict__ w_out,
                       const float* __restrict__ b_lin, float* __restrict__ out){
  int idx=blockIdx.x*blockDim.x+threadIdx.x;
  if(idx>=BATCH*FOUT) return;
  int b=idx/FOUT, q=idx%FOUT;
  float acc=b_lin[q];
  for(int f=0;f<F2;++f) acc += FEAT[b*F2+f]*w_out[q*F2+f];
  out[idx]=acc;
}

extern "C" void kernel_launch(void* const* d_in, const int* in_sizes, int n_in,
                              void* d_out, int out_size, void* d_ws, size_t ws_size,
                              hipStream_t stream) {
  const float* x    =(const float*)d_in[0];
  const float* k1   =(const float*)d_in[1];
  const float* bias1=(const float*)d_in[2];
  const float* k2   =(const float*)d_in[3];
  const float* bias2=(const float*)d_in[4];
  const float* w_out=(const float*)d_in[5];
  const float* b_lin=(const float*)d_in[6];
  float* out=(float*)d_out;

  char* ws=(char*)d_ws;
  float*  A1   =(float* )(ws+0);        //  6000 f
  float*  D1SJ =(float* )(ws+24000);    //  26600 f
  float*  W3H  =(float* )(ws+130400);   //  2920 f
  float*  D2SJ =(float* )(ws+142080);   //  3432 f
  float*  D3_2 =(float* )(ws+155808);   //  858 f (+pad)
  float*  D3_1 =(float* )(ws+159248);   //  300 f
  float*  WINT =(float* )(ws+160448);   //  12 f
  float2* E60  =(float2*)(ws+160496);   //  60 c
  float2* E20  =(float2*)(ws+160976);   //  20 c
  float2* E12  =(float2*)(ws+161136);   //  12 c (+pad)
  unsigned* zLUT=(unsigned*)(ws+161248);//  1330 u32 (+pad)
  unsigned* xh2LUT=(unsigned*)(ws+166576); // 146 u32
  unsigned* h2LUT =(unsigned*)(ws+167160); // 146 u32
  unsigned short* fhLUT=(unsigned short*)(ws+167744); // 146 u16 (+pad)
  float2* XHAT =(float2*)(ws+168048);   //  [b][100] c
  float2* K1H  =(float2*)(ws+270448);   //  [o][100] c
  float2* KA   =(float2*)(ws+286448);   //  153600 c (1.2MB)
  float2* XH2  =(float2*)(ws+1515248);  //  [b][286][20] c
  float2* K2H  =(float2*)(ws+7372528);  //  [o][286][20] c
  float*  FEAT =(float* )(ws+9202928);  //  128*40 f -> 9223408 total

  (void)in_sizes; (void)n_in; (void)out_size; (void)ws_size;

  gen_all<<<168,256,0,stream>>>(A1,D1SJ,W3H,D2SJ,D3_2,D3_1,WINT,E60,E20,E12,
                                zLUT,xh2LUT,h2LUT,fhLUT);
  front_k<<<736,256,0,stream>>>(x,k1,k2,E60,A1,D3_1,XHAT,K1H,KA);
  dim3 g1(BATCH,F1);
  fused1<<<g1,256,0,stream>>>(XHAT,K1H,D1SJ,W3H,E20,bias1,zLUT,xh2LUT,fhLUT,XH2);
  k2h_k<<<(NH2*F1*F2+255)/256,256,0,stream>>>(KA,D3_2,h2LUT,xh2LUT,K2H);
  dim3 g2(BATCH,F2);
  fused2<<<g2,256,0,stream>>>(XH2,K2H,D2SJ,WINT,E12,bias2,h2LUT,xh2LUT,FEAT);
  head_k<<<(BATCH*FOUT+255)/256,256,0,stream>>>(FEAT,w_out,b_lin,out);
}

// Round 10
// 238.796 us; speedup vs baseline: 1.5030x; 1.0794x over previous
//
#include <hip/hip_runtime.h>
#include <math.h>

#define PI_D 3.14159265358979323846

#define BATCH 128
#define F1 20
#define F2 40
#define FOUT 10
#define NS1 100   // sum_{l<10} (2l+1)
#define NS2 286   // sum_{l<6} (2l+1)^2
#define NH2 146   // Hermitian half count of NS2

typedef float v2f __attribute__((ext_vector_type(2)));
#define PKFMA(a,b,c) __builtin_elementwise_fma((a),(b),(c))
#define SW(v) __builtin_shufflevector((v),(v),1,0)
static __device__ __forceinline__ v2f bc2(float s){ return (v2f){s,s}; }
static __device__ __forceinline__ v2f ldv(const float2* p){ return *(const v2f*)p; }

// async global->LDS, 16B per lane; lds arg must be wave-uniform base
#define GLOAD_LDS16(g,l) __builtin_amdgcn_global_load_lds( \
  (const __attribute__((address_space(1))) void*)(g), \
  (__attribute__((address_space(3))) void*)(l), 16, 0, 0)

__constant__ int ZB10c[11] = {0,1,10,35,84,165,286,455,680,969,1330};
__constant__ int B2OFFc[7] = {0,1,10,35,84,165,286};
__constant__ int HOFFc[7]  = {0,1,6,19,44,85,146};
// E8c[q] = exp(-2*pi*i*q/8)
__constant__ float2 E8c[8] = {
  { 1.f, 0.f}, { 0.70710678118654752f,-0.70710678118654752f},
  { 0.f,-1.f}, {-0.70710678118654752f,-0.70710678118654752f},
  {-1.f, 0.f}, {-0.70710678118654752f, 0.70710678118654752f},
  { 0.f, 1.f}, { 0.70710678118654752f, 0.70710678118654752f}};

// wave-synchronous phase fence
#define WFENCE do{ __builtin_amdgcn_sched_barrier(0); \
  asm volatile("s_waitcnt lgkmcnt(0)" ::: "memory"); \
  __builtin_amdgcn_sched_barrier(0); }while(0)

// half-space H = { (m,n): n>0 } U { (m,n): n==0 && m>=0 }
__device__ inline void h_decode(int h, int& l, int& m, int& n){
  l=0; while(HOFFc[l+1]<=h) ++l;
  int r=h-HOFFc[l], L=2*l+1;
  if(r<l+1){ n=0; m=r; }
  else { int q=r-(l+1); n=q/L+1; m=q%L-l; }
}

// ---------------- double-precision table generation helpers ----------------
__device__ inline double ipow_d(double x, int n){ double r=1.0; for(int i=0;i<n;++i) r*=x; return r; }
__device__ inline double dfact(int n){ double r=1.0; for(int i=2;i<=n;++i) r*=(double)i; return r; }

__device__ double wigd(int l, int mp, int m, double beta){
  double cb=cos(0.5*beta), sb=sin(0.5*beta);
  double pref=sqrt(dfact(l+mp)*dfact(l-mp)*dfact(l+m)*dfact(l-m));
  int s0 = (m-mp>0) ? (m-mp) : 0;
  int s1 = (l+m < l-mp) ? (l+m) : (l-mp);
  double acc=0.0;
  for(int s=s0;s<=s1;++s){
    double den=dfact(l+m-s)*dfact(s)*dfact(mp-m+s)*dfact(l-mp-s);
    double t=ipow_d(cb,2*l+m-mp-2*s)*ipow_d(sb,mp-m+2*s)/den;
    acc += ((mp-m+s)&1)? -t : t;
  }
  return pref*acc;
}

__device__ double dhw(int b, int j){
  double beta=PI_D*(2*j+1)/(4.0*b);
  double s=0.0;
  for(int k=0;k<b;++k) s += sin((2*k+1)*beta)/(2*k+1);
  return (2.0/b)*sin(beta)*s;
}

__device__ inline float2 cmulc(float2 a, float2 b){ // a * conj(b)
  return make_float2(a.x*b.x + a.y*b.y, a.y*b.x - a.x*b.y);
}

// ---------------- single merged table-generation kernel ----------------
// beta->pi-beta symmetry: d^l_{m',m}(pi-b) = (-1)^{l+m} d^l_{-m',m}(b)
// (derived by s-substitution in the reference wigd sum) halves D1SJ/W3H/D2SJ work.
__global__ void gen_all(float* A1, float* D1SJ, float* W3H, float* D2SJ,
                        float* D3_2, float* D3_1, float* WINT,
                        float2* E60, float2* E20, float2* E12,
                        unsigned* zLUT, unsigned* xh2LUT, unsigned* h2LUT,
                        unsigned short* fhLUT){
  int blk=blockIdx.x, t=threadIdx.x;
  if(blk<24){                     // A1: [j][s1], 60x100
    int idx=blk*256+t; if(idx>=6000) return;
    int j=idx/NS1, s=idx%NS1;
    int l=0; while((l+1)*(l+1)<=s) ++l;
    int m=s-l*l-l;
    double beta=PI_D*(2*j+1)/120.0;
    A1[idx]=(float)(wigd(l,m,0,beta)*dhw(30,j)*(2.0*PI_D/60.0));
  } else if(blk<76){              // D1SJ: j=0..9 computed, 19-j derived
    int idx=(blk-24)*256+t; if(idx>=13300) return;
    int j=idx/1330, s=idx%1330;
    int l=0; while(ZB10c[l+1]<=s) ++l;
    int r=s-ZB10c[l]; int L=2*l+1;
    int mi=r/L, ni=r%L;
    double beta=PI_D*(2*j+1)/40.0;
    float v=(float)((2*l+1)*wigd(l,mi-l,ni-l,beta));
    D1SJ[j*1330+s]=v;
    int s2=ZB10c[l]+(2*l-mi)*L+ni;
    D1SJ[(19-j)*1330+s2]=(ni&1)? -v : v;
  } else if(blk<82){              // W3H: j=0..9 computed, 19-j derived
    int idx=(blk-76)*256+t; if(idx>=10*NH2) return;
    int j=idx/NH2, h=idx%NH2;
    int l,m,n; h_decode(h,l,m,n);
    double beta=PI_D*(2*j+1)/40.0;
    double c=2.0*PI_D/20.0;
    float v=(float)(wigd(l,m,n,beta)*dhw(10,j)*c*c);
    W3H[j*NH2+h]=v;
    if(n==0){
      W3H[(19-j)*NH2+h]=((l+m)&1)? -v : v;
    } else {
      int L=2*l+1;
      int hp=HOFFc[l]+(l+1)+(n-1)*L+(l-m);   // (m,n) -> (-m,n)
      W3H[(19-j)*NH2+hp]=((l+n)&1)? -v : v;
    }
  } else if(blk<89){              // D2SJ: j=0..5 computed, 11-j derived
    int idx=(blk-82)*256+t; if(idx>=1716) return;
    int j=idx/286, s=idx%286;
    int l=0; while(B2OFFc[l+1]<=s) ++l;
    int r=s-B2OFFc[l]; int L=2*l+1;
    int mi=r/L, ni=r%L;
    double beta=PI_D*(2*j+1)/24.0;
    float v=(float)((2*l+1)*wigd(l,mi-l,ni-l,beta));
    D2SJ[j*286+s]=v;
    int s2=B2OFFc[l]+(2*l-mi)*L+ni;
    D2SJ[(11-j)*286+s2]=(ni&1)? -v : v;
  } else if(blk<93){              // D3_2: [bi][286]
    int idx=(blk-89)*256+t; if(idx>=3*286) return;
    int bi=idx/286, s=idx%286;
    int l=0; while(B2OFFc[l+1]<=s) ++l;
    int r=s-B2OFFc[l]; int L=2*l+1;
    int mi=r/L, ni=r%L;
    double beta=(bi+1)*(PI_D/8.0)/3.0;
    D3_2[idx]=(float)wigd(l,mi-l,ni-l,beta);
  } else if(blk<95){              // D3_1: [bi][100]
    int idx=(blk-93)*256+t; if(idx>=3*100) return;
    int bi=idx/100, s=idx%100;
    int l=0; while((l+1)*(l+1)<=s) ++l;
    int m=s-l*l-l;
    double beta=(bi+1)*(PI_D/8.0)/3.0;
    D3_1[idx]=(float)wigd(l,m,0,beta);
  } else if(blk==95){             // misc
    if(t<12){ double c=2.0*PI_D/12.0; WINT[t]=(float)(dhw(6,t)*c*c); }
    if(t<60){ double a=2.0*PI_D*t/60.0; E60[t]=make_float2((float)cos(a),(float)sin(a)); }
    if(t<20){ double a=2.0*PI_D*t/20.0; E20[t]=make_float2((float)cos(a),(float)sin(a)); }
    if(t<12){ double a=2.0*PI_D*t/12.0; E12[t]=make_float2((float)cos(a),(float)sin(a)); }
  } else if(blk<102){             // zLUT[1330]: packed s1x | s1k<<16
    int idx=(blk-96)*256+t; if(idx>=1330) return;
    int l=0; while(ZB10c[l+1]<=idx) ++l;
    int r=idx-ZB10c[l], L=2*l+1;
    int mi=r/L, ni=r%L;
    unsigned s1x=(unsigned)(l*l+mi), s1k=(unsigned)(l*l+ni);
    zLUT[idx]=s1x|(s1k<<16);
  } else {                        // blk==102: xh2LUT, h2LUT, fhLUT
    if(t<146){
      int l,m,n; h_decode(t,l,m,n);
      int L=2*l+1;
      int s2 =B2OFFc[l]+(m+l)*L+(n+l);
      int s2p=B2OFFc[l]+(l-m)*L+(l-n);
      unsigned sg=(unsigned)((m+n)&1);
      xh2LUT[t]=(unsigned)s2 | ((unsigned)s2p<<10) | (sg<<20);
      h2LUT[t]=(unsigned)l | ((unsigned)(m+l)<<4) | ((unsigned)(n+l)<<8) | ((unsigned)s2<<12);
      fhLUT[t]=(unsigned short)((n==0)? m : 6+(n-1)*11+(m+5));
    }
  }
}

// ---------------- front: per-b DFT+S2 analysis | k1h | KA (k2 gamma-DFT) ----------------
__global__ __launch_bounds__(256) void front_k(const float* __restrict__ x,
    const float* __restrict__ k1, const float* __restrict__ k2,
    const float2* __restrict__ E60, const float* __restrict__ A1,
    const float* __restrict__ D3_1,
    float2* __restrict__ XHAT, float2* __restrict__ K1H, float2* __restrict__ KA){
  __shared__ float2 E8s[8];
  int blk=blockIdx.x, t=threadIdx.x;
  if(blk<128){
    __shared__ __align__(16) float xs[3600];
    __shared__ float2 E60s[60];      // conjugated twiddles
    __shared__ float2 XFs[1140];     // [j][mi], mi = m+9
    if(t<60){ float2 e=E60[t]; E60s[t]=make_float2(e.x,-e.y); }
    {
      const float4* src=(const float4*)(x+blk*3600);
      float4* dst=(float4*)xs;
      for(int i=t;i<900;i+=256) GLOAD_LDS16(src+i, dst+(i&~63));
    }
    __syncthreads();
    for(int idx=t; idx<1140; idx+=256){
      int j=idx/19, mi=idx%19;
      int step=(mi<9)? mi+51 : mi-9;
      const float* xr=xs+j*60;
      v2f acc={0.f,0.f};
      int k=0;
      for(int a=0;a<60;++a){
        acc=PKFMA(bc2(xr[a]), ldv(&E60s[k]), acc);
        k+=step; if(k>=60)k-=60;
      }
      XFs[idx]=make_float2(acc.x,acc.y);
    }
    __syncthreads();
    for(int s=t; s<100; s+=256){
      int l=0; while((l+1)*(l+1)<=s) ++l;
      int m=s-l*l-l;
      const float2* xf=&XFs[m+9];
      v2f acc={0.f,0.f};
      for(int j=0;j<60;++j){
        acc=PKFMA(bc2(A1[j*NS1+s]), ldv(&xf[j*19]), acc);
      }
      XHAT[blk*NS1+s]=make_float2(acc.x,acc.y);
    }
  } else if(blk<136){
    if(t<8) E8s[t]=E8c[t];
    __syncthreads();
    int idx=(blk-128)*256+t;
    if(idx<F1*NS1){
      int o=idx/NS1, s=idx%NS1;
      int l=0; while((l+1)*(l+1)<=s) ++l;
      int m=s-l*l-l;
      int mm=m&7;
      v2f acc={0.f,0.f};
      for(int bi=0;bi<3;++bi){
        v2f sum={0.f,0.f};
        int q=0;
        #pragma unroll
        for(int ai=0;ai<8;++ai){
          sum=PKFMA(bc2(k1[o*24+bi*8+ai]), ldv(&E8s[q]), sum);
          q=(q+mm)&7;
        }
        acc=PKFMA(bc2(D3_1[bi*100+s]), sum, acc);
      }
      const float SC1f = 0.06123724356957945f;
      K1H[idx]=make_float2(acc.x*SC1f, acc.y*SC1f);
    }
  } else {
    // KA[io*192 + bi*64 + q*8 + ai] = sum_gi k2[io*192+bi*64+ai*8+gi]*e8[(gi*q)&7]
    if(t<8) E8s[t]=E8c[t];
    __syncthreads();
    int idx=(blk-136)*256+t;
    if(idx<153600){
      int ai=idx&7, q=(idx>>3)&7;
      int r2=idx>>6;
      int bi=r2%3, io=r2/3;
      const float* kp=k2+(size_t)io*192+bi*64+ai*8;
      v2f acc={0.f,0.f};
      int ph=0;
      #pragma unroll
      for(int gi=0;gi<8;++gi){
        acc=PKFMA(bc2(kp[gi]), ldv(&E8s[ph]), acc);
        ph=(ph+q)&7;
      }
      KA[(size_t)io*192+bi*64+q*8+ai]=make_float2(acc.x,acc.y);
    }
  }
}

// fused1: wave-per-j barrier-free pipeline, packed-fp32 math.
// XH2 layout: [b][s2][i]
__global__ __launch_bounds__(256,6) void fused1(
    const float2* __restrict__ XHAT, const float2* __restrict__ K1H,
    const float* __restrict__ D1SJ, const float* __restrict__ W3H,
    const float2* __restrict__ E20, const float* __restrict__ bias1,
    const unsigned* __restrict__ zLUT, const unsigned* __restrict__ xh2LUT,
    const unsigned short* __restrict__ fhLUT,
    float2* __restrict__ XH2){
  const int b=blockIdx.x, o=blockIdx.y, t=threadIdx.x;
  const int ln=t&63, w=t>>6;
  __shared__ __align__(16) float2 zS[1330];
  __shared__ __align__(16) float2 TWE2[400];  // [r][k] = e^{i r k th}, 20x20
  __shared__ __align__(16) float2 regA[4][200];
  __shared__ __align__(16) float2 regB[4][190];

  for(int idx=t; idx<400; idx+=256){
    int r=idx/20, c=idx%20;
    TWE2[idx]=E20[(r*c)%20];
  }
  for(int idx=t; idx<1330; idx+=256){
    unsigned u=zLUT[idx];
    v2f xa=ldv(&XHAT[b*NS1 + (u&0xffff)]);
    v2f kb=ldv(&K1H[o*NS1 + (u>>16)]);
    v2f p1=xa*kb, p2=xa*SW(kb);
    zS[idx]=make_float2(p1.x+p1.y, p2.y-p2.x);   // xa*conj(kb)
  }
  __syncthreads();

  const float bb1=bias1[o];
  float2* G  = regA[w];
  float*  vbF= (float*)regA[w];
  float2* Fq = regA[w];
  float*  RB = (float*)regB[w];   // Sx[0..180) Sy[180..360) T0[360..380)
  float*  Sx = RB;
  float*  Sy = RB+180;
  float*  T0f= RB+360;
  float2* U_T= regB[w];           // reuse after C
  v2f fa0={0.f,0.f}, fa1=fa0, fa2=fa0;

  // B-phase twiddle rows: n=c-9 -> row (c+11)%20
  const int BROW[19]={11,12,13,14,15,16,17,18,19,0,1,2,3,4,5,6,7,8,9};

  for(int jq=0;jq<5;++jq){
    const int j=jq*4+w;
    const float* Dg=D1SJ + j*1330;
    // A: Wigner-beta contraction, half-space (181 items)
    for(int idx=ln; idx<181; idx+=64){
      int m,n;
      if(idx<10){ m=0; n=idx; } else { int q=idx-10; m=q/19+1; n=q%19-9; }
      int an=n<0?-n:n;
      int l=m>an?m:an;
      int L=2*l+1;
      int zi=ZB10c[l]+(m+l)*L+(n+l);
      int m2=2*m+2;
      v2f a0={0.f,0.f};
      for(; l<10; ++l){
        a0=PKFMA(ldv(&zS[zi]), bc2(Dg[zi]), a0);
        zi += L*L + 2*L + m2; L += 2;
      }
      *(v2f*)&G[m*19+(n+9)]=a0;
    }
    WFENCE;
    // B: S_m(g quad) via split-accumulator dot trick (45 items) + T0 quads (5)
    if(ln<45){
      int mb=ln/5+1, g0=(ln%5)*4;
      const float2* Gr=&G[mb*19];
      v2f p10={0.f,0.f},p20=p10,p11=p10,p21=p10,p12=p10,p22=p10,p13=p10,p23=p10;
      #pragma unroll
      for(int c=0;c<19;++c){
        v2f gv=ldv(&Gr[c]);
        const float* er=(const float*)&TWE2[BROW[c]*20+g0];
        float4 e01=*(const float4*)er, e23=*(const float4*)(er+4);
        v2f e0={e01.x,e01.y}, e1={e01.z,e01.w}, e2={e23.x,e23.y}, e3={e23.z,e23.w};
        p10=PKFMA(gv,e0,p10); p20=PKFMA(gv,SW(e0),p20);
        p11=PKFMA(gv,e1,p11); p21=PKFMA(gv,SW(e1),p21);
        p12=PKFMA(gv,e2,p12); p22=PKFMA(gv,SW(e2),p22);
        p13=PKFMA(gv,e3,p13); p23=PKFMA(gv,SW(e3),p23);
      }
      int si=(mb-1)*20+g0;
      *(v2f*)&Sx[si]  =(v2f){2.f*(p10.x-p10.y), 2.f*(p11.x-p11.y)};
      *(v2f*)&Sx[si+2]=(v2f){2.f*(p12.x-p12.y), 2.f*(p13.x-p13.y)};
      *(v2f*)&Sy[si]  =(v2f){2.f*(p20.x+p20.y), 2.f*(p21.x+p21.y)};
      *(v2f*)&Sy[si+2]=(v2f){2.f*(p22.x+p22.y), 2.f*(p23.x+p23.y)};
    } else if(ln<50){
      int g0=(ln-45)*4;
      float r0=G[9].x, r1=r0, r2=r0, r3=r0;   // n=0 term
      #pragma unroll
      for(int n=1;n<10;++n){
        float2 gv=G[9+n];
        const float2* tw=&TWE2[n*20+g0];
        float2 e0=tw[0],e1=tw[1],e2=tw[2],e3=tw[3];
        r0+=2.f*(gv.x*e0.x-gv.y*e0.y);
        r1+=2.f*(gv.x*e1.x-gv.y*e1.y);
        r2+=2.f*(gv.x*e2.x-gv.y*e2.y);
        r3+=2.f*(gv.x*e3.x-gv.y*e3.y);
      }
      T0f[g0]=r0; T0f[g0+1]=r1; T0f[g0+2]=r2; T0f[g0+3]=r3;
    }
    WFENCE;
    // C: v(a,g)=T0+sum_m Re[S e^{ima}], bias, relu; packed over g-pairs (50 items)
    if(ln<50){
      int ap=ln/5, g0=(ln%5)*4;
      int a0=2*ap, a1=a0+1;
      v2f i01={T0f[g0]+bb1, T0f[g0+1]+bb1};
      v2f i23={T0f[g0+2]+bb1, T0f[g0+3]+bb1};
      v2f vA01=i01, vA23=i23, vB01=i01, vB23=i23;
      #pragma unroll
      for(int m=1;m<10;++m){
        float2 e0=TWE2[a0*20+m], e1=TWE2[a1*20+m];
        v2f sx01=*(const v2f*)&Sx[(m-1)*20+g0];
        v2f sx23=*(const v2f*)&Sx[(m-1)*20+g0+2];
        v2f sy01=*(const v2f*)&Sy[(m-1)*20+g0];
        v2f sy23=*(const v2f*)&Sy[(m-1)*20+g0+2];
        vA01=PKFMA(bc2(e0.x),sx01,vA01); vA01=PKFMA(bc2(-e0.y),sy01,vA01);
        vA23=PKFMA(bc2(e0.x),sx23,vA23); vA23=PKFMA(bc2(-e0.y),sy23,vA23);
        vB01=PKFMA(bc2(e1.x),sx01,vB01); vB01=PKFMA(bc2(-e1.y),sy01,vB01);
        vB23=PKFMA(bc2(e1.x),sx23,vB23); vB23=PKFMA(bc2(-e1.y),sy23,vB23);
      }
      v2f z2={0.f,0.f};
      *(v2f*)&vbF[a0*20+g0]  =__builtin_elementwise_max(vA01,z2);
      *(v2f*)&vbF[a0*20+g0+2]=__builtin_elementwise_max(vA23,z2);
      *(v2f*)&vbF[a1*20+g0]  =__builtin_elementwise_max(vB01,z2);
      *(v2f*)&vbF[a1*20+g0+2]=__builtin_elementwise_max(vB23,z2);
    }
    WFENCE;
    // D: U_T[nu][a]=sum_g v(a,g) e^{-i nu g}; 2-nu batch (60 items)
    if(ln<60){
      int a=ln/3, np=ln%3;
      int nu0=2*np, nu1=2*np+1;
      int r0=(np==0)?0:(20-2*np);
      int r1=19-2*np;
      const float* vp=&vbF[a*20];
      const float2* T0r=&TWE2[r0*20];
      const float2* T1r=&TWE2[r1*20];
      v2f u0={0.f,0.f}, u1=u0;
      #pragma unroll
      for(int g=0;g<20;++g){
        v2f xb=bc2(vp[g]);
        u0=PKFMA(xb, ldv(&T0r[g]), u0);
        u1=PKFMA(xb, ldv(&T1r[g]), u1);
      }
      *(v2f*)&U_T[nu0*20+a]=u0; *(v2f*)&U_T[nu1*20+a]=u1;
    }
    WFENCE;
    // E: Fq(mu,nu)=sum_a U_T[nu][a] e^{-i mu a}; dot trick (61 items)
    if(ln<61){
      int mu,nu;
      if(ln<6){ mu=ln; nu=0; } else { int q=ln-6; nu=q/11+1; mu=q%11-5; }
      int mm=(mu+20)%20;
      int rm=(20-mm)%20;
      const float2* Ur=&U_T[nu*20];
      const float2* Er=&TWE2[rm*20];
      v2f p1={0.f,0.f}, p2=p1;
      #pragma unroll
      for(int a=0;a<20;++a){
        v2f u=ldv(&Ur[a]), e=ldv(&Er[a]);
        p1=PKFMA(u,e,p1);
        p2=PKFMA(u,SW(e),p2);
      }
      Fq[ln]=make_float2(p1.x-p1.y, p2.x+p2.y);
    }
    WFENCE;
    // F: accumulate half-s2 with W3H into registers
    {
      const float* W3r=W3H + j*NH2;
      fa0=PKFMA(bc2(W3r[ln]),    ldv(&Fq[fhLUT[ln]]),    fa0);
      fa1=PKFMA(bc2(W3r[64+ln]), ldv(&Fq[fhLUT[64+ln]]), fa1);
      if(ln<18) fa2=PKFMA(bc2(W3r[128+ln]), ldv(&Fq[fhLUT[128+ln]]), fa2);
    }
    WFENCE;
  }
  // spill register accumulators, merge 4 waves, expand half->full by conjugation
  regB[w][ln]=make_float2(fa0.x,fa0.y);
  regB[w][64+ln]=make_float2(fa1.x,fa1.y);
  if(ln<18) regB[w][128+ln]=make_float2(fa2.x,fa2.y);
  __syncthreads();
  for(int h=t; h<146; h+=256){
    unsigned u=xh2LUT[h];
    int s2=u&1023, s2p=(u>>10)&1023;
    float sg=((u>>20)&1)? -1.f : 1.f;
    float2 a0=regB[0][h], a1=regB[1][h], a2=regB[2][h], a3=regB[3][h];
    float2 a=make_float2(a0.x+a1.x+a2.x+a3.x, a0.y+a1.y+a2.y+a3.y);
    XH2[(b*286+s2 )*F1+o]=a;
    XH2[(b*286+s2p)*F1+o]=make_float2(sg*a.x, -sg*a.y);
  }
}

// K2H: block per (i,o); KA row staged to LDS once; 146 h-threads consume.
__global__ __launch_bounds__(192) void k2h_k(const float2* __restrict__ KA,
                      const float* __restrict__ D3_2,
                      const unsigned* __restrict__ h2LUT, const unsigned* __restrict__ xh2LUT,
                      float2* __restrict__ K2H){
  __shared__ float2 kaS[192];
  __shared__ float2 E8s[8];
  int io=blockIdx.x, t=threadIdx.x;
  int i=io/F2, o=io%F2;
  if(t<8) E8s[t]=E8c[t];
  kaS[t]=KA[(size_t)io*192+t];
  __syncthreads();
  if(t>=146) return;
  unsigned hu=h2LUT[t];
  int l=hu&15, mi=(hu>>4)&15, ni=(hu>>8)&15, s2=hu>>12;
  int m=mi-l, n=ni-l;
  unsigned xu=xh2LUT[t];
  int s2p=(xu>>10)&1023;
  float sg=((xu>>20)&1)? -1.f : 1.f;
  int q=n&7, p=(m-n)&7;
  v2f a1={0.f,0.f}, a2=a1;
  for(int bi=0;bi<3;++bi){
    const float2* kp=&kaS[bi*64+q*8];
    v2f s1={0.f,0.f}, s2v=s1;
    int ph=0;
    #pragma unroll
    for(int ai=0;ai<8;++ai){
      v2f ka=ldv(&kp[ai]), e=ldv(&E8s[ph]);
      s1=PKFMA(ka,e,s1); s2v=PKFMA(ka,SW(e),s2v);
      ph=(ph+p)&7;
    }
    v2f dv=bc2(D3_2[bi*286+s2]);
    a1=PKFMA(dv,s1,a1); a2=PKFMA(dv,s2v,a2);
  }
  const float SC2f = 0.034722222222222224f;
  float re=(a1.x-a1.y)*SC2f, im=(a2.x+a2.y)*SC2f;
  K2H[((size_t)o*286+s2)*F1+i]=make_float2(re,im);
  K2H[((size_t)o*286+s2p)*F1+i]=make_float2(sg*re,-sg*im);
}

// fused2: cooperative z2 build, then wave-per-3j single-pass synthesis+integrate
__global__ __launch_bounds__(256,3) void fused2(
    const float2* __restrict__ XH2, const float2* __restrict__ K2H,
    const float* __restrict__ D2SJ, const float* __restrict__ WINT,
    const float2* __restrict__ E12, const float* __restrict__ bias2,
    const unsigned* __restrict__ h2LUT, const unsigned* __restrict__ xh2LUT,
    float* __restrict__ FEAT){
  const int b=blockIdx.x, o=blockIdx.y, t=threadIdx.x;
  const int ln=t&63, w=t>>6;
  __shared__ __align__(16) float2 Xs[2420];
  __shared__ __align__(16) float2 Ks[2420];
  __shared__ float2 zpS[1144];
  __shared__ float2 z2S[286];
  __shared__ float  redS[256];
  float2* alias=(float2*)Xs;       // reused after z-build
  float2* TWE12=alias;             // [12][12]: e^{i r c th12}

  const int gb[4]={0,84,165,286};
  const int hb[4]={0,44,85,146};
  for(int grp=0; grp<3; ++grp){
    int row0=gb[grp], rows=gb[grp+1]-row0;
    {
      int cnt4=rows*10;
      const float4* xsrc=(const float4*)(XH2+(size_t)(b*286+row0)*F1);
      const float4* ksrc=(const float4*)(K2H+(size_t)(o*286+row0)*F1);
      float4* xd=(float4*)Xs; float4* kd=(float4*)Ks;
      for(int i4=t;i4<cnt4;i4+=256){
        int wb=i4&~63;
        GLOAD_LDS16(xsrc+i4, xd+wb);
        GLOAD_LDS16(ksrc+i4, kd+wb);
      }
    }
    __syncthreads();
    int nh=hb[grp+1]-hb[grp];
    for(int idx=t; idx<4*nh; idx+=256){
      int hl=idx>>2, iq=idx&3;
      int h=hb[grp]+hl;
      unsigned hu=h2LUT[h];
      int l=hu&15, mi=(hu>>4)&15, ni=(hu>>8)&15, s2=hu>>12;
      int L=2*l+1;
      int xr0=(B2OFFc[l]-row0)+mi*L;
      int kr0=(B2OFFc[l]-row0)+ni*L;
      v2f p1={0.f,0.f}, p2=p1;
      for(int k=0;k<L;++k){
        const float2* xp=Xs+(xr0+k)*F1+iq*5;
        const float2* kp=Ks+(kr0+k)*F1+iq*5;
        #pragma unroll
        for(int i=0;i<5;++i){
          v2f xa=ldv(&xp[i]), kb=ldv(&kp[i]);
          p1=PKFMA(xa,kb,p1);
          p2=PKFMA(xa,SW(kb),p2);
        }
      }
      zpS[iq*286+s2]=make_float2(p1.x+p1.y, p2.y-p2.x);
    }
    __syncthreads();
  }
  for(int idx=t; idx<146; idx+=256){
    unsigned xu=xh2LUT[idx];
    int s2=xu&1023, s2p=(xu>>10)&1023;
    float sg=((xu>>20)&1)? -1.f : 1.f;
    float2 a;
    a.x=zpS[0*286+s2].x+zpS[1*286+s2].x+zpS[2*286+s2].x+zpS[3*286+s2].x;
    a.y=zpS[0*286+s2].y+zpS[1*286+s2].y+zpS[2*286+s2].y+zpS[3*286+s2].y;
    z2S[s2]=a;
    z2S[s2p]=make_float2(sg*a.x,-sg*a.y);
  }
  __syncthreads();
  for(int idx=t; idx<144; idx+=256){
    int r=idx/12, c=idx%12;
    TWE12[idx]=E12[(r*c)%12];
  }
  __syncthreads();

  float2* base2=alias+144+w*400;
  float2* G2_0=base2; float2* G2_1=base2+66; float2* G2_2=base2+132;
  float*  SP=(float*)(base2+198);
  float*  S2x0=SP, *S2x1=SP+60, *S2x2=SP+120;
  float*  S2y0=SP+180, *S2y1=SP+240, *S2y2=SP+300;
  float*  T02=SP+360;               // [3][12]
  float personal=0.f;
  const float b2v=bias2[o];
  const int j0=3*w, j1=3*w+1, j2=3*w+2;
  const float* Dg0=D2SJ + j0*286;
  const float* Dg1=D2SJ + j1*286;
  const float* Dg2=D2SJ + j2*286;
  const int BR12[11]={7,8,9,10,11,0,1,2,3,4,5};

  // A2: 61 half items, 3 j's
  if(ln<61){
    int m,n;
    if(ln<6){m=0;n=ln;} else {int qq=ln-6;m=qq/11+1;n=qq%11-5;}
    int an=n<0?-n:n; int l=m>an?m:an; int L=2*l+1;
    int zi=B2OFFc[l]+(m+l)*L+(n+l); int m2=2*m+2;
    v2f a0={0.f,0.f}, a1=a0, a2=a0;
    for(;l<6;++l){
      v2f zv=ldv(&z2S[zi]);
      a0=PKFMA(zv, bc2(Dg0[zi]), a0);
      a1=PKFMA(zv, bc2(Dg1[zi]), a1);
      a2=PKFMA(zv, bc2(Dg2[zi]), a2);
      zi+=L*L+2*L+m2; L+=2;
    }
    int gi=m*11+(n+5);
    *(v2f*)&G2_0[gi]=a0; *(v2f*)&G2_1[gi]=a1; *(v2f*)&G2_2[gi]=a2;
  }
  WFENCE;
  // B2: 42 items (30 S-pairs + 12 T0), 3 j's, dot trick
  if(ln<30){
    int m=ln/6+1, g=(ln%6)*2;
    v2f p10={0.f,0.f},p20=p10,p11=p10,p21=p10;
    v2f q10=p10,q20=p10,q11=p10,q21=p10;
    v2f r10=p10,r20=p10,r11=p10,r21=p10;
    #pragma unroll
    for(int c=0;c<11;++c){
      float4 eq=*(const float4*)&TWE12[BR12[c]*12+g];
      v2f e0={eq.x,eq.y}, e1={eq.z,eq.w};
      v2f g0=ldv(&G2_0[m*11+c]), g1=ldv(&G2_1[m*11+c]), g2=ldv(&G2_2[m*11+c]);
      p10=PKFMA(g0,e0,p10); p20=PKFMA(g0,SW(e0),p20);
      p11=PKFMA(g0,e1,p11); p21=PKFMA(g0,SW(e1),p21);
      q10=PKFMA(g1,e0,q10); q20=PKFMA(g1,SW(e0),q20);
      q11=PKFMA(g1,e1,q11); q21=PKFMA(g1,SW(e1),q21);
      r10=PKFMA(g2,e0,r10); r20=PKFMA(g2,SW(e0),r20);
      r11=PKFMA(g2,e1,r11); r21=PKFMA(g2,SW(e1),r21);
    }
    int si=(m-1)*12+g;
    S2x0[si]=2.f*(p10.x-p10.y); S2x0[si+1]=2.f*(p11.x-p11.y);
    S2y0[si]=2.f*(p20.x+p20.y); S2y0[si+1]=2.f*(p21.x+p21.y);
    S2x1[si]=2.f*(q10.x-q10.y); S2x1[si+1]=2.f*(q11.x-q11.y);
    S2y1[si]=2.f*(q20.x+q20.y); S2y1[si+1]=2.f*(q21.x+q21.y);
    S2x2[si]=2.f*(r10.x-r10.y); S2x2[si+1]=2.f*(r11.x-r11.y);
    S2y2[si]=2.f*(r20.x+r20.y); S2y2[si+1]=2.f*(r21.x+r21.y);
  } else if(ln<42){
    int g=ln-30;
    float r0=G2_0[5].x, r1=G2_1[5].x, r2=G2_2[5].x;
    #pragma unroll
    for(int n=1;n<6;++n){
      float2 e=TWE12[n*12+g];
      float2 g0=G2_0[5+n], g1=G2_1[5+n], g2=G2_2[5+n];
      r0+=2.f*(g0.x*e.x-g0.y*e.y);
      r1+=2.f*(g1.x*e.x-g1.y*e.y);
      r2+=2.f*(g2.x*e.x-g2.y*e.y);
    }
    T02[g]=r0; T02[12+g]=r1; T02[24+g]=r2;
  }
  WFENCE;
  // C2: 36 items, packed g-pairs, fused relu+integrate, 3 j's
  if(ln<36){
    float w0=WINT[j0], w1=WINT[j1], w2=WINT[j2];
    int a=ln/3, g4=(ln%3)*4;
    v2f iA0={T02[g4]+b2v, T02[g4+1]+b2v},       iB0={T02[g4+2]+b2v, T02[g4+3]+b2v};
    v2f iA1={T02[12+g4]+b2v, T02[12+g4+1]+b2v}, iB1={T02[12+g4+2]+b2v, T02[12+g4+3]+b2v};
    v2f iA2={T02[24+g4]+b2v, T02[24+g4+1]+b2v}, iB2={T02[24+g4+2]+b2v, T02[24+g4+3]+b2v};
    #pragma unroll
    for(int m=1;m<6;++m){
      float2 e=TWE12[a*12+m];
      v2f ex=bc2(e.x), eny=bc2(-e.y);
      int si=(m-1)*12+g4;
      v2f sx, sy;
      sx=*(const v2f*)&S2x0[si];   sy=*(const v2f*)&S2y0[si];
      iA0=PKFMA(ex,sx,iA0); iA0=PKFMA(eny,sy,iA0);
      sx=*(const v2f*)&S2x0[si+2]; sy=*(const v2f*)&S2y0[si+2];
      iB0=PKFMA(ex,sx,iB0); iB0=PKFMA(eny,sy,iB0);
      sx=*(const v2f*)&S2x1[si];   sy=*(const v2f*)&S2y1[si];
      iA1=PKFMA(ex,sx,iA1); iA1=PKFMA(eny,sy,iA1);
      sx=*(const v2f*)&S2x1[si+2]; sy=*(const v2f*)&S2y1[si+2];
      iB1=PKFMA(ex,sx,iB1); iB1=PKFMA(eny,sy,iB1);
      sx=*(const v2f*)&S2x2[si];   sy=*(const v2f*)&S2y2[si];
      iA2=PKFMA(ex,sx,iA2); iA2=PKFMA(eny,sy,iA2);
      sx=*(const v2f*)&S2x2[si+2]; sy=*(const v2f*)&S2y2[si+2];
      iB2=PKFMA(ex,sx,iB2); iB2=PKFMA(eny,sy,iB2);
    }
    v2f z2={0.f,0.f};
    v2f rA0=__builtin_elementwise_max(iA0,z2), rB0=__builtin_elementwise_max(iB0,z2);
    v2f rA1=__builtin_elementwise_max(iA1,z2), rB1=__builtin_elementwise_max(iB1,z2);
    v2f rA2=__builtin_elementwise_max(iA2,z2), rB2=__builtin_elementwise_max(iB2,z2);
    personal += w0*(rA0.x+rA0.y+rB0.x+rB0.y)
              + w1*(rA1.x+rA1.y+rB1.x+rB1.y)
              + w2*(rA2.x+rA2.y+rB2.x+rB2.y);
  }
  redS[t]=personal;
  __syncthreads();
  for(int s=128;s>0;s>>=1){
    if(t<s) redS[t]+=redS[t+s];
    __syncthreads();
  }
  if(t==0) FEAT[b*F2+o]=redS[0];
}

__global__ void head_k(const float* __restrict__ FEAT, const float* __restrict__ w_out,
                       const float* __restrict__ b_lin, float* __restrict__ out){
  int idx=blockIdx.x*blockDim.x+threadIdx.x;
  if(idx>=BATCH*FOUT) return;
  int b=idx/FOUT, q=idx%FOUT;
  float acc=b_lin[q];
  for(int f=0;f<F2;++f) acc += FEAT[b*F2+f]*w_out[q*F2+f];
  out[idx]=acc;
}

extern "C" void kernel_launch(void* const* d_in, const int* in_sizes, int n_in,
                              void* d_out, int out_size, void* d_ws, size_t ws_size,
                              hipStream_t stream) {
  const float* x    =(const float*)d_in[0];
  const float* k1   =(const float*)d_in[1];
  const float* bias1=(const float*)d_in[2];
  const float* k2   =(const float*)d_in[3];
  const float* bias2=(const float*)d_in[4];
  const float* w_out=(const float*)d_in[5];
  const float* b_lin=(const float*)d_in[6];
  float* out=(float*)d_out;

  char* ws=(char*)d_ws;
  float*  A1   =(float* )(ws+0);        //  6000 f
  float*  D1SJ =(float* )(ws+24000);    //  26600 f
  float*  W3H  =(float* )(ws+130400);   //  2920 f
  float*  D2SJ =(float* )(ws+142080);   //  3432 f
  float*  D3_2 =(float* )(ws+155808);   //  858 f (+pad)
  float*  D3_1 =(float* )(ws+159248);   //  300 f
  float*  WINT =(float* )(ws+160448);   //  12 f
  float2* E60  =(float2*)(ws+160496);   //  60 c
  float2* E20  =(float2*)(ws+160976);   //  20 c
  float2* E12  =(float2*)(ws+161136);   //  12 c (+pad)
  unsigned* zLUT=(unsigned*)(ws+161248);//  1330 u32 (+pad)
  unsigned* xh2LUT=(unsigned*)(ws+166576); // 146 u32
  unsigned* h2LUT =(unsigned*)(ws+167160); // 146 u32
  unsigned short* fhLUT=(unsigned short*)(ws+167744); // 146 u16 (+pad)
  float2* XHAT =(float2*)(ws+168048);   //  [b][100] c
  float2* K1H  =(float2*)(ws+270448);   //  [o][100] c
  float2* KA   =(float2*)(ws+286448);   //  153600 c (1.2MB)
  float2* XH2  =(float2*)(ws+1515248);  //  [b][286][20] c
  float2* K2H  =(float2*)(ws+7372528);  //  [o][286][20] c
  float*  FEAT =(float* )(ws+9202928);  //  128*40 f -> 9223408 total

  (void)in_sizes; (void)n_in; (void)out_size; (void)ws_size;

  gen_all<<<103,256,0,stream>>>(A1,D1SJ,W3H,D2SJ,D3_2,D3_1,WINT,E60,E20,E12,
                                zLUT,xh2LUT,h2LUT,fhLUT);
  front_k<<<736,256,0,stream>>>(x,k1,k2,E60,A1,D3_1,XHAT,K1H,KA);
  dim3 g1(BATCH,F1);
  fused1<<<g1,256,0,stream>>>(XHAT,K1H,D1SJ,W3H,E20,bias1,zLUT,xh2LUT,fhLUT,XH2);
  k2h_k<<<F1*F2,192,0,stream>>>(KA,D3_2,h2LUT,xh2LUT,K2H);
  dim3 g2(BATCH,F2);
  fused2<<<g2,256,0,stream>>>(XH2,K2H,D2SJ,WINT,E12,bias2,h2LUT,xh2LUT,FEAT);
  head_k<<<(BATCH*FOUT+255)/256,256,0,stream>>>(FEAT,w_out,b_lin,out);
}

// Round 11
// 233.356 us; speedup vs baseline: 1.5381x; 1.0233x over previous
//
#include <hip/hip_runtime.h>
#include <math.h>

#define PI_D 3.14159265358979323846

#define BATCH 128
#define F1 20
#define F2 40
#define FOUT 10
#define NS1 100   // sum_{l<10} (2l+1)
#define NS2 286   // sum_{l<6} (2l+1)^2
#define NH2 146   // Hermitian half count of NS2

typedef float v2f __attribute__((ext_vector_type(2)));
#define PKFMA(a,b,c) __builtin_elementwise_fma((a),(b),(c))
#define SW(v) __builtin_shufflevector((v),(v),1,0)
static __device__ __forceinline__ v2f bc2(float s){ return (v2f){s,s}; }
static __device__ __forceinline__ v2f ldv(const float2* p){ return *(const v2f*)p; }

// async global->LDS, 16B per lane; lds arg must be wave-uniform base
#define GLOAD_LDS16(g,l) __builtin_amdgcn_global_load_lds( \
  (const __attribute__((address_space(1))) void*)(g), \
  (__attribute__((address_space(3))) void*)(l), 16, 0, 0)

__constant__ int ZB10c[11] = {0,1,10,35,84,165,286,455,680,969,1330};
__constant__ int B2OFFc[7] = {0,1,10,35,84,165,286};
__constant__ int HOFFc[7]  = {0,1,6,19,44,85,146};
// E8c[q] = exp(-2*pi*i*q/8)
__constant__ float2 E8c[8] = {
  { 1.f, 0.f}, { 0.70710678118654752f,-0.70710678118654752f},
  { 0.f,-1.f}, {-0.70710678118654752f,-0.70710678118654752f},
  {-1.f, 0.f}, {-0.70710678118654752f, 0.70710678118654752f},
  { 0.f, 1.f}, { 0.70710678118654752f, 0.70710678118654752f}};

// wave-synchronous phase fence
#define WFENCE do{ __builtin_amdgcn_sched_barrier(0); \
  asm volatile("s_waitcnt lgkmcnt(0)" ::: "memory"); \
  __builtin_amdgcn_sched_barrier(0); }while(0)

// half-space H = { (m,n): n>0 } U { (m,n): n==0 && m>=0 }
__device__ inline void h_decode(int h, int& l, int& m, int& n){
  l=0; while(HOFFc[l+1]<=h) ++l;
  int r=h-HOFFc[l], L=2*l+1;
  if(r<l+1){ n=0; m=r; }
  else { int q=r-(l+1); n=q/L+1; m=q%L-l; }
}

// ---------------- double-precision table generation helpers ----------------
__device__ inline double ipow_d(double x, int n){ double r=1.0; for(int i=0;i<n;++i) r*=x; return r; }
__device__ inline double dfact(int n){ double r=1.0; for(int i=2;i<=n;++i) r*=(double)i; return r; }

__device__ double wigd(int l, int mp, int m, double beta){
  double cb=cos(0.5*beta), sb=sin(0.5*beta);
  double pref=sqrt(dfact(l+mp)*dfact(l-mp)*dfact(l+m)*dfact(l-m));
  int s0 = (m-mp>0) ? (m-mp) : 0;
  int s1 = (l+m < l-mp) ? (l+m) : (l-mp);
  double acc=0.0;
  for(int s=s0;s<=s1;++s){
    double den=dfact(l+m-s)*dfact(s)*dfact(mp-m+s)*dfact(l-mp-s);
    double t=ipow_d(cb,2*l+m-mp-2*s)*ipow_d(sb,mp-m+2*s)/den;
    acc += ((mp-m+s)&1)? -t : t;
  }
  return pref*acc;
}

__device__ double dhw(int b, int j){
  double beta=PI_D*(2*j+1)/(4.0*b);
  double s=0.0;
  for(int k=0;k<b;++k) s += sin((2*k+1)*beta)/(2*k+1);
  return (2.0/b)*sin(beta)*s;
}

__device__ inline float2 cmulc(float2 a, float2 b){ // a * conj(b)
  return make_float2(a.x*b.x + a.y*b.y, a.y*b.x - a.x*b.y);
}

// ---------------- single merged table-generation kernel ----------------
// beta->pi-beta symmetry: d^l_{m',m}(pi-b) = (-1)^{l+m} d^l_{-m',m}(b)
// halves D1SJ/W3H/D2SJ work; dhw hoisted to per-block LDS table.
__global__ void gen_all(float* A1, float* D1SJ, float* W3H, float* D2SJ,
                        float* D3_2, float* D3_1, float* WINT,
                        float2* E60, float2* E20, float2* E12,
                        unsigned* zLUT, unsigned* xh2LUT, unsigned* h2LUT,
                        unsigned short* fhLUT, unsigned* aLUT){
  __shared__ double dhwS[60];
  int blk=blockIdx.x, t=threadIdx.x;
  if(blk<24){                     // A1: [j][s1], 60x100
    if(t<60) dhwS[t]=dhw(30,t);
    __syncthreads();
    int idx=blk*256+t;
    if(idx<6000){
      int j=idx/NS1, s=idx%NS1;
      int l=0; while((l+1)*(l+1)<=s) ++l;
      int m=s-l*l-l;
      double beta=PI_D*(2*j+1)/120.0;
      A1[idx]=(float)(wigd(l,m,0,beta)*dhwS[j]*(2.0*PI_D/60.0));
    }
  } else if(blk<76){              // D1SJ: j=0..9 computed, 19-j derived
    int idx=(blk-24)*256+t; if(idx>=13300) return;
    int j=idx/1330, s=idx%1330;
    int l=0; while(ZB10c[l+1]<=s) ++l;
    int r=s-ZB10c[l]; int L=2*l+1;
    int mi=r/L, ni=r%L;
    double beta=PI_D*(2*j+1)/40.0;
    float v=(float)((2*l+1)*wigd(l,mi-l,ni-l,beta));
    D1SJ[j*1330+s]=v;
    int s2=ZB10c[l]+(2*l-mi)*L+ni;
    D1SJ[(19-j)*1330+s2]=(ni&1)? -v : v;
  } else if(blk<82){              // W3H: j=0..9 computed, 19-j derived
    if(t<20) dhwS[t]=dhw(10,t);
    __syncthreads();
    int idx=(blk-76)*256+t;
    if(idx<10*NH2){
      int j=idx/NH2, h=idx%NH2;
      int l,m,n; h_decode(h,l,m,n);
      double beta=PI_D*(2*j+1)/40.0;
      double c=2.0*PI_D/20.0;
      float v=(float)(wigd(l,m,n,beta)*dhwS[j]*c*c);
      W3H[j*NH2+h]=v;
      if(n==0){
        W3H[(19-j)*NH2+h]=((l+m)&1)? -v : v;
      } else {
        int L=2*l+1;
        int hp=HOFFc[l]+(l+1)+(n-1)*L+(l-m);   // (m,n) -> (-m,n)
        W3H[(19-j)*NH2+hp]=((l+n)&1)? -v : v;
      }
    }
  } else if(blk<89){              // D2SJ: j=0..5 computed, 11-j derived
    int idx=(blk-82)*256+t; if(idx>=1716) return;
    int j=idx/286, s=idx%286;
    int l=0; while(B2OFFc[l+1]<=s) ++l;
    int r=s-B2OFFc[l]; int L=2*l+1;
    int mi=r/L, ni=r%L;
    double beta=PI_D*(2*j+1)/24.0;
    float v=(float)((2*l+1)*wigd(l,mi-l,ni-l,beta));
    D2SJ[j*286+s]=v;
    int s2=B2OFFc[l]+(2*l-mi)*L+ni;
    D2SJ[(11-j)*286+s2]=(ni&1)? -v : v;
  } else if(blk<93){              // D3_2: [bi][286]
    int idx=(blk-89)*256+t; if(idx>=3*286) return;
    int bi=idx/286, s=idx%286;
    int l=0; while(B2OFFc[l+1]<=s) ++l;
    int r=s-B2OFFc[l]; int L=2*l+1;
    int mi=r/L, ni=r%L;
    double beta=(bi+1)*(PI_D/8.0)/3.0;
    D3_2[idx]=(float)wigd(l,mi-l,ni-l,beta);
  } else if(blk<95){              // D3_1: [bi][100]
    int idx=(blk-93)*256+t; if(idx>=3*100) return;
    int bi=idx/100, s=idx%100;
    int l=0; while((l+1)*(l+1)<=s) ++l;
    int m=s-l*l-l;
    double beta=(bi+1)*(PI_D/8.0)/3.0;
    D3_1[idx]=(float)wigd(l,m,0,beta);
  } else if(blk==95){             // misc
    if(t<12){ double c=2.0*PI_D/12.0; WINT[t]=(float)(dhw(6,t)*c*c); }
    if(t<60){ double a=2.0*PI_D*t/60.0; E60[t]=make_float2((float)cos(a),(float)sin(a)); }
    if(t<20){ double a=2.0*PI_D*t/20.0; E20[t]=make_float2((float)cos(a),(float)sin(a)); }
    if(t<12){ double a=2.0*PI_D*t/12.0; E12[t]=make_float2((float)cos(a),(float)sin(a)); }
  } else if(blk<102){             // zLUT[1330]: packed s1x | s1k<<16
    int idx=(blk-96)*256+t; if(idx>=1330) return;
    int l=0; while(ZB10c[l+1]<=idx) ++l;
    int r=idx-ZB10c[l], L=2*l+1;
    int mi=r/L, ni=r%L;
    unsigned s1x=(unsigned)(l*l+mi), s1k=(unsigned)(l*l+ni);
    zLUT[idx]=s1x|(s1k<<16);
  } else if(blk==102){            // xh2LUT, h2LUT, fhLUT
    if(t<146){
      int l,m,n; h_decode(t,l,m,n);
      int L=2*l+1;
      int s2 =B2OFFc[l]+(m+l)*L+(n+l);
      int s2p=B2OFFc[l]+(l-m)*L+(l-n);
      unsigned sg=(unsigned)((m+n)&1);
      xh2LUT[t]=(unsigned)s2 | ((unsigned)s2p<<10) | (sg<<20);
      h2LUT[t]=(unsigned)l | ((unsigned)(m+l)<<4) | ((unsigned)(n+l)<<8) | ((unsigned)s2<<12);
      fhLUT[t]=(unsigned short)((n==0)? m : 6+(n-1)*11+(m+5));
    }
  } else {                        // blk==103: aLUT[181] sorted by lmin
    if(t==0){
      int idx=0;
      for(int lm=0;lm<10;++lm){
        for(int m=0;m<10;++m){
          int nlo=(m==0)?0:-9;
          for(int n=nlo;n<10;++n){
            int an=n<0?-n:n;
            int lmin=m>an?m:an;
            if(lmin!=lm) continue;
            int L=2*lm+1;
            int zi=ZB10c[lm]+(m+lm)*L+(n+lm);
            aLUT[idx++]=(unsigned)zi | ((unsigned)m<<11) | ((unsigned)(n+9)<<15) | ((unsigned)lm<<20);
          }
        }
      }
    }
  }
}

// ---------------- front: per-b DFT+S2 analysis | k1h | KA (k2 gamma-DFT) ----------------
__global__ __launch_bounds__(256) void front_k(const float* __restrict__ x,
    const float* __restrict__ k1, const float* __restrict__ k2,
    const float2* __restrict__ E60, const float* __restrict__ A1,
    const float* __restrict__ D3_1,
    float2* __restrict__ XHAT, float2* __restrict__ K1H, float2* __restrict__ KA){
  __shared__ float2 E8s[8];
  int blk=blockIdx.x, t=threadIdx.x;
  if(blk<128){
    __shared__ __align__(16) float xs[3600];
    __shared__ float2 E60s[60];      // conjugated twiddles
    __shared__ float2 XFs[1140];     // [j][mi], mi = m+9
    if(t<60){ float2 e=E60[t]; E60s[t]=make_float2(e.x,-e.y); }
    {
      const float4* src=(const float4*)(x+blk*3600);
      float4* dst=(float4*)xs;
      for(int i=t;i<900;i+=256) GLOAD_LDS16(src+i, dst+(i&~63));
    }
    __syncthreads();
    for(int idx=t; idx<1140; idx+=256){
      int j=idx/19, mi=idx%19;
      int step=(mi<9)? mi+51 : mi-9;
      const float* xr=xs+j*60;
      v2f acc={0.f,0.f};
      int k=0;
      for(int a=0;a<60;++a){
        acc=PKFMA(bc2(xr[a]), ldv(&E60s[k]), acc);
        k+=step; if(k>=60)k-=60;
      }
      XFs[idx]=make_float2(acc.x,acc.y);
    }
    __syncthreads();
    for(int s=t; s<100; s+=256){
      int l=0; while((l+1)*(l+1)<=s) ++l;
      int m=s-l*l-l;
      const float2* xf=&XFs[m+9];
      v2f acc={0.f,0.f};
      for(int j=0;j<60;++j){
        acc=PKFMA(bc2(A1[j*NS1+s]), ldv(&xf[j*19]), acc);
      }
      XHAT[blk*NS1+s]=make_float2(acc.x,acc.y);
    }
  } else if(blk<136){
    if(t<8) E8s[t]=E8c[t];
    __syncthreads();
    int idx=(blk-128)*256+t;
    if(idx<F1*NS1){
      int o=idx/NS1, s=idx%NS1;
      int l=0; while((l+1)*(l+1)<=s) ++l;
      int m=s-l*l-l;
      int mm=m&7;
      v2f acc={0.f,0.f};
      for(int bi=0;bi<3;++bi){
        v2f sum={0.f,0.f};
        int q=0;
        #pragma unroll
        for(int ai=0;ai<8;++ai){
          sum=PKFMA(bc2(k1[o*24+bi*8+ai]), ldv(&E8s[q]), sum);
          q=(q+mm)&7;
        }
        acc=PKFMA(bc2(D3_1[bi*100+s]), sum, acc);
      }
      const float SC1f = 0.06123724356957945f;
      K1H[idx]=make_float2(acc.x*SC1f, acc.y*SC1f);
    }
  } else {
    // KA[io*192 + bi*64 + q*8 + ai] = sum_gi k2[io*192+bi*64+ai*8+gi]*e8[(gi*q)&7]
    if(t<8) E8s[t]=E8c[t];
    __syncthreads();
    int idx=(blk-136)*256+t;
    if(idx<153600){
      int ai=idx&7, q=(idx>>3)&7;
      int r2=idx>>6;
      int bi=r2%3, io=r2/3;
      const float* kp=k2+(size_t)io*192+bi*64+ai*8;
      v2f acc={0.f,0.f};
      int ph=0;
      #pragma unroll
      for(int gi=0;gi<8;++gi){
        acc=PKFMA(bc2(kp[gi]), ldv(&E8s[ph]), acc);
        ph=(ph+q)&7;
      }
      KA[(size_t)io*192+bi*64+q*8+ai]=make_float2(acc.x,acc.y);
    }
  }
}

// fused1: wave-per-j barrier-free pipeline, packed-fp32 math, LUT-driven.
// XH2 layout: [b][s2][i]
__global__ __launch_bounds__(256,6) void fused1(
    const float2* __restrict__ XHAT, const float2* __restrict__ K1H,
    const float* __restrict__ D1SJ, const float* __restrict__ W3H,
    const float2* __restrict__ E20, const float* __restrict__ bias1,
    const unsigned* __restrict__ zLUT, const unsigned* __restrict__ xh2LUT,
    const unsigned short* __restrict__ fhLUT, const unsigned* __restrict__ aLUT,
    float2* __restrict__ XH2){
  const int b=blockIdx.x, o=blockIdx.y, t=threadIdx.x;
  const int ln=t&63, w=t>>6;
  __shared__ __align__(16) float2 zS[1330];
  __shared__ __align__(16) float2 TWE2[400];  // [r][k] = e^{i r k th}, 20x20
  __shared__ __align__(16) float2 regA[4][200];
  __shared__ __align__(16) float2 regB[4][190];

  for(int idx=t; idx<400; idx+=256){
    int r=idx/20, c=idx%20;
    TWE2[idx]=E20[(r*c)%20];
  }
  {
    float2* st=regA[0];   // xh rows staged: [0..99]=XHAT row, [100..199]=K1H row
    if(t<100) st[t]=XHAT[b*NS1+t];
    else if(t<200) st[t]=K1H[o*NS1+(t-100)];
  }
  __syncthreads();
  {
    const float2* st=regA[0];
    for(int idx=t; idx<1330; idx+=256){
      unsigned u=zLUT[idx];
      v2f xa=ldv(&st[u&0xffff]);
      v2f kb=ldv(&st[100+(u>>16)]);
      v2f p1=xa*kb, p2=xa*SW(kb);
      zS[idx]=make_float2(p1.x+p1.y, p2.y-p2.x);   // xa*conj(kb)
    }
  }
  __syncthreads();

  const float bb1=bias1[o];
  float2* G  = regA[w];
  float*  vbF= (float*)regA[w];
  float2* Fq = regA[w];
  float*  RB = (float*)regB[w];   // Sx[0..180) Sy[180..360) T0[360..380)
  float*  Sx = RB;
  float*  Sy = RB+180;
  float*  T0f= RB+360;
  float2* U_T= regB[w];           // reuse after C
  v2f fa0={0.f,0.f}, fa1=fa0, fa2=fa0;

  // B-phase twiddle rows: n=c-9 -> row (c+11)%20
  const int BROW[19]={11,12,13,14,15,16,17,18,19,0,1,2,3,4,5,6,7,8,9};

  for(int jq=0;jq<5;++jq){
    const int j=jq*4+w;
    const float* Dg=D1SJ + j*1330;
    // A: Wigner-beta contraction, half-space (181 items, lmin-sorted LUT)
    for(int idx=ln; idx<181; idx+=64){
      unsigned au=aLUT[idx];
      int zi=au&2047;
      int m=(au>>11)&15, n9=(au>>15)&31, l=(au>>20)&15;
      int L=2*l+1;
      int m2=2*m+2;
      v2f a0={0.f,0.f};
      for(; l<10; ++l){
        a0=PKFMA(ldv(&zS[zi]), bc2(Dg[zi]), a0);
        zi += L*L + 2*L + m2; L += 2;
      }
      *(v2f*)&G[m*19+n9]=a0;
    }
    WFENCE;
    // B: S_m(g quad) via split-accumulator dot trick (45 items) + T0 quads (5)
    if(ln<45){
      int mb=ln/5+1, g0=(ln%5)*4;
      const float2* Gr=&G[mb*19];
      v2f p10={0.f,0.f},p20=p10,p11=p10,p21=p10,p12=p10,p22=p10,p13=p10,p23=p10;
      #pragma unroll
      for(int c=0;c<19;++c){
        v2f gv=ldv(&Gr[c]);
        const float* er=(const float*)&TWE2[BROW[c]*20+g0];
        float4 e01=*(const float4*)er, e23=*(const float4*)(er+4);
        v2f e0={e01.x,e01.y}, e1={e01.z,e01.w}, e2={e23.x,e23.y}, e3={e23.z,e23.w};
        p10=PKFMA(gv,e0,p10); p20=PKFMA(gv,SW(e0),p20);
        p11=PKFMA(gv,e1,p11); p21=PKFMA(gv,SW(e1),p21);
        p12=PKFMA(gv,e2,p12); p22=PKFMA(gv,SW(e2),p22);
        p13=PKFMA(gv,e3,p13); p23=PKFMA(gv,SW(e3),p23);
      }
      int si=(mb-1)*20+g0;
      *(v2f*)&Sx[si]  =(v2f){2.f*(p10.x-p10.y), 2.f*(p11.x-p11.y)};
      *(v2f*)&Sx[si+2]=(v2f){2.f*(p12.x-p12.y), 2.f*(p13.x-p13.y)};
      *(v2f*)&Sy[si]  =(v2f){2.f*(p20.x+p20.y), 2.f*(p21.x+p21.y)};
      *(v2f*)&Sy[si+2]=(v2f){2.f*(p22.x+p22.y), 2.f*(p23.x+p23.y)};
    } else if(ln<50){
      int g0=(ln-45)*4;
      float r0=G[9].x, r1=r0, r2=r0, r3=r0;   // n=0 term
      #pragma unroll
      for(int n=1;n<10;++n){
        float2 gv=G[9+n];
        const float2* tw=&TWE2[n*20+g0];
        float2 e0=tw[0],e1=tw[1],e2=tw[2],e3=tw[3];
        r0+=2.f*(gv.x*e0.x-gv.y*e0.y);
        r1+=2.f*(gv.x*e1.x-gv.y*e1.y);
        r2+=2.f*(gv.x*e2.x-gv.y*e2.y);
        r3+=2.f*(gv.x*e3.x-gv.y*e3.y);
      }
      T0f[g0]=r0; T0f[g0+1]=r1; T0f[g0+2]=r2; T0f[g0+3]=r3;
    }
    WFENCE;
    // C: v(a,g)=T0+sum_m Re[S e^{ima}], bias, relu; packed over g-pairs (50 items)
    if(ln<50){
      int ap=ln/5, g0=(ln%5)*4;
      int a0=2*ap, a1=a0+1;
      v2f i01={T0f[g0]+bb1, T0f[g0+1]+bb1};
      v2f i23={T0f[g0+2]+bb1, T0f[g0+3]+bb1};
      v2f vA01=i01, vA23=i23, vB01=i01, vB23=i23;
      #pragma unroll
      for(int m=1;m<10;++m){
        float2 e0=TWE2[a0*20+m], e1=TWE2[a1*20+m];
        v2f sx01=*(const v2f*)&Sx[(m-1)*20+g0];
        v2f sx23=*(const v2f*)&Sx[(m-1)*20+g0+2];
        v2f sy01=*(const v2f*)&Sy[(m-1)*20+g0];
        v2f sy23=*(const v2f*)&Sy[(m-1)*20+g0+2];
        vA01=PKFMA(bc2(e0.x),sx01,vA01); vA01=PKFMA(bc2(-e0.y),sy01,vA01);
        vA23=PKFMA(bc2(e0.x),sx23,vA23); vA23=PKFMA(bc2(-e0.y),sy23,vA23);
        vB01=PKFMA(bc2(e1.x),sx01,vB01); vB01=PKFMA(bc2(-e1.y),sy01,vB01);
        vB23=PKFMA(bc2(e1.x),sx23,vB23); vB23=PKFMA(bc2(-e1.y),sy23,vB23);
      }
      v2f z2={0.f,0.f};
      *(v2f*)&vbF[a0*20+g0]  =__builtin_elementwise_max(vA01,z2);
      *(v2f*)&vbF[a0*20+g0+2]=__builtin_elementwise_max(vA23,z2);
      *(v2f*)&vbF[a1*20+g0]  =__builtin_elementwise_max(vB01,z2);
      *(v2f*)&vbF[a1*20+g0+2]=__builtin_elementwise_max(vB23,z2);
    }
    WFENCE;
    // D: U_T[nu][a]=sum_g v(a,g) e^{-i nu g}; 2-nu batch (60 items)
    if(ln<60){
      int a=ln/3, np=ln%3;
      int nu0=2*np, nu1=2*np+1;
      int r0=(np==0)?0:(20-2*np);
      int r1=19-2*np;
      const float* vp=&vbF[a*20];
      const float2* T0r=&TWE2[r0*20];
      const float2* T1r=&TWE2[r1*20];
      v2f u0={0.f,0.f}, u1=u0;
      #pragma unroll
      for(int g=0;g<20;++g){
        v2f xb=bc2(vp[g]);
        u0=PKFMA(xb, ldv(&T0r[g]), u0);
        u1=PKFMA(xb, ldv(&T1r[g]), u1);
      }
      *(v2f*)&U_T[nu0*20+a]=u0; *(v2f*)&U_T[nu1*20+a]=u1;
    }
    WFENCE;
    // E: Fq(mu,nu)=sum_a U_T[nu][a] e^{-i mu a}; dot trick (61 items)
    if(ln<61){
      int mu,nu;
      if(ln<6){ mu=ln; nu=0; } else { int q=ln-6; nu=q/11+1; mu=q%11-5; }
      int mm=(mu+20)%20;
      int rm=(20-mm)%20;
      const float2* Ur=&U_T[nu*20];
      const float2* Er=&TWE2[rm*20];
      v2f p1={0.f,0.f}, p2=p1;
      #pragma unroll
      for(int a=0;a<20;++a){
        v2f u=ldv(&Ur[a]), e=ldv(&Er[a]);
        p1=PKFMA(u,e,p1);
        p2=PKFMA(u,SW(e),p2);
      }
      Fq[ln]=make_float2(p1.x-p1.y, p2.x+p2.y);
    }
    WFENCE;
    // F: accumulate half-s2 with W3H into registers
    {
      const float* W3r=W3H + j*NH2;
      fa0=PKFMA(bc2(W3r[ln]),    ldv(&Fq[fhLUT[ln]]),    fa0);
      fa1=PKFMA(bc2(W3r[64+ln]), ldv(&Fq[fhLUT[64+ln]]), fa1);
      if(ln<18) fa2=PKFMA(bc2(W3r[128+ln]), ldv(&Fq[fhLUT[128+ln]]), fa2);
    }
    WFENCE;
  }
  // spill register accumulators, merge 4 waves, expand half->full by conjugation
  regB[w][ln]=make_float2(fa0.x,fa0.y);
  regB[w][64+ln]=make_float2(fa1.x,fa1.y);
  if(ln<18) regB[w][128+ln]=make_float2(fa2.x,fa2.y);
  __syncthreads();
  for(int h=t; h<146; h+=256){
    unsigned u=xh2LUT[h];
    int s2=u&1023, s2p=(u>>10)&1023;
    float sg=((u>>20)&1)? -1.f : 1.f;
    float2 a0=regB[0][h], a1=regB[1][h], a2=regB[2][h], a3=regB[3][h];
    float2 a=make_float2(a0.x+a1.x+a2.x+a3.x, a0.y+a1.y+a2.y+a3.y);
    XH2[(b*286+s2 )*F1+o]=a;
    XH2[(b*286+s2p)*F1+o]=make_float2(sg*a.x, -sg*a.y);
  }
}

// K2H: block per (i,o); KA row staged to LDS once; 146 h-threads consume.
__global__ __launch_bounds__(192) void k2h_k(const float2* __restrict__ KA,
                      const float* __restrict__ D3_2,
                      const unsigned* __restrict__ h2LUT, const unsigned* __restrict__ xh2LUT,
                      float2* __restrict__ K2H){
  __shared__ float2 kaS[192];
  __shared__ float2 E8s[8];
  int io=blockIdx.x, t=threadIdx.x;
  int i=io/F2, o=io%F2;
  if(t<8) E8s[t]=E8c[t];
  kaS[t]=KA[(size_t)io*192+t];
  __syncthreads();
  if(t>=146) return;
  unsigned hu=h2LUT[t];
  int l=hu&15, mi=(hu>>4)&15, ni=(hu>>8)&15, s2=hu>>12;
  int m=mi-l, n=ni-l;
  unsigned xu=xh2LUT[t];
  int s2p=(xu>>10)&1023;
  float sg=((xu>>20)&1)? -1.f : 1.f;
  int q=n&7, p=(m-n)&7;
  v2f a1={0.f,0.f}, a2=a1;
  for(int bi=0;bi<3;++bi){
    const float2* kp=&kaS[bi*64+q*8];
    v2f s1={0.f,0.f}, s2v=s1;
    int ph=0;
    #pragma unroll
    for(int ai=0;ai<8;++ai){
      v2f ka=ldv(&kp[ai]), e=ldv(&E8s[ph]);
      s1=PKFMA(ka,e,s1); s2v=PKFMA(ka,SW(e),s2v);
      ph=(ph+p)&7;
    }
    v2f dv=bc2(D3_2[bi*286+s2]);
    a1=PKFMA(dv,s1,a1); a2=PKFMA(dv,s2v,a2);
  }
  const float SC2f = 0.034722222222222224f;
  float re=(a1.x-a1.y)*SC2f, im=(a2.x+a2.y)*SC2f;
  K2H[((size_t)o*286+s2)*F1+i]=make_float2(re,im);
  K2H[((size_t)o*286+s2p)*F1+i]=make_float2(sg*re,-sg*im);
}

// fused2: cooperative z2 build, then wave-per-3j single-pass synthesis+integrate
__global__ __launch_bounds__(256,3) void fused2(
    const float2* __restrict__ XH2, const float2* __restrict__ K2H,
    const float* __restrict__ D2SJ, const float* __restrict__ WINT,
    const float2* __restrict__ E12, const float* __restrict__ bias2,
    const unsigned* __restrict__ h2LUT, const unsigned* __restrict__ xh2LUT,
    float* __restrict__ FEAT){
  const int b=blockIdx.x, o=blockIdx.y, t=threadIdx.x;
  const int ln=t&63, w=t>>6;
  __shared__ __align__(16) float2 Xs[2420];
  __shared__ __align__(16) float2 Ks[2420];
  __shared__ float2 zpS[1144];
  __shared__ float2 z2S[286];
  __shared__ float  redS[256];
  float2* alias=(float2*)Xs;       // reused after z-build
  float2* TWE12=alias;             // [12][12]: e^{i r c th12}

  const int gb[4]={0,84,165,286};
  const int hb[4]={0,44,85,146};
  for(int grp=0; grp<3; ++grp){
    int row0=gb[grp], rows=gb[grp+1]-row0;
    {
      int cnt4=rows*10;
      const float4* xsrc=(const float4*)(XH2+(size_t)(b*286+row0)*F1);
      const float4* ksrc=(const float4*)(K2H+(size_t)(o*286+row0)*F1);
      float4* xd=(float4*)Xs; float4* kd=(float4*)Ks;
      for(int i4=t;i4<cnt4;i4+=256){
        int wb=i4&~63;
        GLOAD_LDS16(xsrc+i4, xd+wb);
        GLOAD_LDS16(ksrc+i4, kd+wb);
      }
    }
    __syncthreads();
    int nh=hb[grp+1]-hb[grp];
    for(int idx=t; idx<4*nh; idx+=256){
      int hl=idx>>2, iq=idx&3;
      int h=hb[grp]+hl;
      unsigned hu=h2LUT[h];
      int l=hu&15, mi=(hu>>4)&15, ni=(hu>>8)&15, s2=hu>>12;
      int L=2*l+1;
      int xr0=(B2OFFc[l]-row0)+mi*L;
      int kr0=(B2OFFc[l]-row0)+ni*L;
      v2f p1={0.f,0.f}, p2=p1;
      for(int k=0;k<L;++k){
        const float2* xp=Xs+(xr0+k)*F1+iq*5;
        const float2* kp=Ks+(kr0+k)*F1+iq*5;
        #pragma unroll
        for(int i=0;i<5;++i){
          v2f xa=ldv(&xp[i]), kb=ldv(&kp[i]);
          p1=PKFMA(xa,kb,p1);
          p2=PKFMA(xa,SW(kb),p2);
        }
      }
      zpS[iq*286+s2]=make_float2(p1.x+p1.y, p2.y-p2.x);
    }
    __syncthreads();
  }
  for(int idx=t; idx<146; idx+=256){
    unsigned xu=xh2LUT[idx];
    int s2=xu&1023, s2p=(xu>>10)&1023;
    float sg=((xu>>20)&1)? -1.f : 1.f;
    float2 a;
    a.x=zpS[0*286+s2].x+zpS[1*286+s2].x+zpS[2*286+s2].x+zpS[3*286+s2].x;
    a.y=zpS[0*286+s2].y+zpS[1*286+s2].y+zpS[2*286+s2].y+zpS[3*286+s2].y;
    z2S[s2]=a;
    z2S[s2p]=make_float2(sg*a.x,-sg*a.y);
  }
  __syncthreads();
  for(int idx=t; idx<144; idx+=256){
    int r=idx/12, c=idx%12;
    TWE12[idx]=E12[(r*c)%12];
  }
  __syncthreads();

  float2* base2=alias+144+w*400;
  float2* G2_0=base2; float2* G2_1=base2+66; float2* G2_2=base2+132;
  float*  SP=(float*)(base2+198);
  float*  S2x0=SP, *S2x1=SP+60, *S2x2=SP+120;
  float*  S2y0=SP+180, *S2y1=SP+240, *S2y2=SP+300;
  float*  T02=SP+360;               // [3][12]
  float personal=0.f;
  const float b2v=bias2[o];
  const int j0=3*w, j1=3*w+1, j2=3*w+2;
  const float* Dg0=D2SJ + j0*286;
  const float* Dg1=D2SJ + j1*286;
  const float* Dg2=D2SJ + j2*286;
  const int BR12[11]={7,8,9,10,11,0,1,2,3,4,5};

  // A2: 61 half items, 3 j's
  if(ln<61){
    int m,n;
    if(ln<6){m=0;n=ln;} else {int qq=ln-6;m=qq/11+1;n=qq%11-5;}
    int an=n<0?-n:n; int l=m>an?m:an; int L=2*l+1;
    int zi=B2OFFc[l]+(m+l)*L+(n+l); int m2=2*m+2;
    v2f a0={0.f,0.f}, a1=a0, a2=a0;
    for(;l<6;++l){
      v2f zv=ldv(&z2S[zi]);
      a0=PKFMA(zv, bc2(Dg0[zi]), a0);
      a1=PKFMA(zv, bc2(Dg1[zi]), a1);
      a2=PKFMA(zv, bc2(Dg2[zi]), a2);
      zi+=L*L+2*L+m2; L+=2;
    }
    int gi=m*11+(n+5);
    *(v2f*)&G2_0[gi]=a0; *(v2f*)&G2_1[gi]=a1; *(v2f*)&G2_2[gi]=a2;
  }
  WFENCE;
  // B2: 42 items (30 S-pairs + 12 T0), 3 j's, dot trick
  if(ln<30){
    int m=ln/6+1, g=(ln%6)*2;
    v2f p10={0.f,0.f},p20=p10,p11=p10,p21=p10;
    v2f q10=p10,q20=p10,q11=p10,q21=p10;
    v2f r10=p10,r20=p10,r11=p10,r21=p10;
    #pragma unroll
    for(int c=0;c<11;++c){
      float4 eq=*(const float4*)&TWE12[BR12[c]*12+g];
      v2f e0={eq.x,eq.y}, e1={eq.z,eq.w};
      v2f g0=ldv(&G2_0[m*11+c]), g1=ldv(&G2_1[m*11+c]), g2=ldv(&G2_2[m*11+c]);
      p10=PKFMA(g0,e0,p10); p20=PKFMA(g0,SW(e0),p20);
      p11=PKFMA(g0,e1,p11); p21=PKFMA(g0,SW(e1),p21);
      q10=PKFMA(g1,e0,q10); q20=PKFMA(g1,SW(e0),q20);
      q11=PKFMA(g1,e1,q11); q21=PKFMA(g1,SW(e1),q21);
      r10=PKFMA(g2,e0,r10); r20=PKFMA(g2,SW(e0),r20);
      r11=PKFMA(g2,e1,r11); r21=PKFMA(g2,SW(e1),r21);
    }
    int si=(m-1)*12+g;
    S2x0[si]=2.f*(p10.x-p10.y); S2x0[si+1]=2.f*(p11.x-p11.y);
    S2y0[si]=2.f*(p20.x+p20.y); S2y0[si+1]=2.f*(p21.x+p21.y);
    S2x1[si]=2.f*(q10.x-q10.y); S2x1[si+1]=2.f*(q11.x-q11.y);
    S2y1[si]=2.f*(q20.x+q20.y); S2y1[si+1]=2.f*(q21.x+q21.y);
    S2x2[si]=2.f*(r10.x-r10.y); S2x2[si+1]=2.f*(r11.x-r11.y);
    S2y2[si]=2.f*(r20.x+r20.y); S2y2[si+1]=2.f*(r21.x+r21.y);
  } else if(ln<42){
    int g=ln-30;
    float r0=G2_0[5].x, r1=G2_1[5].x, r2=G2_2[5].x;
    #pragma unroll
    for(int n=1;n<6;++n){
      float2 e=TWE12[n*12+g];
      float2 g0=G2_0[5+n], g1=G2_1[5+n], g2=G2_2[5+n];
      r0+=2.f*(g0.x*e.x-g0.y*e.y);
      r1+=2.f*(g1.x*e.x-g1.y*e.y);
      r2+=2.f*(g2.x*e.x-g2.y*e.y);
    }
    T02[g]=r0; T02[12+g]=r1; T02[24+g]=r2;
  }
  WFENCE;
  // C2: 36 items, packed g-pairs, fused relu+integrate, 3 j's
  if(ln<36){
    float w0=WINT[j0], w1=WINT[j1], w2=WINT[j2];
    int a=ln/3, g4=(ln%3)*4;
    v2f iA0={T02[g4]+b2v, T02[g4+1]+b2v},       iB0={T02[g4+2]+b2v, T02[g4+3]+b2v};
    v2f iA1={T02[12+g4]+b2v, T02[12+g4+1]+b2v}, iB1={T02[12+g4+2]+b2v, T02[12+g4+3]+b2v};
    v2f iA2={T02[24+g4]+b2v, T02[24+g4+1]+b2v}, iB2={T02[24+g4+2]+b2v, T02[24+g4+3]+b2v};
    #pragma unroll
    for(int m=1;m<6;++m){
      float2 e=TWE12[a*12+m];
      v2f ex=bc2(e.x), eny=bc2(-e.y);
      int si=(m-1)*12+g4;
      v2f sx, sy;
      sx=*(const v2f*)&S2x0[si];   sy=*(const v2f*)&S2y0[si];
      iA0=PKFMA(ex,sx,iA0); iA0=PKFMA(eny,sy,iA0);
      sx=*(const v2f*)&S2x0[si+2]; sy=*(const v2f*)&S2y0[si+2];
      iB0=PKFMA(ex,sx,iB0); iB0=PKFMA(eny,sy,iB0);
      sx=*(const v2f*)&S2x1[si];   sy=*(const v2f*)&S2y1[si];
      iA1=PKFMA(ex,sx,iA1); iA1=PKFMA(eny,sy,iA1);
      sx=*(const v2f*)&S2x1[si+2]; sy=*(const v2f*)&S2y1[si+2];
      iB1=PKFMA(ex,sx,iB1); iB1=PKFMA(eny,sy,iB1);
      sx=*(const v2f*)&S2x2[si];   sy=*(const v2f*)&S2y2[si];
      iA2=PKFMA(ex,sx,iA2); iA2=PKFMA(eny,sy,iA2);
      sx=*(const v2f*)&S2x2[si+2]; sy=*(const v2f*)&S2y2[si+2];
      iB2=PKFMA(ex,sx,iB2); iB2=PKFMA(eny,sy,iB2);
    }
    v2f z2={0.f,0.f};
    v2f rA0=__builtin_elementwise_max(iA0,z2), rB0=__builtin_elementwise_max(iB0,z2);
    v2f rA1=__builtin_elementwise_max(iA1,z2), rB1=__builtin_elementwise_max(iB1,z2);
    v2f rA2=__builtin_elementwise_max(iA2,z2), rB2=__builtin_elementwise_max(iB2,z2);
    personal += w0*(rA0.x+rA0.y+rB0.x+rB0.y)
              + w1*(rA1.x+rA1.y+rB1.x+rB1.y)
              + w2*(rA2.x+rA2.y+rB2.x+rB2.y);
  }
  redS[t]=personal;
  __syncthreads();
  for(int s=128;s>0;s>>=1){
    if(t<s) redS[t]+=redS[t+s];
    __syncthreads();
  }
  if(t==0) FEAT[b*F2+o]=redS[0];
}

__global__ void head_k(const float* __restrict__ FEAT, const float* __restrict__ w_out,
                       const float* __restrict__ b_lin, float* __restrict__ out){
  int idx=blockIdx.x*blockDim.x+threadIdx.x;
  if(idx>=BATCH*FOUT) return;
  int b=idx/FOUT, q=idx%FOUT;
  float acc=b_lin[q];
  for(int f=0;f<F2;++f) acc += FEAT[b*F2+f]*w_out[q*F2+f];
  out[idx]=acc;
}

extern "C" void kernel_launch(void* const* d_in, const int* in_sizes, int n_in,
                              void* d_out, int out_size, void* d_ws, size_t ws_size,
                              hipStream_t stream) {
  const float* x    =(const float*)d_in[0];
  const float* k1   =(const float*)d_in[1];
  const float* bias1=(const float*)d_in[2];
  const float* k2   =(const float*)d_in[3];
  const float* bias2=(const float*)d_in[4];
  const float* w_out=(const float*)d_in[5];
  const float* b_lin=(const float*)d_in[6];
  float* out=(float*)d_out;

  char* ws=(char*)d_ws;
  float*  A1   =(float* )(ws+0);        //  6000 f
  float*  D1SJ =(float* )(ws+24000);    //  26600 f
  float*  W3H  =(float* )(ws+130400);   //  2920 f
  float*  D2SJ =(float* )(ws+142080);   //  3432 f
  float*  D3_2 =(float* )(ws+155808);   //  858 f (+pad)
  float*  D3_1 =(float* )(ws+159248);   //  300 f
  float*  WINT =(float* )(ws+160448);   //  12 f
  float2* E60  =(float2*)(ws+160496);   //  60 c
  float2* E20  =(float2*)(ws+160976);   //  20 c
  float2* E12  =(float2*)(ws+161136);   //  12 c (+pad)
  unsigned* zLUT=(unsigned*)(ws+161248);//  1330 u32 (+pad)
  unsigned* xh2LUT=(unsigned*)(ws+166576); // 146 u32
  unsigned* h2LUT =(unsigned*)(ws+167160); // 146 u32
  unsigned short* fhLUT=(unsigned short*)(ws+167744); // 146 u16 (+pad)
  unsigned* aLUT =(unsigned*)(ws+168048);  // 181 u32 (+pad)
  float2* XHAT =(float2*)(ws+168784);   //  [b][100] c
  float2* K1H  =(float2*)(ws+271184);   //  [o][100] c
  float2* KA   =(float2*)(ws+287184);   //  153600 c (1.2MB)
  float2* XH2  =(float2*)(ws+1515984);  //  [b][286][20] c
  float2* K2H  =(float2*)(ws+7373264);  //  [o][286][20] c
  float*  FEAT =(float* )(ws+9203664);  //  128*40 f -> 9224144 total

  (void)in_sizes; (void)n_in; (void)out_size; (void)ws_size;

  gen_all<<<104,256,0,stream>>>(A1,D1SJ,W3H,D2SJ,D3_2,D3_1,WINT,E60,E20,E12,
                                zLUT,xh2LUT,h2LUT,fhLUT,aLUT);
  front_k<<<736,256,0,stream>>>(x,k1,k2,E60,A1,D3_1,XHAT,K1H,KA);
  dim3 g1(BATCH,F1);
  fused1<<<g1,256,0,stream>>>(XHAT,K1H,D1SJ,W3H,E20,bias1,zLUT,xh2LUT,fhLUT,aLUT,XH2);
  k2h_k<<<F1*F2,192,0,stream>>>(KA,D3_2,h2LUT,xh2LUT,K2H);
  dim3 g2(BATCH,F2);
  fused2<<<g2,256,0,stream>>>(XH2,K2H,D2SJ,WINT,E12,bias2,h2LUT,xh2LUT,FEAT);
  head_k<<<(BATCH*FOUT+255)/256,256,0,stream>>>(FEAT,w_out,b_lin,out);
}

// Round 12
// 217.973 us; speedup vs baseline: 1.6466x; 1.0706x over previous
//
#include <hip/hip_runtime.h>
#include <math.h>

#define PI_D 3.14159265358979323846

#define BATCH 128
#define F1 20
#define F2 40
#define FOUT 10
#define NS1 100   // sum_{l<10} (2l+1)
#define NS2 286   // sum_{l<6} (2l+1)^2
#define NH2 146   // Hermitian half count of NS2

typedef float v2f __attribute__((ext_vector_type(2)));
#define PKFMA(a,b,c) __builtin_elementwise_fma((a),(b),(c))
#define SW(v) __builtin_shufflevector((v),(v),1,0)
static __device__ __forceinline__ v2f bc2(float s){ return (v2f){s,s}; }
static __device__ __forceinline__ v2f ldv(const float2* p){ return *(const v2f*)p; }

// async global->LDS, 16B per lane; lds arg must be wave-uniform base
#define GLOAD_LDS16(g,l) __builtin_amdgcn_global_load_lds( \
  (const __attribute__((address_space(1))) void*)(g), \
  (__attribute__((address_space(3))) void*)(l), 16, 0, 0)

__constant__ int ZB10c[11] = {0,1,10,35,84,165,286,455,680,969,1330};
__constant__ int B2OFFc[7] = {0,1,10,35,84,165,286};
__constant__ int HOFFc[7]  = {0,1,6,19,44,85,146};
// E8c[q] = exp(-2*pi*i*q/8)
__constant__ float2 E8c[8] = {
  { 1.f, 0.f}, { 0.70710678118654752f,-0.70710678118654752f},
  { 0.f,-1.f}, {-0.70710678118654752f,-0.70710678118654752f},
  {-1.f, 0.f}, {-0.70710678118654752f, 0.70710678118654752f},
  { 0.f, 1.f}, { 0.70710678118654752f, 0.70710678118654752f}};

// wave-synchronous phase fence
#define WFENCE do{ __builtin_amdgcn_sched_barrier(0); \
  asm volatile("s_waitcnt lgkmcnt(0)" ::: "memory"); \
  __builtin_amdgcn_sched_barrier(0); }while(0)

// half-space H = { (m,n): n>0 } U { (m,n): n==0 && m>=0 }
__device__ inline void h_decode(int h, int& l, int& m, int& n){
  l=0; while(HOFFc[l+1]<=h) ++l;
  int r=h-HOFFc[l], L=2*l+1;
  if(r<l+1){ n=0; m=r; }
  else { int q=r-(l+1); n=q/L+1; m=q%L-l; }
}

// ---------------- double-precision table generation helpers ----------------
__device__ inline double ipow_d(double x, int n){ double r=1.0; for(int i=0;i<n;++i) r*=x; return r; }
__device__ inline double dfact(int n){ double r=1.0; for(int i=2;i<=n;++i) r*=(double)i; return r; }

__device__ double wigd(int l, int mp, int m, double beta){
  double cb=cos(0.5*beta), sb=sin(0.5*beta);
  double pref=sqrt(dfact(l+mp)*dfact(l-mp)*dfact(l+m)*dfact(l-m));
  int s0 = (m-mp>0) ? (m-mp) : 0;
  int s1 = (l+m < l-mp) ? (l+m) : (l-mp);
  double acc=0.0;
  for(int s=s0;s<=s1;++s){
    double den=dfact(l+m-s)*dfact(s)*dfact(mp-m+s)*dfact(l-mp-s);
    double t=ipow_d(cb,2*l+m-mp-2*s)*ipow_d(sb,mp-m+2*s)/den;
    acc += ((mp-m+s)&1)? -t : t;
  }
  return pref*acc;
}

__device__ double dhw(int b, int j){
  double beta=PI_D*(2*j+1)/(4.0*b);
  double s=0.0;
  for(int k=0;k<b;++k) s += sin((2*k+1)*beta)/(2*k+1);
  return (2.0/b)*sin(beta)*s;
}

__device__ inline float2 cmulc(float2 a, float2 b){ // a * conj(b)
  return make_float2(a.x*b.x + a.y*b.y, a.y*b.x - a.x*b.y);
}

// ---------------- single merged table-generation kernel ----------------
// beta->pi-beta symmetry: d^l_{m',m}(pi-b) = (-1)^{l+m} d^l_{-m',m}(b)
// halves D1SJ/W3H/D2SJ work; dhw hoisted to per-block LDS table.
__global__ void gen_all(float* A1, float* D1SJ, float* W3H, float* D2SJ,
                        float* D3_2, float* D3_1, float* WINT,
                        float2* E60, float2* E20, float2* E12,
                        unsigned* zLUT, unsigned* xh2LUT, unsigned* h2LUT,
                        unsigned short* fhLUT, unsigned* aLUT){
  __shared__ double dhwS[60];
  int blk=blockIdx.x, t=threadIdx.x;
  if(blk<24){                     // A1: [j][s1], 60x100
    if(t<60) dhwS[t]=dhw(30,t);
    __syncthreads();
    int idx=blk*256+t;
    if(idx<6000){
      int j=idx/NS1, s=idx%NS1;
      int l=0; while((l+1)*(l+1)<=s) ++l;
      int m=s-l*l-l;
      double beta=PI_D*(2*j+1)/120.0;
      A1[idx]=(float)(wigd(l,m,0,beta)*dhwS[j]*(2.0*PI_D/60.0));
    }
  } else if(blk<76){              // D1SJ: j=0..9 computed, 19-j derived
    int idx=(blk-24)*256+t; if(idx>=13300) return;
    int j=idx/1330, s=idx%1330;
    int l=0; while(ZB10c[l+1]<=s) ++l;
    int r=s-ZB10c[l]; int L=2*l+1;
    int mi=r/L, ni=r%L;
    double beta=PI_D*(2*j+1)/40.0;
    float v=(float)((2*l+1)*wigd(l,mi-l,ni-l,beta));
    D1SJ[j*1330+s]=v;
    int s2=ZB10c[l]+(2*l-mi)*L+ni;
    D1SJ[(19-j)*1330+s2]=(ni&1)? -v : v;
  } else if(blk<82){              // W3H: j=0..9 computed, 19-j derived
    if(t<20) dhwS[t]=dhw(10,t);
    __syncthreads();
    int idx=(blk-76)*256+t;
    if(idx<10*NH2){
      int j=idx/NH2, h=idx%NH2;
      int l,m,n; h_decode(h,l,m,n);
      double beta=PI_D*(2*j+1)/40.0;
      double c=2.0*PI_D/20.0;
      float v=(float)(wigd(l,m,n,beta)*dhwS[j]*c*c);
      W3H[j*NH2+h]=v;
      if(n==0){
        W3H[(19-j)*NH2+h]=((l+m)&1)? -v : v;
      } else {
        int L=2*l+1;
        int hp=HOFFc[l]+(l+1)+(n-1)*L+(l-m);   // (m,n) -> (-m,n)
        W3H[(19-j)*NH2+hp]=((l+n)&1)? -v : v;
      }
    }
  } else if(blk<89){              // D2SJ: j=0..5 computed, 11-j derived
    int idx=(blk-82)*256+t; if(idx>=1716) return;
    int j=idx/286, s=idx%286;
    int l=0; while(B2OFFc[l+1]<=s) ++l;
    int r=s-B2OFFc[l]; int L=2*l+1;
    int mi=r/L, ni=r%L;
    double beta=PI_D*(2*j+1)/24.0;
    float v=(float)((2*l+1)*wigd(l,mi-l,ni-l,beta));
    D2SJ[j*286+s]=v;
    int s2=B2OFFc[l]+(2*l-mi)*L+ni;
    D2SJ[(11-j)*286+s2]=(ni&1)? -v : v;
  } else if(blk<93){              // D3_2: [bi][286]
    int idx=(blk-89)*256+t; if(idx>=3*286) return;
    int bi=idx/286, s=idx%286;
    int l=0; while(B2OFFc[l+1]<=s) ++l;
    int r=s-B2OFFc[l]; int L=2*l+1;
    int mi=r/L, ni=r%L;
    double beta=(bi+1)*(PI_D/8.0)/3.0;
    D3_2[idx]=(float)wigd(l,mi-l,ni-l,beta);
  } else if(blk<95){              // D3_1: [bi][100]
    int idx=(blk-93)*256+t; if(idx>=3*100) return;
    int bi=idx/100, s=idx%100;
    int l=0; while((l+1)*(l+1)<=s) ++l;
    int m=s-l*l-l;
    double beta=(bi+1)*(PI_D/8.0)/3.0;
    D3_1[idx]=(float)wigd(l,m,0,beta);
  } else if(blk==95){             // misc
    if(t<12){ double c=2.0*PI_D/12.0; WINT[t]=(float)(dhw(6,t)*c*c); }
    if(t<60){ double a=2.0*PI_D*t/60.0; E60[t]=make_float2((float)cos(a),(float)sin(a)); }
    if(t<20){ double a=2.0*PI_D*t/20.0; E20[t]=make_float2((float)cos(a),(float)sin(a)); }
    if(t<12){ double a=2.0*PI_D*t/12.0; E12[t]=make_float2((float)cos(a),(float)sin(a)); }
  } else if(blk<102){             // zLUT[1330]: packed s1x | s1k<<16
    int idx=(blk-96)*256+t; if(idx>=1330) return;
    int l=0; while(ZB10c[l+1]<=idx) ++l;
    int r=idx-ZB10c[l], L=2*l+1;
    int mi=r/L, ni=r%L;
    unsigned s1x=(unsigned)(l*l+mi), s1k=(unsigned)(l*l+ni);
    zLUT[idx]=s1x|(s1k<<16);
  } else if(blk==102){            // xh2LUT, h2LUT, fhLUT
    if(t<146){
      int l,m,n; h_decode(t,l,m,n);
      int L=2*l+1;
      int s2 =B2OFFc[l]+(m+l)*L+(n+l);
      int s2p=B2OFFc[l]+(l-m)*L+(l-n);
      unsigned sg=(unsigned)((m+n)&1);
      xh2LUT[t]=(unsigned)s2 | ((unsigned)s2p<<10) | (sg<<20);
      h2LUT[t]=(unsigned)l | ((unsigned)(m+l)<<4) | ((unsigned)(n+l)<<8) | ((unsigned)s2<<12);
      fhLUT[t]=(unsigned short)((n==0)? m : 6+(n-1)*11+(m+5));
    }
  } else {                        // blk==103: aLUT[181] sorted by lmin
    if(t==0){
      int idx=0;
      for(int lm=0;lm<10;++lm){
        for(int m=0;m<10;++m){
          int nlo=(m==0)?0:-9;
          for(int n=nlo;n<10;++n){
            int an=n<0?-n:n;
            int lmin=m>an?m:an;
            if(lmin!=lm) continue;
            int L=2*lm+1;
            int zi=ZB10c[lm]+(m+lm)*L+(n+lm);
            aLUT[idx++]=(unsigned)zi | ((unsigned)m<<11) | ((unsigned)(n+9)<<15) | ((unsigned)lm<<20);
          }
        }
      }
    }
  }
}

// ---------------- front: per-b DFT+S2 analysis | k1h | KA (k2 gamma-DFT) ----------------
__global__ __launch_bounds__(256) void front_k(const float* __restrict__ x,
    const float* __restrict__ k1, const float* __restrict__ k2,
    const float2* __restrict__ E60, const float* __restrict__ A1,
    const float* __restrict__ D3_1,
    float2* __restrict__ XHAT, float2* __restrict__ K1H, float2* __restrict__ KA){
  __shared__ float2 E8s[8];
  int blk=blockIdx.x, t=threadIdx.x;
  if(blk<128){
    __shared__ __align__(16) float xs[3600];
    __shared__ float2 E60s[60];      // conjugated twiddles
    __shared__ float2 XFs[1140];     // [j][mi], mi = m+9
    if(t<60){ float2 e=E60[t]; E60s[t]=make_float2(e.x,-e.y); }
    {
      const float4* src=(const float4*)(x+blk*3600);
      float4* dst=(float4*)xs;
      for(int i=t;i<900;i+=256) GLOAD_LDS16(src+i, dst+(i&~63));
    }
    __syncthreads();
    for(int idx=t; idx<1140; idx+=256){
      int j=idx/19, mi=idx%19;
      int step=(mi<9)? mi+51 : mi-9;
      const float* xr=xs+j*60;
      v2f acc={0.f,0.f};
      int k=0;
      for(int a=0;a<60;++a){
        acc=PKFMA(bc2(xr[a]), ldv(&E60s[k]), acc);
        k+=step; if(k>=60)k-=60;
      }
      XFs[idx]=make_float2(acc.x,acc.y);
    }
    __syncthreads();
    for(int s=t; s<100; s+=256){
      int l=0; while((l+1)*(l+1)<=s) ++l;
      int m=s-l*l-l;
      const float2* xf=&XFs[m+9];
      v2f acc={0.f,0.f};
      for(int j=0;j<60;++j){
        acc=PKFMA(bc2(A1[j*NS1+s]), ldv(&xf[j*19]), acc);
      }
      XHAT[blk*NS1+s]=make_float2(acc.x,acc.y);
    }
  } else if(blk<136){
    if(t<8) E8s[t]=E8c[t];
    __syncthreads();
    int idx=(blk-128)*256+t;
    if(idx<F1*NS1){
      int o=idx/NS1, s=idx%NS1;
      int l=0; while((l+1)*(l+1)<=s) ++l;
      int m=s-l*l-l;
      int mm=m&7;
      v2f acc={0.f,0.f};
      for(int bi=0;bi<3;++bi){
        v2f sum={0.f,0.f};
        int q=0;
        #pragma unroll
        for(int ai=0;ai<8;++ai){
          sum=PKFMA(bc2(k1[o*24+bi*8+ai]), ldv(&E8s[q]), sum);
          q=(q+mm)&7;
        }
        acc=PKFMA(bc2(D3_1[bi*100+s]), sum, acc);
      }
      const float SC1f = 0.06123724356957945f;
      K1H[idx]=make_float2(acc.x*SC1f, acc.y*SC1f);
    }
  } else {
    // KA[io*192 + bi*64 + q*8 + ai] = sum_gi k2[io*192+bi*64+ai*8+gi]*e8[(gi*q)&7]
    if(t<8) E8s[t]=E8c[t];
    __syncthreads();
    int idx=(blk-136)*256+t;
    if(idx<153600){
      int ai=idx&7, q=(idx>>3)&7;
      int r2=idx>>6;
      int bi=r2%3, io=r2/3;
      const float* kp=k2+(size_t)io*192+bi*64+ai*8;
      v2f acc={0.f,0.f};
      int ph=0;
      #pragma unroll
      for(int gi=0;gi<8;++gi){
        acc=PKFMA(bc2(kp[gi]), ldv(&E8s[ph]), acc);
        ph=(ph+q)&7;
      }
      KA[(size_t)io*192+bi*64+q*8+ai]=make_float2(acc.x,acc.y);
    }
  }
}

// fused1: wave-per-j barrier-free pipeline, packed-fp32 + radix-2 (g,g+10) split.
// XH2 layout: [b][s2][i]
__global__ __launch_bounds__(256,6) void fused1(
    const float2* __restrict__ XHAT, const float2* __restrict__ K1H,
    const float* __restrict__ D1SJ, const float* __restrict__ W3H,
    const float2* __restrict__ E20, const float* __restrict__ bias1,
    const unsigned* __restrict__ zLUT, const unsigned* __restrict__ xh2LUT,
    const unsigned short* __restrict__ fhLUT, const unsigned* __restrict__ aLUT,
    float2* __restrict__ XH2){
  const int b=blockIdx.x, o=blockIdx.y, t=threadIdx.x;
  const int ln=t&63, w=t>>6;
  __shared__ __align__(16) float2 zS[1330];
  __shared__ __align__(16) float2 TWE2[400];  // [r][k] = e^{i r k th}, 20x20
  __shared__ __align__(16) float2 regA[4][200];
  __shared__ __align__(16) float2 regB[4][190];

  for(int idx=t; idx<400; idx+=256){
    int r=idx/20, c=idx%20;
    TWE2[idx]=E20[(r*c)%20];
  }
  {
    float2* st=regA[0];   // xh rows staged: [0..99]=XHAT row, [100..199]=K1H row
    if(t<100) st[t]=XHAT[b*NS1+t];
    else if(t<200) st[t]=K1H[o*NS1+(t-100)];
  }
  __syncthreads();
  {
    const float2* st=regA[0];
    for(int idx=t; idx<1330; idx+=256){
      unsigned u=zLUT[idx];
      v2f xa=ldv(&st[u&0xffff]);
      v2f kb=ldv(&st[100+(u>>16)]);
      v2f p1=xa*kb, p2=xa*SW(kb);
      zS[idx]=make_float2(p1.x+p1.y, p2.y-p2.x);   // xa*conj(kb)
    }
  }
  __syncthreads();

  const float bb1=bias1[o];
  float2* G  = regA[w];
  float*  vbF= (float*)regA[w];
  float2* Fq = regA[w];
  float*  RB = (float*)regB[w];   // Sx[0..180) Sy[180..360) T0[360..380)
  float*  Sx = RB;
  float*  Sy = RB+180;
  float*  T0f= RB+360;
  float2* U_T= regB[w];           // reuse after C
  v2f fa0={0.f,0.f}, fa1=fa0, fa2=fa0;

  // B-phase twiddle rows: n=c-9 -> row (c+11)%20
  const int BROW[19]={11,12,13,14,15,16,17,18,19,0,1,2,3,4,5,6,7,8,9};

  for(int jq=0;jq<5;++jq){
    const int j=jq*4+w;
    const float* Dg=D1SJ + j*1330;
    // A: Wigner-beta contraction, half-space (181 items, lmin-sorted LUT)
    for(int idx=ln; idx<181; idx+=64){
      unsigned au=aLUT[idx];
      int zi=au&2047;
      int m=(au>>11)&15, n9=(au>>15)&31, l=(au>>20)&15;
      int L=2*l+1;
      int m2=2*m+2;
      v2f a0={0.f,0.f};
      for(; l<10; ++l){
        a0=PKFMA(ldv(&zS[zi]), bc2(Dg[zi]), a0);
        zi += L*L + 2*L + m2; L += 2;
      }
      *(v2f*)&G[m*19+n9]=a0;
    }
    WFENCE;
    // B: radix-2 split S_m(g)/S_m(g+10): 45 items (mb x g-pair) + T0 (5 items)
    if(ln<45){
      int mb=ln/5+1, gp=(ln%5)*2;
      const float2* Gr=&G[mb*19];
      v2f E1a={0.f,0.f},E2a=E1a,O1a=E1a,O2a=E1a;
      v2f E1b=E1a,E2b=E1a,O1b=E1a,O2b=E1a;
      #pragma unroll
      for(int c=0;c<19;++c){
        v2f gv=ldv(&Gr[c]);
        const float* er=(const float*)&TWE2[BROW[c]*20+gp];
        float4 e01=*(const float4*)er;
        v2f e0={e01.x,e01.y}, e1={e01.z,e01.w};
        if(c&1){   // c odd -> n=c-9 even -> E
          E1a=PKFMA(gv,e0,E1a); E2a=PKFMA(gv,SW(e0),E2a);
          E1b=PKFMA(gv,e1,E1b); E2b=PKFMA(gv,SW(e1),E2b);
        } else {   // n odd -> O
          O1a=PKFMA(gv,e0,O1a); O2a=PKFMA(gv,SW(e0),O2a);
          O1b=PKFMA(gv,e1,O1b); O2b=PKFMA(gv,SW(e1),O2b);
        }
      }
      int si=(mb-1)*20+gp;
      float exa=E1a.x-E1a.y, oxa=O1a.x-O1a.y;
      float eya=E2a.x+E2a.y, oya=O2a.x+O2a.y;
      float exb=E1b.x-E1b.y, oxb=O1b.x-O1b.y;
      float eyb=E2b.x+E2b.y, oyb=O2b.x+O2b.y;
      *(v2f*)&Sx[si]   =(v2f){2.f*(exa+oxa), 2.f*(exb+oxb)};
      *(v2f*)&Sx[si+10]=(v2f){2.f*(exa-oxa), 2.f*(exb-oxb)};
      *(v2f*)&Sy[si]   =(v2f){2.f*(eya+oya), 2.f*(eyb+oyb)};
      *(v2f*)&Sy[si+10]=(v2f){2.f*(eya-oya), 2.f*(eyb-oyb)};
    } else if(ln<50){
      int gt=(ln-45)*2;
      float g0x=G[9].x;
      float Ea=0.f,Eb=0.f,Oa=0.f,Ob=0.f;
      #pragma unroll
      for(int n=1;n<10;++n){
        float2 gv=G[9+n];
        const float* er=(const float*)&TWE2[n*20+gt];
        float4 e01=*(const float4*)er;
        float ra=gv.x*e01.x-gv.y*e01.y;
        float rb=gv.x*e01.z-gv.y*e01.w;
        if((n&1)==0){ Ea+=ra; Eb+=rb; } else { Oa+=ra; Ob+=rb; }
      }
      T0f[gt]   =g0x+2.f*(Ea+Oa);
      T0f[gt+1] =g0x+2.f*(Eb+Ob);
      T0f[gt+10]=g0x+2.f*(Ea-Oa);
      T0f[gt+11]=g0x+2.f*(Eb-Ob);
    }
    WFENCE;
    // C: radix-2 split v(a,g)/v(a+10,g): 50 items (a=0..9 x 4-g), bias+relu
    if(ln<50){
      int a=ln/5, g0=(ln%5)*4;
      v2f i01={T0f[g0]+bb1, T0f[g0+1]+bb1};
      v2f i23={T0f[g0+2]+bb1, T0f[g0+3]+bb1};
      v2f P01={0.f,0.f},P23=P01,Q01=P01,Q23=P01;
      #pragma unroll
      for(int m=1;m<10;++m){
        float2 e=TWE2[a*20+m];
        v2f sx01=*(const v2f*)&Sx[(m-1)*20+g0];
        v2f sx23=*(const v2f*)&Sx[(m-1)*20+g0+2];
        v2f sy01=*(const v2f*)&Sy[(m-1)*20+g0];
        v2f sy23=*(const v2f*)&Sy[(m-1)*20+g0+2];
        if(m&1){
          Q01=PKFMA(bc2(e.x),sx01,Q01); Q01=PKFMA(bc2(-e.y),sy01,Q01);
          Q23=PKFMA(bc2(e.x),sx23,Q23); Q23=PKFMA(bc2(-e.y),sy23,Q23);
        } else {
          P01=PKFMA(bc2(e.x),sx01,P01); P01=PKFMA(bc2(-e.y),sy01,P01);
          P23=PKFMA(bc2(e.x),sx23,P23); P23=PKFMA(bc2(-e.y),sy23,P23);
        }
      }
      v2f z2={0.f,0.f};
      v2f vA01=i01+P01+Q01, vA23=i23+P23+Q23;
      v2f vB01=i01+P01-Q01, vB23=i23+P23-Q23;
      *(v2f*)&vbF[a*20+g0]       =__builtin_elementwise_max(vA01,z2);
      *(v2f*)&vbF[a*20+g0+2]     =__builtin_elementwise_max(vA23,z2);
      *(v2f*)&vbF[(a+10)*20+g0]  =__builtin_elementwise_max(vB01,z2);
      *(v2f*)&vbF[(a+10)*20+g0+2]=__builtin_elementwise_max(vB23,z2);
    }
    WFENCE;
    // D: U_T[nu][a]=sum_g v(a,g) e^{-i nu g}; 2-nu batch (60 items)
    if(ln<60){
      int a=ln/3, np=ln%3;
      int nu0=2*np, nu1=2*np+1;
      int r0=(np==0)?0:(20-2*np);
      int r1=19-2*np;
      const float* vp=&vbF[a*20];
      const float2* T0r=&TWE2[r0*20];
      const float2* T1r=&TWE2[r1*20];
      v2f u0={0.f,0.f}, u1=u0;
      #pragma unroll
      for(int g=0;g<20;++g){
        v2f xb=bc2(vp[g]);
        u0=PKFMA(xb, ldv(&T0r[g]), u0);
        u1=PKFMA(xb, ldv(&T1r[g]), u1);
      }
      *(v2f*)&U_T[nu0*20+a]=u0; *(v2f*)&U_T[nu1*20+a]=u1;
    }
    WFENCE;
    // E: Fq(mu,nu)=sum_a U_T[nu][a] e^{-i mu a}; dot trick (61 items)
    if(ln<61){
      int mu,nu;
      if(ln<6){ mu=ln; nu=0; } else { int q=ln-6; nu=q/11+1; mu=q%11-5; }
      int mm=(mu+20)%20;
      int rm=(20-mm)%20;
      const float2* Ur=&U_T[nu*20];
      const float2* Er=&TWE2[rm*20];
      v2f p1={0.f,0.f}, p2=p1;
      #pragma unroll
      for(int a=0;a<20;++a){
        v2f u=ldv(&Ur[a]), e=ldv(&Er[a]);
        p1=PKFMA(u,e,p1);
        p2=PKFMA(u,SW(e),p2);
      }
      Fq[ln]=make_float2(p1.x-p1.y, p2.x+p2.y);
    }
    WFENCE;
    // F: accumulate half-s2 with W3H into registers
    {
      const float* W3r=W3H + j*NH2;
      fa0=PKFMA(bc2(W3r[ln]),    ldv(&Fq[fhLUT[ln]]),    fa0);
      fa1=PKFMA(bc2(W3r[64+ln]), ldv(&Fq[fhLUT[64+ln]]), fa1);
      if(ln<18) fa2=PKFMA(bc2(W3r[128+ln]), ldv(&Fq[fhLUT[128+ln]]), fa2);
    }
    WFENCE;
  }
  // spill register accumulators, merge 4 waves, expand half->full by conjugation
  regB[w][ln]=make_float2(fa0.x,fa0.y);
  regB[w][64+ln]=make_float2(fa1.x,fa1.y);
  if(ln<18) regB[w][128+ln]=make_float2(fa2.x,fa2.y);
  __syncthreads();
  for(int h=t; h<146; h+=256){
    unsigned u=xh2LUT[h];
    int s2=u&1023, s2p=(u>>10)&1023;
    float sg=((u>>20)&1)? -1.f : 1.f;
    float2 a0=regB[0][h], a1=regB[1][h], a2=regB[2][h], a3=regB[3][h];
    float2 a=make_float2(a0.x+a1.x+a2.x+a3.x, a0.y+a1.y+a2.y+a3.y);
    XH2[(b*286+s2 )*F1+o]=a;
    XH2[(b*286+s2p)*F1+o]=make_float2(sg*a.x, -sg*a.y);
  }
}

// K2H: block per (i,o); KA row staged to LDS once; 146 h-threads consume.
__global__ __launch_bounds__(192) void k2h_k(const float2* __restrict__ KA,
                      const float* __restrict__ D3_2,
                      const unsigned* __restrict__ h2LUT, const unsigned* __restrict__ xh2LUT,
                      float2* __restrict__ K2H){
  __shared__ float2 kaS[192];
  __shared__ float2 E8s[8];
  int io=blockIdx.x, t=threadIdx.x;
  int i=io/F2, o=io%F2;
  if(t<8) E8s[t]=E8c[t];
  kaS[t]=KA[(size_t)io*192+t];
  __syncthreads();
  if(t>=146) return;
  unsigned hu=h2LUT[t];
  int l=hu&15, mi=(hu>>4)&15, ni=(hu>>8)&15, s2=hu>>12;
  int m=mi-l, n=ni-l;
  unsigned xu=xh2LUT[t];
  int s2p=(xu>>10)&1023;
  float sg=((xu>>20)&1)? -1.f : 1.f;
  int q=n&7, p=(m-n)&7;
  v2f a1={0.f,0.f}, a2=a1;
  for(int bi=0;bi<3;++bi){
    const float2* kp=&kaS[bi*64+q*8];
    v2f s1={0.f,0.f}, s2v=s1;
    int ph=0;
    #pragma unroll
    for(int ai=0;ai<8;++ai){
      v2f ka=ldv(&kp[ai]), e=ldv(&E8s[ph]);
      s1=PKFMA(ka,e,s1); s2v=PKFMA(ka,SW(e),s2v);
      ph=(ph+p)&7;
    }
    v2f dv=bc2(D3_2[bi*286+s2]);
    a1=PKFMA(dv,s1,a1); a2=PKFMA(dv,s2v,a2);
  }
  const float SC2f = 0.034722222222222224f;
  float re=(a1.x-a1.y)*SC2f, im=(a2.x+a2.y)*SC2f;
  K2H[((size_t)o*286+s2)*F1+i]=make_float2(re,im);
  K2H[((size_t)o*286+s2p)*F1+i]=make_float2(sg*re,-sg*im);
}

// fused2: cooperative z2 build, then wave-per-3j single-pass synthesis+integrate
__global__ __launch_bounds__(256,3) void fused2(
    const float2* __restrict__ XH2, const float2* __restrict__ K2H,
    const float* __restrict__ D2SJ, const float* __restrict__ WINT,
    const float2* __restrict__ E12, const float* __restrict__ bias2,
    const unsigned* __restrict__ h2LUT, const unsigned* __restrict__ xh2LUT,
    float* __restrict__ FEAT){
  const int b=blockIdx.x, o=blockIdx.y, t=threadIdx.x;
  const int ln=t&63, w=t>>6;
  __shared__ __align__(16) float2 Xs[2420];
  __shared__ __align__(16) float2 Ks[2420];
  __shared__ float2 zpS[1144];
  __shared__ float2 z2S[286];
  __shared__ float  redS[256];
  float2* alias=(float2*)Xs;       // reused after z-build
  float2* TWE12=alias;             // [12][12]: e^{i r c th12}

  const int gb[4]={0,84,165,286};
  const int hb[4]={0,44,85,146};
  for(int grp=0; grp<3; ++grp){
    int row0=gb[grp], rows=gb[grp+1]-row0;
    {
      int cnt4=rows*10;
      const float4* xsrc=(const float4*)(XH2+(size_t)(b*286+row0)*F1);
      const float4* ksrc=(const float4*)(K2H+(size_t)(o*286+row0)*F1);
      float4* xd=(float4*)Xs; float4* kd=(float4*)Ks;
      for(int i4=t;i4<cnt4;i4+=256){
        int wb=i4&~63;
        GLOAD_LDS16(xsrc+i4, xd+wb);
        GLOAD_LDS16(ksrc+i4, kd+wb);
      }
    }
    __syncthreads();
    int nh=hb[grp+1]-hb[grp];
    for(int idx=t; idx<4*nh; idx+=256){
      int hl=idx>>2, iq=idx&3;
      int h=hb[grp]+hl;
      unsigned hu=h2LUT[h];
      int l=hu&15, mi=(hu>>4)&15, ni=(hu>>8)&15, s2=hu>>12;
      int L=2*l+1;
      int xr0=(B2OFFc[l]-row0)+mi*L;
      int kr0=(B2OFFc[l]-row0)+ni*L;
      v2f p1={0.f,0.f}, p2=p1;
      for(int k=0;k<L;++k){
        const float2* xp=Xs+(xr0+k)*F1+iq*5;
        const float2* kp=Ks+(kr0+k)*F1+iq*5;
        #pragma unroll
        for(int i=0;i<5;++i){
          v2f xa=ldv(&xp[i]), kb=ldv(&kp[i]);
          p1=PKFMA(xa,kb,p1);
          p2=PKFMA(xa,SW(kb),p2);
        }
      }
      zpS[iq*286+s2]=make_float2(p1.x+p1.y, p2.y-p2.x);
    }
    __syncthreads();
  }
  for(int idx=t; idx<146; idx+=256){
    unsigned xu=xh2LUT[idx];
    int s2=xu&1023, s2p=(xu>>10)&1023;
    float sg=((xu>>20)&1)? -1.f : 1.f;
    float2 a;
    a.x=zpS[0*286+s2].x+zpS[1*286+s2].x+zpS[2*286+s2].x+zpS[3*286+s2].x;
    a.y=zpS[0*286+s2].y+zpS[1*286+s2].y+zpS[2*286+s2].y+zpS[3*286+s2].y;
    z2S[s2]=a;
    z2S[s2p]=make_float2(sg*a.x,-sg*a.y);
  }
  __syncthreads();
  for(int idx=t; idx<144; idx+=256){
    int r=idx/12, c=idx%12;
    TWE12[idx]=E12[(r*c)%12];
  }
  __syncthreads();

  float2* base2=alias+144+w*400;
  float2* G2_0=base2; float2* G2_1=base2+66; float2* G2_2=base2+132;
  float*  SP=(float*)(base2+198);
  float*  S2x0=SP, *S2x1=SP+60, *S2x2=SP+120;
  float*  S2y0=SP+180, *S2y1=SP+240, *S2y2=SP+300;
  float*  T02=SP+360;               // [3][12]
  float personal=0.f;
  const float b2v=bias2[o];
  const int j0=3*w, j1=3*w+1, j2=3*w+2;
  const float* Dg0=D2SJ + j0*286;
  const float* Dg1=D2SJ + j1*286;
  const float* Dg2=D2SJ + j2*286;
  const int BR12[11]={7,8,9,10,11,0,1,2,3,4,5};

  // A2: 61 half items, 3 j's
  if(ln<61){
    int m,n;
    if(ln<6){m=0;n=ln;} else {int qq=ln-6;m=qq/11+1;n=qq%11-5;}
    int an=n<0?-n:n; int l=m>an?m:an; int L=2*l+1;
    int zi=B2OFFc[l]+(m+l)*L+(n+l); int m2=2*m+2;
    v2f a0={0.f,0.f}, a1=a0, a2=a0;
    for(;l<6;++l){
      v2f zv=ldv(&z2S[zi]);
      a0=PKFMA(zv, bc2(Dg0[zi]), a0);
      a1=PKFMA(zv, bc2(Dg1[zi]), a1);
      a2=PKFMA(zv, bc2(Dg2[zi]), a2);
      zi+=L*L+2*L+m2; L+=2;
    }
    int gi=m*11+(n+5);
    *(v2f*)&G2_0[gi]=a0; *(v2f*)&G2_1[gi]=a1; *(v2f*)&G2_2[gi]=a2;
  }
  WFENCE;
  // B2: 42 items (30 S-pairs + 12 T0), 3 j's, dot trick
  if(ln<30){
    int m=ln/6+1, g=(ln%6)*2;
    v2f p10={0.f,0.f},p20=p10,p11=p10,p21=p10;
    v2f q10=p10,q20=p10,q11=p10,q21=p10;
    v2f r10=p10,r20=p10,r11=p10,r21=p10;
    #pragma unroll
    for(int c=0;c<11;++c){
      float4 eq=*(const float4*)&TWE12[BR12[c]*12+g];
      v2f e0={eq.x,eq.y}, e1={eq.z,eq.w};
      v2f g0=ldv(&G2_0[m*11+c]), g1=ldv(&G2_1[m*11+c]), g2=ldv(&G2_2[m*11+c]);
      p10=PKFMA(g0,e0,p10); p20=PKFMA(g0,SW(e0),p20);
      p11=PKFMA(g0,e1,p11); p21=PKFMA(g0,SW(e1),p21);
      q10=PKFMA(g1,e0,q10); q20=PKFMA(g1,SW(e0),q20);
      q11=PKFMA(g1,e1,q11); q21=PKFMA(g1,SW(e1),q21);
      r10=PKFMA(g2,e0,r10); r20=PKFMA(g2,SW(e0),r20);
      r11=PKFMA(g2,e1,r11); r21=PKFMA(g2,SW(e1),r21);
    }
    int si=(m-1)*12+g;
    S2x0[si]=2.f*(p10.x-p10.y); S2x0[si+1]=2.f*(p11.x-p11.y);
    S2y0[si]=2.f*(p20.x+p20.y); S2y0[si+1]=2.f*(p21.x+p21.y);
    S2x1[si]=2.f*(q10.x-q10.y); S2x1[si+1]=2.f*(q11.x-q11.y);
    S2y1[si]=2.f*(q20.x+q20.y); S2y1[si+1]=2.f*(q21.x+q21.y);
    S2x2[si]=2.f*(r10.x-r10.y); S2x2[si+1]=2.f*(r11.x-r11.y);
    S2y2[si]=2.f*(r20.x+r20.y); S2y2[si+1]=2.f*(r21.x+r21.y);
  } else if(ln<42){
    int g=ln-30;
    float r0=G2_0[5].x, r1=G2_1[5].x, r2=G2_2[5].x;
    #pragma unroll
    for(int n=1;n<6;++n){
      float2 e=TWE12[n*12+g];
      float2 g0=G2_0[5+n], g1=G2_1[5+n], g2=G2_2[5+n];
      r0+=2.f*(g0.x*e.x-g0.y*e.y);
      r1+=2.f*(g1.x*e.x-g1.y*e.y);
      r2+=2.f*(g2.x*e.x-g2.y*e.y);
    }
    T02[g]=r0; T02[12+g]=r1; T02[24+g]=r2;
  }
  WFENCE;
  // C2: 36 items, packed g-pairs, fused relu+integrate, 3 j's
  if(ln<36){
    float w0=WINT[j0], w1=WINT[j1], w2=WINT[j2];
    int a=ln/3, g4=(ln%3)*4;
    v2f iA0={T02[g4]+b2v, T02[g4+1]+b2v},       iB0={T02[g4+2]+b2v, T02[g4+3]+b2v};
    v2f iA1={T02[12+g4]+b2v, T02[12+g4+1]+b2v}, iB1={T02[12+g4+2]+b2v, T02[12+g4+3]+b2v};
    v2f iA2={T02[24+g4]+b2v, T02[24+g4+1]+b2v}, iB2={T02[24+g4+2]+b2v, T02[24+g4+3]+b2v};
    #pragma unroll
    for(int m=1;m<6;++m){
      float2 e=TWE12[a*12+m];
      v2f ex=bc2(e.x), eny=bc2(-e.y);
      int si=(m-1)*12+g4;
      v2f sx, sy;
      sx=*(const v2f*)&S2x0[si];   sy=*(const v2f*)&S2y0[si];
      iA0=PKFMA(ex,sx,iA0); iA0=PKFMA(eny,sy,iA0);
      sx=*(const v2f*)&S2x0[si+2]; sy=*(const v2f*)&S2y0[si+2];
      iB0=PKFMA(ex,sx,iB0); iB0=PKFMA(eny,sy,iB0);
      sx=*(const v2f*)&S2x1[si];   sy=*(const v2f*)&S2y1[si];
      iA1=PKFMA(ex,sx,iA1); iA1=PKFMA(eny,sy,iA1);
      sx=*(const v2f*)&S2x1[si+2]; sy=*(const v2f*)&S2y1[si+2];
      iB1=PKFMA(ex,sx,iB1); iB1=PKFMA(eny,sy,iB1);
      sx=*(const v2f*)&S2x2[si];   sy=*(const v2f*)&S2y2[si];
      iA2=PKFMA(ex,sx,iA2); iA2=PKFMA(eny,sy,iA2);
      sx=*(const v2f*)&S2x2[si+2]; sy=*(const v2f*)&S2y2[si+2];
      iB2=PKFMA(ex,sx,iB2); iB2=PKFMA(eny,sy,iB2);
    }
    v2f z2={0.f,0.f};
    v2f rA0=__builtin_elementwise_max(iA0,z2), rB0=__builtin_elementwise_max(iB0,z2);
    v2f rA1=__builtin_elementwise_max(iA1,z2), rB1=__builtin_elementwise_max(iB1,z2);
    v2f rA2=__builtin_elementwise_max(iA2,z2), rB2=__builtin_elementwise_max(iB2,z2);
    personal += w0*(rA0.x+rA0.y+rB0.x+rB0.y)
              + w1*(rA1.x+rA1.y+rB1.x+rB1.y)
              + w2*(rA2.x+rA2.y+rB2.x+rB2.y);
  }
  redS[t]=personal;
  __syncthreads();
  for(int s=128;s>0;s>>=1){
    if(t<s) redS[t]+=redS[t+s];
    __syncthreads();
  }
  if(t==0) FEAT[b*F2+o]=redS[0];
}

__global__ void head_k(const float* __restrict__ FEAT, const float* __restrict__ w_out,
                       const float* __restrict__ b_lin, float* __restrict__ out){
  int idx=blockIdx.x*blockDim.x+threadIdx.x;
  if(idx>=BATCH*FOUT) return;
  int b=idx/FOUT, q=idx%FOUT;
  float acc=b_lin[q];
  for(int f=0;f<F2;++f) acc += FEAT[b*F2+f]*w_out[q*F2+f];
  out[idx]=acc;
}

extern "C" void kernel_launch(void* const* d_in, const int* in_sizes, int n_in,
                              void* d_out, int out_size, void* d_ws, size_t ws_size,
                              hipStream_t stream) {
  const float* x    =(const float*)d_in[0];
  const float* k1   =(const float*)d_in[1];
  const float* bias1=(const float*)d_in[2];
  const float* k2   =(const float*)d_in[3];
  const float* bias2=(const float*)d_in[4];
  const float* w_out=(const float*)d_in[5];
  const float* b_lin=(const float*)d_in[6];
  float* out=(float*)d_out;

  char* ws=(char*)d_ws;
  float*  A1   =(float* )(ws+0);        //  6000 f
  float*  D1SJ =(float* )(ws+24000);    //  26600 f
  float*  W3H  =(float* )(ws+130400);   //  2920 f
  float*  D2SJ =(float* )(ws+142080);   //  3432 f
  float*  D3_2 =(float* )(ws+155808);   //  858 f (+pad)
  float*  D3_1 =(float* )(ws+159248);   //  300 f
  float*  WINT =(float* )(ws+160448);   //  12 f
  float2* E60  =(float2*)(ws+160496);   //  60 c
  float2* E20  =(float2*)(ws+160976);   //  20 c
  float2* E12  =(float2*)(ws+161136);   //  12 c (+pad)
  unsigned* zLUT=(unsigned*)(ws+161248);//  1330 u32 (+pad)
  unsigned* xh2LUT=(unsigned*)(ws+166576); // 146 u32
  unsigned* h2LUT =(unsigned*)(ws+167160); // 146 u32
  unsigned short* fhLUT=(unsigned short*)(ws+167744); // 146 u16 (+pad)
  unsigned* aLUT =(unsigned*)(ws+168048);  // 181 u32 (+pad)
  float2* XHAT =(float2*)(ws+168784);   //  [b][100] c
  float2* K1H  =(float2*)(ws+271184);   //  [o][100] c
  float2* KA   =(float2*)(ws+287184);   //  153600 c (1.2MB)
  float2* XH2  =(float2*)(ws+1515984);  //  [b][286][20] c
  float2* K2H  =(float2*)(ws+7373264);  //  [o][286][20] c
  float*  FEAT =(float* )(ws+9203664);  //  128*40 f -> 9224144 total

  (void)in_sizes; (void)n_in; (void)out_size; (void)ws_size;

  gen_all<<<104,256,0,stream>>>(A1,D1SJ,W3H,D2SJ,D3_2,D3_1,WINT,E60,E20,E12,
                                zLUT,xh2LUT,h2LUT,fhLUT,aLUT);
  front_k<<<736,256,0,stream>>>(x,k1,k2,E60,A1,D3_1,XHAT,K1H,KA);
  dim3 g1(BATCH,F1);
  fused1<<<g1,256,0,stream>>>(XHAT,K1H,D1SJ,W3H,E20,bias1,zLUT,xh2LUT,fhLUT,aLUT,XH2);
  k2h_k<<<F1*F2,192,0,stream>>>(KA,D3_2,h2LUT,xh2LUT,K2H);
  dim3 g2(BATCH,F2);
  fused2<<<g2,256,0,stream>>>(XH2,K2H,D2SJ,WINT,E12,bias2,h2LUT,xh2LUT,FEAT);
  head_k<<<(BATCH*FOUT+255)/256,256,0,stream>>>(FEAT,w_out,b_lin,out);
}

// Round 13
// 212.763 us; speedup vs baseline: 1.6869x; 1.0245x over previous
//
#include <hip/hip_runtime.h>
#include <math.h>

#define PI_D 3.14159265358979323846

#define BATCH 128
#define F1 20
#define F2 40
#define FOUT 10
#define NS1 100   // sum_{l<10} (2l+1)
#define NS2 286   // sum_{l<6} (2l+1)^2
#define NH2 146   // Hermitian half count of NS2

typedef float v2f __attribute__((ext_vector_type(2)));
#define PKFMA(a,b,c) __builtin_elementwise_fma((a),(b),(c))
#define SW(v) __builtin_shufflevector((v),(v),1,0)
static __device__ __forceinline__ v2f bc2(float s){ return (v2f){s,s}; }
static __device__ __forceinline__ v2f ldv(const float2* p){ return *(const v2f*)p; }

// async global->LDS, 16B per lane; lds arg must be wave-uniform base
#define GLOAD_LDS16(g,l) __builtin_amdgcn_global_load_lds( \
  (const __attribute__((address_space(1))) void*)(g), \
  (__attribute__((address_space(3))) void*)(l), 16, 0, 0)

__constant__ int ZB10c[11] = {0,1,10,35,84,165,286,455,680,969,1330};
__constant__ int B2OFFc[7] = {0,1,10,35,84,165,286};
__constant__ int HOFFc[7]  = {0,1,6,19,44,85,146};
// E8c[q] = exp(-2*pi*i*q/8)
__constant__ float2 E8c[8] = {
  { 1.f, 0.f}, { 0.70710678118654752f,-0.70710678118654752f},
  { 0.f,-1.f}, {-0.70710678118654752f,-0.70710678118654752f},
  {-1.f, 0.f}, {-0.70710678118654752f, 0.70710678118654752f},
  { 0.f, 1.f}, { 0.70710678118654752f, 0.70710678118654752f}};

// wave-synchronous phase fence
#define WFENCE do{ __builtin_amdgcn_sched_barrier(0); \
  asm volatile("s_waitcnt lgkmcnt(0)" ::: "memory"); \
  __builtin_amdgcn_sched_barrier(0); }while(0)

// half-space H = { (m,n): n>0 } U { (m,n): n==0 && m>=0 }
__device__ inline void h_decode(int h, int& l, int& m, int& n){
  l=0; while(HOFFc[l+1]<=h) ++l;
  int r=h-HOFFc[l], L=2*l+1;
  if(r<l+1){ n=0; m=r; }
  else { int q=r-(l+1); n=q/L+1; m=q%L-l; }
}

// ---------------- double-precision table generation helpers ----------------
__device__ inline double ipow_d(double x, int n){ double r=1.0; for(int i=0;i<n;++i) r*=x; return r; }
__device__ inline double dfact(int n){ double r=1.0; for(int i=2;i<=n;++i) r*=(double)i; return r; }

__device__ double wigd(int l, int mp, int m, double beta){
  double cb=cos(0.5*beta), sb=sin(0.5*beta);
  double pref=sqrt(dfact(l+mp)*dfact(l-mp)*dfact(l+m)*dfact(l-m));
  int s0 = (m-mp>0) ? (m-mp) : 0;
  int s1 = (l+m < l-mp) ? (l+m) : (l-mp);
  double acc=0.0;
  for(int s=s0;s<=s1;++s){
    double den=dfact(l+m-s)*dfact(s)*dfact(mp-m+s)*dfact(l-mp-s);
    double t=ipow_d(cb,2*l+m-mp-2*s)*ipow_d(sb,mp-m+2*s)/den;
    acc += ((mp-m+s)&1)? -t : t;
  }
  return pref*acc;
}

__device__ double dhw(int b, int j){
  double beta=PI_D*(2*j+1)/(4.0*b);
  double s=0.0;
  for(int k=0;k<b;++k) s += sin((2*k+1)*beta)/(2*k+1);
  return (2.0/b)*sin(beta)*s;
}

__device__ inline float2 cmulc(float2 a, float2 b){ // a * conj(b)
  return make_float2(a.x*b.x + a.y*b.y, a.y*b.x - a.x*b.y);
}

// ---------------- single merged table-generation kernel ----------------
// beta->pi-beta symmetry: d^l_{m',m}(pi-b) = (-1)^{l+m} d^l_{-m',m}(b)
// halves D1SJ/W3H/D2SJ work; dhw hoisted to per-block LDS table.
__global__ void gen_all(float* A1, float* D1SJ, float* W3H, float* D2SJ,
                        float* D3_2, float* D3_1, float* WINT,
                        float2* E60, float2* E20, float2* E12,
                        unsigned* zLUT, unsigned* xh2LUT, unsigned* h2LUT,
                        unsigned short* fhLUT, unsigned* aLUT){
  __shared__ double dhwS[60];
  int blk=blockIdx.x, t=threadIdx.x;
  if(blk<24){                     // A1: [j][s1], 60x100
    if(t<60) dhwS[t]=dhw(30,t);
    __syncthreads();
    int idx=blk*256+t;
    if(idx<6000){
      int j=idx/NS1, s=idx%NS1;
      int l=0; while((l+1)*(l+1)<=s) ++l;
      int m=s-l*l-l;
      double beta=PI_D*(2*j+1)/120.0;
      A1[idx]=(float)(wigd(l,m,0,beta)*dhwS[j]*(2.0*PI_D/60.0));
    }
  } else if(blk<76){              // D1SJ: j=0..9 computed, 19-j derived
    int idx=(blk-24)*256+t; if(idx>=13300) return;
    int j=idx/1330, s=idx%1330;
    int l=0; while(ZB10c[l+1]<=s) ++l;
    int r=s-ZB10c[l]; int L=2*l+1;
    int mi=r/L, ni=r%L;
    double beta=PI_D*(2*j+1)/40.0;
    float v=(float)((2*l+1)*wigd(l,mi-l,ni-l,beta));
    D1SJ[j*1330+s]=v;
    int s2=ZB10c[l]+(2*l-mi)*L+ni;
    D1SJ[(19-j)*1330+s2]=(ni&1)? -v : v;
  } else if(blk<82){              // W3H: j=0..9 computed, 19-j derived
    if(t<20) dhwS[t]=dhw(10,t);
    __syncthreads();
    int idx=(blk-76)*256+t;
    if(idx<10*NH2){
      int j=idx/NH2, h=idx%NH2;
      int l,m,n; h_decode(h,l,m,n);
      double beta=PI_D*(2*j+1)/40.0;
      double c=2.0*PI_D/20.0;
      float v=(float)(wigd(l,m,n,beta)*dhwS[j]*c*c);
      W3H[j*NH2+h]=v;
      if(n==0){
        W3H[(19-j)*NH2+h]=((l+m)&1)? -v : v;
      } else {
        int L=2*l+1;
        int hp=HOFFc[l]+(l+1)+(n-1)*L+(l-m);   // (m,n) -> (-m,n)
        W3H[(19-j)*NH2+hp]=((l+n)&1)? -v : v;
      }
    }
  } else if(blk<89){              // D2SJ: j=0..5 computed, 11-j derived
    int idx=(blk-82)*256+t; if(idx>=1716) return;
    int j=idx/286, s=idx%286;
    int l=0; while(B2OFFc[l+1]<=s) ++l;
    int r=s-B2OFFc[l]; int L=2*l+1;
    int mi=r/L, ni=r%L;
    double beta=PI_D*(2*j+1)/24.0;
    float v=(float)((2*l+1)*wigd(l,mi-l,ni-l,beta));
    D2SJ[j*286+s]=v;
    int s2=B2OFFc[l]+(2*l-mi)*L+ni;
    D2SJ[(11-j)*286+s2]=(ni&1)? -v : v;
  } else if(blk<93){              // D3_2: [bi][286]
    int idx=(blk-89)*256+t; if(idx>=3*286) return;
    int bi=idx/286, s=idx%286;
    int l=0; while(B2OFFc[l+1]<=s) ++l;
    int r=s-B2OFFc[l]; int L=2*l+1;
    int mi=r/L, ni=r%L;
    double beta=(bi+1)*(PI_D/8.0)/3.0;
    D3_2[idx]=(float)wigd(l,mi-l,ni-l,beta);
  } else if(blk<95){              // D3_1: [bi][100]
    int idx=(blk-93)*256+t; if(idx>=3*100) return;
    int bi=idx/100, s=idx%100;
    int l=0; while((l+1)*(l+1)<=s) ++l;
    int m=s-l*l-l;
    double beta=(bi+1)*(PI_D/8.0)/3.0;
    D3_1[idx]=(float)wigd(l,m,0,beta);
  } else if(blk==95){             // misc
    if(t<12){ double c=2.0*PI_D/12.0; WINT[t]=(float)(dhw(6,t)*c*c); }
    if(t<60){ double a=2.0*PI_D*t/60.0; E60[t]=make_float2((float)cos(a),(float)sin(a)); }
    if(t<20){ double a=2.0*PI_D*t/20.0; E20[t]=make_float2((float)cos(a),(float)sin(a)); }
    if(t<12){ double a=2.0*PI_D*t/12.0; E12[t]=make_float2((float)cos(a),(float)sin(a)); }
  } else if(blk<102){             // zLUT[1330]: packed s1x | s1k<<16
    int idx=(blk-96)*256+t; if(idx>=1330) return;
    int l=0; while(ZB10c[l+1]<=idx) ++l;
    int r=idx-ZB10c[l], L=2*l+1;
    int mi=r/L, ni=r%L;
    unsigned s1x=(unsigned)(l*l+mi), s1k=(unsigned)(l*l+ni);
    zLUT[idx]=s1x|(s1k<<16);
  } else if(blk==102){            // xh2LUT, h2LUT, fhLUT
    if(t<146){
      int l,m,n; h_decode(t,l,m,n);
      int L=2*l+1;
      int s2 =B2OFFc[l]+(m+l)*L+(n+l);
      int s2p=B2OFFc[l]+(l-m)*L+(l-n);
      unsigned sg=(unsigned)((m+n)&1);
      xh2LUT[t]=(unsigned)s2 | ((unsigned)s2p<<10) | (sg<<20);
      h2LUT[t]=(unsigned)l | ((unsigned)(m+l)<<4) | ((unsigned)(n+l)<<8) | ((unsigned)s2<<12);
      fhLUT[t]=(unsigned short)((n==0)? m : 6+(n-1)*11+(m+5));
    }
  } else {                        // blk==103: aLUT[181] sorted by lmin
    if(t==0){
      int idx=0;
      for(int lm=0;lm<10;++lm){
        for(int m=0;m<10;++m){
          int nlo=(m==0)?0:-9;
          for(int n=nlo;n<10;++n){
            int an=n<0?-n:n;
            int lmin=m>an?m:an;
            if(lmin!=lm) continue;
            int L=2*lm+1;
            int zi=ZB10c[lm]+(m+lm)*L+(n+lm);
            aLUT[idx++]=(unsigned)zi | ((unsigned)m<<11) | ((unsigned)(n+9)<<15) | ((unsigned)lm<<20);
          }
        }
      }
    }
  }
}

// ---------------- front: per-b DFT+S2 analysis | k1h | KA (k2 gamma-DFT) ----------------
__global__ __launch_bounds__(256) void front_k(const float* __restrict__ x,
    const float* __restrict__ k1, const float* __restrict__ k2,
    const float2* __restrict__ E60, const float* __restrict__ A1,
    const float* __restrict__ D3_1,
    float2* __restrict__ XHAT, float2* __restrict__ K1H, float2* __restrict__ KA){
  __shared__ float2 E8s[8];
  int blk=blockIdx.x, t=threadIdx.x;
  if(blk<128){
    __shared__ __align__(16) float xs[3600];
    __shared__ float2 E60s[60];      // conjugated twiddles
    __shared__ float2 XFs[1140];     // [j][mi], mi = m+9
    if(t<60){ float2 e=E60[t]; E60s[t]=make_float2(e.x,-e.y); }
    {
      const float4* src=(const float4*)(x+blk*3600);
      float4* dst=(float4*)xs;
      for(int i=t;i<900;i+=256) GLOAD_LDS16(src+i, dst+(i&~63));
    }
    __syncthreads();
    // radix-2: x(a)+/-x(a+30) with e^{-im(a+30)} = (-1)^m e^{-ima}
    for(int idx=t; idx<1140; idx+=256){
      int j=idx/19, mi=idx%19;
      int step=(mi<9)? mi+51 : mi-9;
      bool modd = ((mi&1)==0);       // parity(mi-9) = !parity(mi)
      const float* xr=xs+j*60;
      v2f acc={0.f,0.f};
      int k=0;
      for(int a=0;a<30;++a){
        float xv = modd ? (xr[a]-xr[a+30]) : (xr[a]+xr[a+30]);
        acc=PKFMA(bc2(xv), ldv(&E60s[k]), acc);
        k+=step; if(k>=60)k-=60;
      }
      XFs[idx]=make_float2(acc.x,acc.y);
    }
    __syncthreads();
    for(int s=t; s<100; s+=256){
      int l=0; while((l+1)*(l+1)<=s) ++l;
      int m=s-l*l-l;
      const float2* xf=&XFs[m+9];
      v2f acc={0.f,0.f};
      for(int j=0;j<60;++j){
        acc=PKFMA(bc2(A1[j*NS1+s]), ldv(&xf[j*19]), acc);
      }
      XHAT[blk*NS1+s]=make_float2(acc.x,acc.y);
    }
  } else if(blk<136){
    if(t<8) E8s[t]=E8c[t];
    __syncthreads();
    int idx=(blk-128)*256+t;
    if(idx<F1*NS1){
      int o=idx/NS1, s=idx%NS1;
      int l=0; while((l+1)*(l+1)<=s) ++l;
      int m=s-l*l-l;
      int mm=m&7;
      v2f acc={0.f,0.f};
      for(int bi=0;bi<3;++bi){
        v2f sum={0.f,0.f};
        int q=0;
        #pragma unroll
        for(int ai=0;ai<8;++ai){
          sum=PKFMA(bc2(k1[o*24+bi*8+ai]), ldv(&E8s[q]), sum);
          q=(q+mm)&7;
        }
        acc=PKFMA(bc2(D3_1[bi*100+s]), sum, acc);
      }
      const float SC1f = 0.06123724356957945f;
      K1H[idx]=make_float2(acc.x*SC1f, acc.y*SC1f);
    }
  } else {
    // KA[io*192 + bi*64 + q*8 + ai] = sum_gi k2[io*192+bi*64+ai*8+gi]*e8[(gi*q)&7]
    if(t<8) E8s[t]=E8c[t];
    __syncthreads();
    int idx=(blk-136)*256+t;
    if(idx<153600){
      int ai=idx&7, q=(idx>>3)&7;
      int r2=idx>>6;
      int bi=r2%3, io=r2/3;
      const float* kp=k2+(size_t)io*192+bi*64+ai*8;
      v2f acc={0.f,0.f};
      int ph=0;
      #pragma unroll
      for(int gi=0;gi<8;++gi){
        acc=PKFMA(bc2(kp[gi]), ldv(&E8s[ph]), acc);
        ph=(ph+q)&7;
      }
      KA[(size_t)io*192+bi*64+q*8+ai]=make_float2(acc.x,acc.y);
    }
  }
}

// fused1: 8-wave wave-per-j barrier-free pipeline, packed-fp32 + radix-2.
// XH2 layout: [b][s2][i]
__global__ __launch_bounds__(512,6) void fused1(
    const float2* __restrict__ XHAT, const float2* __restrict__ K1H,
    const float* __restrict__ D1SJ, const float* __restrict__ W3H,
    const float2* __restrict__ E20, const float* __restrict__ bias1,
    const unsigned* __restrict__ zLUT, const unsigned* __restrict__ xh2LUT,
    const unsigned short* __restrict__ fhLUT, const unsigned* __restrict__ aLUT,
    float2* __restrict__ XH2){
  const int b=blockIdx.x, o=blockIdx.y, t=threadIdx.x;
  const int ln=t&63, w=t>>6;
  __shared__ __align__(16) float2 zS[1330];
  __shared__ __align__(16) float2 TWE2[400];  // [r][k] = e^{i r k th}, 20x20
  __shared__ __align__(16) float2 regA[8][200];
  __shared__ __align__(16) float2 regB[8][190];

  for(int idx=t; idx<400; idx+=512){
    int r=idx/20, c=idx%20;
    TWE2[idx]=E20[(r*c)%20];
  }
  {
    float2* st=regA[0];   // xh rows staged: [0..99]=XHAT row, [100..199]=K1H row
    if(t<100) st[t]=XHAT[b*NS1+t];
    else if(t<200) st[t]=K1H[o*NS1+(t-100)];
  }
  __syncthreads();
  {
    const float2* st=regA[0];
    for(int idx=t; idx<1330; idx+=512){
      unsigned u=zLUT[idx];
      v2f xa=ldv(&st[u&0xffff]);
      v2f kb=ldv(&st[100+(u>>16)]);
      v2f p1=xa*kb, p2=xa*SW(kb);
      zS[idx]=make_float2(p1.x+p1.y, p2.y-p2.x);   // xa*conj(kb)
    }
  }
  __syncthreads();

  const float bb1=bias1[o];
  float2* G  = regA[w];
  float*  vbF= (float*)regA[w];
  float2* Fq = regA[w];
  float*  RB = (float*)regB[w];   // Sx[0..180) Sy[180..360) T0[360..380)
  float*  Sx = RB;
  float*  Sy = RB+180;
  float*  T0f= RB+360;
  float2* U_T= regB[w];           // reuse after C
  v2f fa0={0.f,0.f}, fa1=fa0, fa2=fa0;

  // B-phase twiddle rows: n=c-9 -> row (c+11)%20
  const int BROW[19]={11,12,13,14,15,16,17,18,19,0,1,2,3,4,5,6,7,8,9};

  for(int jq=0;jq<3;++jq){
    const int j=jq*8+w;
    const bool act=(j<20);
    const float* Dg=D1SJ + (act? j*1330 : 0);
    // A: Wigner-beta contraction, half-space (181 items, lmin-sorted LUT)
    if(act) for(int idx=ln; idx<181; idx+=64){
      unsigned au=aLUT[idx];
      int zi=au&2047;
      int m=(au>>11)&15, n9=(au>>15)&31, l=(au>>20)&15;
      int L=2*l+1;
      int m2=2*m+2;
      v2f a0={0.f,0.f};
      for(; l<10; ++l){
        a0=PKFMA(ldv(&zS[zi]), bc2(Dg[zi]), a0);
        zi += L*L + 2*L + m2; L += 2;
      }
      *(v2f*)&G[m*19+n9]=a0;
    }
    WFENCE;
    // B: radix-2 split S_m(g)/S_m(g+10): 45 items (mb x g-pair) + T0 (5 items)
    if(act){
    if(ln<45){
      int mb=ln/5+1, gp=(ln%5)*2;
      const float2* Gr=&G[mb*19];
      v2f E1a={0.f,0.f},E2a=E1a,O1a=E1a,O2a=E1a;
      v2f E1b=E1a,E2b=E1a,O1b=E1a,O2b=E1a;
      #pragma unroll
      for(int c=0;c<19;++c){
        v2f gv=ldv(&Gr[c]);
        const float* er=(const float*)&TWE2[BROW[c]*20+gp];
        float4 e01=*(const float4*)er;
        v2f e0={e01.x,e01.y}, e1={e01.z,e01.w};
        if(c&1){   // c odd -> n=c-9 even -> E
          E1a=PKFMA(gv,e0,E1a); E2a=PKFMA(gv,SW(e0),E2a);
          E1b=PKFMA(gv,e1,E1b); E2b=PKFMA(gv,SW(e1),E2b);
        } else {   // n odd -> O
          O1a=PKFMA(gv,e0,O1a); O2a=PKFMA(gv,SW(e0),O2a);
          O1b=PKFMA(gv,e1,O1b); O2b=PKFMA(gv,SW(e1),O2b);
        }
      }
      int si=(mb-1)*20+gp;
      float exa=E1a.x-E1a.y, oxa=O1a.x-O1a.y;
      float eya=E2a.x+E2a.y, oya=O2a.x+O2a.y;
      float exb=E1b.x-E1b.y, oxb=O1b.x-O1b.y;
      float eyb=E2b.x+E2b.y, oyb=O2b.x+O2b.y;
      *(v2f*)&Sx[si]   =(v2f){2.f*(exa+oxa), 2.f*(exb+oxb)};
      *(v2f*)&Sx[si+10]=(v2f){2.f*(exa-oxa), 2.f*(exb-oxb)};
      *(v2f*)&Sy[si]   =(v2f){2.f*(eya+oya), 2.f*(eyb+oyb)};
      *(v2f*)&Sy[si+10]=(v2f){2.f*(eya-oya), 2.f*(eyb-oyb)};
    } else if(ln<50){
      int gt=(ln-45)*2;
      float g0x=G[9].x;
      float Ea=0.f,Eb=0.f,Oa=0.f,Ob=0.f;
      #pragma unroll
      for(int n=1;n<10;++n){
        float2 gv=G[9+n];
        const float* er=(const float*)&TWE2[n*20+gt];
        float4 e01=*(const float4*)er;
        float ra=gv.x*e01.x-gv.y*e01.y;
        float rb=gv.x*e01.z-gv.y*e01.w;
        if((n&1)==0){ Ea+=ra; Eb+=rb; } else { Oa+=ra; Ob+=rb; }
      }
      T0f[gt]   =g0x+2.f*(Ea+Oa);
      T0f[gt+1] =g0x+2.f*(Eb+Ob);
      T0f[gt+10]=g0x+2.f*(Ea-Oa);
      T0f[gt+11]=g0x+2.f*(Eb-Ob);
    }
    }
    WFENCE;
    // C: radix-2 split v(a,g)/v(a+10,g): 50 items (a=0..9 x 4-g), bias+relu
    if(act && ln<50){
      int a=ln/5, g0=(ln%5)*4;
      v2f i01={T0f[g0]+bb1, T0f[g0+1]+bb1};
      v2f i23={T0f[g0+2]+bb1, T0f[g0+3]+bb1};
      v2f P01={0.f,0.f},P23=P01,Q01=P01,Q23=P01;
      #pragma unroll
      for(int m=1;m<10;++m){
        float2 e=TWE2[a*20+m];
        v2f sx01=*(const v2f*)&Sx[(m-1)*20+g0];
        v2f sx23=*(const v2f*)&Sx[(m-1)*20+g0+2];
        v2f sy01=*(const v2f*)&Sy[(m-1)*20+g0];
        v2f sy23=*(const v2f*)&Sy[(m-1)*20+g0+2];
        if(m&1){
          Q01=PKFMA(bc2(e.x),sx01,Q01); Q01=PKFMA(bc2(-e.y),sy01,Q01);
          Q23=PKFMA(bc2(e.x),sx23,Q23); Q23=PKFMA(bc2(-e.y),sy23,Q23);
        } else {
          P01=PKFMA(bc2(e.x),sx01,P01); P01=PKFMA(bc2(-e.y),sy01,P01);
          P23=PKFMA(bc2(e.x),sx23,P23); P23=PKFMA(bc2(-e.y),sy23,P23);
        }
      }
      v2f z2={0.f,0.f};
      v2f vA01=i01+P01+Q01, vA23=i23+P23+Q23;
      v2f vB01=i01+P01-Q01, vB23=i23+P23-Q23;
      *(v2f*)&vbF[a*20+g0]       =__builtin_elementwise_max(vA01,z2);
      *(v2f*)&vbF[a*20+g0+2]     =__builtin_elementwise_max(vA23,z2);
      *(v2f*)&vbF[(a+10)*20+g0]  =__builtin_elementwise_max(vB01,z2);
      *(v2f*)&vbF[(a+10)*20+g0+2]=__builtin_elementwise_max(vB23,z2);
    }
    WFENCE;
    // D: radix-2 input split U_T[nu][a]=sum_{g<10}(v(a,g)+/-v(a,g+10))e^{-i nu g}
    if(act && ln<60){
      int a=ln/3, np=ln%3;
      int nu0=2*np, nu1=2*np+1;
      int r0=(np==0)?0:(20-2*np);
      int r1=19-2*np;
      const float* vp=&vbF[a*20];
      const float2* T0r=&TWE2[r0*20];
      const float2* T1r=&TWE2[r1*20];
      v2f u0={0.f,0.f}, u1=u0;
      #pragma unroll
      for(int g=0;g<10;++g){
        float va=vp[g], vb=vp[g+10];
        u0=PKFMA(bc2(va+vb), ldv(&T0r[g]), u0);
        u1=PKFMA(bc2(va-vb), ldv(&T1r[g]), u1);
      }
      *(v2f*)&U_T[nu0*20+a]=u0; *(v2f*)&U_T[nu1*20+a]=u1;
    }
    WFENCE;
    // E: radix-2 input split Fq(mu,nu)=sum_{a<10}(U[a]+/-U[a+10])e^{-i mu a}
    if(act && ln<61){
      int mu,nu;
      if(ln<6){ mu=ln; nu=0; } else { int q=ln-6; nu=q/11+1; mu=q%11-5; }
      int mm=(mu+20)%20;
      int rm=(20-mm)%20;
      bool modd=(mm&1);
      const float2* Ur=&U_T[nu*20];
      const float2* Er=&TWE2[rm*20];
      v2f p1={0.f,0.f}, p2=p1;
      #pragma unroll
      for(int a=0;a<10;++a){
        v2f ua=ldv(&Ur[a]), ub=ldv(&Ur[a+10]);
        v2f u = modd ? (ua-ub) : (ua+ub);
        v2f e=ldv(&Er[a]);
        p1=PKFMA(u,e,p1);
        p2=PKFMA(u,SW(e),p2);
      }
      Fq[ln]=make_float2(p1.x-p1.y, p2.x+p2.y);
    }
    WFENCE;
    // F: accumulate half-s2 with W3H into registers
    if(act){
      const float* W3r=W3H + j*NH2;
      fa0=PKFMA(bc2(W3r[ln]),    ldv(&Fq[fhLUT[ln]]),    fa0);
      fa1=PKFMA(bc2(W3r[64+ln]), ldv(&Fq[fhLUT[64+ln]]), fa1);
      if(ln<18) fa2=PKFMA(bc2(W3r[128+ln]), ldv(&Fq[fhLUT[128+ln]]), fa2);
    }
    WFENCE;
  }
  // spill register accumulators, merge 8 waves, expand half->full by conjugation
  regB[w][ln]=make_float2(fa0.x,fa0.y);
  regB[w][64+ln]=make_float2(fa1.x,fa1.y);
  if(ln<18) regB[w][128+ln]=make_float2(fa2.x,fa2.y);
  __syncthreads();
  for(int h=t; h<146; h+=512){
    unsigned u=xh2LUT[h];
    int s2=u&1023, s2p=(u>>10)&1023;
    float sg=((u>>20)&1)? -1.f : 1.f;
    float2 a0=regB[0][h], a1=regB[1][h], a2=regB[2][h], a3=regB[3][h];
    float2 a4=regB[4][h], a5=regB[5][h], a6=regB[6][h], a7=regB[7][h];
    float2 a=make_float2(a0.x+a1.x+a2.x+a3.x+a4.x+a5.x+a6.x+a7.x,
                         a0.y+a1.y+a2.y+a3.y+a4.y+a5.y+a6.y+a7.y);
    XH2[(b*286+s2 )*F1+o]=a;
    XH2[(b*286+s2p)*F1+o]=make_float2(sg*a.x, -sg*a.y);
  }
}

// K2H: block per (i,o); KA row staged to LDS once; 146 h-threads consume.
__global__ __launch_bounds__(192) void k2h_k(const float2* __restrict__ KA,
                      const float* __restrict__ D3_2,
                      const unsigned* __restrict__ h2LUT, const unsigned* __restrict__ xh2LUT,
                      float2* __restrict__ K2H){
  __shared__ float2 kaS[192];
  __shared__ float2 E8s[8];
  int io=blockIdx.x, t=threadIdx.x;
  int i=io/F2, o=io%F2;
  if(t<8) E8s[t]=E8c[t];
  kaS[t]=KA[(size_t)io*192+t];
  __syncthreads();
  if(t>=146) return;
  unsigned hu=h2LUT[t];
  int l=hu&15, mi=(hu>>4)&15, ni=(hu>>8)&15, s2=hu>>12;
  int m=mi-l, n=ni-l;
  unsigned xu=xh2LUT[t];
  int s2p=(xu>>10)&1023;
  float sg=((xu>>20)&1)? -1.f : 1.f;
  int q=n&7, p=(m-n)&7;
  v2f a1={0.f,0.f}, a2=a1;
  for(int bi=0;bi<3;++bi){
    const float2* kp=&kaS[bi*64+q*8];
    v2f s1={0.f,0.f}, s2v=s1;
    int ph=0;
    #pragma unroll
    for(int ai=0;ai<8;++ai){
      v2f ka=ldv(&kp[ai]), e=ldv(&E8s[ph]);
      s1=PKFMA(ka,e,s1); s2v=PKFMA(ka,SW(e),s2v);
      ph=(ph+p)&7;
    }
    v2f dv=bc2(D3_2[bi*286+s2]);
    a1=PKFMA(dv,s1,a1); a2=PKFMA(dv,s2v,a2);
  }
  const float SC2f = 0.034722222222222224f;
  float re=(a1.x-a1.y)*SC2f, im=(a2.x+a2.y)*SC2f;
  K2H[((size_t)o*286+s2)*F1+i]=make_float2(re,im);
  K2H[((size_t)o*286+s2p)*F1+i]=make_float2(sg*re,-sg*im);
}

// fused2: cooperative z2 build, then wave-per-3j single-pass synthesis+integrate
__global__ __launch_bounds__(256,3) void fused2(
    const float2* __restrict__ XH2, const float2* __restrict__ K2H,
    const float* __restrict__ D2SJ, const float* __restrict__ WINT,
    const float2* __restrict__ E12, const float* __restrict__ bias2,
    const unsigned* __restrict__ h2LUT, const unsigned* __restrict__ xh2LUT,
    float* __restrict__ FEAT){
  const int b=blockIdx.x, o=blockIdx.y, t=threadIdx.x;
  const int ln=t&63, w=t>>6;
  __shared__ __align__(16) float2 Xs[2420];
  __shared__ __align__(16) float2 Ks[2420];
  __shared__ float2 zpS[1144];
  __shared__ float2 z2S[286];
  __shared__ float  redS[256];
  float2* alias=(float2*)Xs;       // reused after z-build
  float2* TWE12=alias;             // [12][12]: e^{i r c th12}

  const int gb[4]={0,84,165,286};
  const int hb[4]={0,44,85,146};
  for(int grp=0; grp<3; ++grp){
    int row0=gb[grp], rows=gb[grp+1]-row0;
    {
      int cnt4=rows*10;
      const float4* xsrc=(const float4*)(XH2+(size_t)(b*286+row0)*F1);
      const float4* ksrc=(const float4*)(K2H+(size_t)(o*286+row0)*F1);
      float4* xd=(float4*)Xs; float4* kd=(float4*)Ks;
      for(int i4=t;i4<cnt4;i4+=256){
        int wb=i4&~63;
        GLOAD_LDS16(xsrc+i4, xd+wb);
        GLOAD_LDS16(ksrc+i4, kd+wb);
      }
    }
    __syncthreads();
    int nh=hb[grp+1]-hb[grp];
    for(int idx=t; idx<4*nh; idx+=256){
      int hl=idx>>2, iq=idx&3;
      int h=hb[grp]+hl;
      unsigned hu=h2LUT[h];
      int l=hu&15, mi=(hu>>4)&15, ni=(hu>>8)&15, s2=hu>>12;
      int L=2*l+1;
      int xr0=(B2OFFc[l]-row0)+mi*L;
      int kr0=(B2OFFc[l]-row0)+ni*L;
      v2f p1={0.f,0.f}, p2=p1;
      for(int k=0;k<L;++k){
        const float2* xp=Xs+(xr0+k)*F1+iq*5;
        const float2* kp=Ks+(kr0+k)*F1+iq*5;
        #pragma unroll
        for(int i=0;i<5;++i){
          v2f xa=ldv(&xp[i]), kb=ldv(&kp[i]);
          p1=PKFMA(xa,kb,p1);
          p2=PKFMA(xa,SW(kb),p2);
        }
      }
      zpS[iq*286+s2]=make_float2(p1.x+p1.y, p2.y-p2.x);
    }
    __syncthreads();
  }
  for(int idx=t; idx<146; idx+=256){
    unsigned xu=xh2LUT[idx];
    int s2=xu&1023, s2p=(xu>>10)&1023;
    float sg=((xu>>20)&1)? -1.f : 1.f;
    float2 a;
    a.x=zpS[0*286+s2].x+zpS[1*286+s2].x+zpS[2*286+s2].x+zpS[3*286+s2].x;
    a.y=zpS[0*286+s2].y+zpS[1*286+s2].y+zpS[2*286+s2].y+zpS[3*286+s2].y;
    z2S[s2]=a;
    z2S[s2p]=make_float2(sg*a.x,-sg*a.y);
  }
  __syncthreads();
  for(int idx=t; idx<144; idx+=256){
    int r=idx/12, c=idx%12;
    TWE12[idx]=E12[(r*c)%12];
  }
  __syncthreads();

  float2* base2=alias+144+w*400;
  float2* G2_0=base2; float2* G2_1=base2+66; float2* G2_2=base2+132;
  float*  SP=(float*)(base2+198);
  float*  S2x0=SP, *S2x1=SP+60, *S2x2=SP+120;
  float*  S2y0=SP+180, *S2y1=SP+240, *S2y2=SP+300;
  float*  T02=SP+360;               // [3][12]
  float personal=0.f;
  const float b2v=bias2[o];
  const int j0=3*w, j1=3*w+1, j2=3*w+2;
  const float* Dg0=D2SJ + j0*286;
  const float* Dg1=D2SJ + j1*286;
  const float* Dg2=D2SJ + j2*286;
  const int BR12[11]={7,8,9,10,11,0,1,2,3,4,5};

  // A2: 61 half items, 3 j's
  if(ln<61){
    int m,n;
    if(ln<6){m=0;n=ln;} else {int qq=ln-6;m=qq/11+1;n=qq%11-5;}
    int an=n<0?-n:n; int l=m>an?m:an; int L=2*l+1;
    int zi=B2OFFc[l]+(m+l)*L+(n+l); int m2=2*m+2;
    v2f a0={0.f,0.f}, a1=a0, a2=a0;
    for(;l<6;++l){
      v2f zv=ldv(&z2S[zi]);
      a0=PKFMA(zv, bc2(Dg0[zi]), a0);
      a1=PKFMA(zv, bc2(Dg1[zi]), a1);
      a2=PKFMA(zv, bc2(Dg2[zi]), a2);
      zi+=L*L+2*L+m2; L+=2;
    }
    int gi=m*11+(n+5);
    *(v2f*)&G2_0[gi]=a0; *(v2f*)&G2_1[gi]=a1; *(v2f*)&G2_2[gi]=a2;
  }
  WFENCE;
  // B2: 42 items (30 S-pairs + 12 T0), 3 j's, dot trick
  if(ln<30){
    int m=ln/6+1, g=(ln%6)*2;
    v2f p10={0.f,0.f},p20=p10,p11=p10,p21=p10;
    v2f q10=p10,q20=p10,q11=p10,q21=p10;
    v2f r10=p10,r20=p10,r11=p10,r21=p10;
    #pragma unroll
    for(int c=0;c<11;++c){
      float4 eq=*(const float4*)&TWE12[BR12[c]*12+g];
      v2f e0={eq.x,eq.y}, e1={eq.z,eq.w};
      v2f g0=ldv(&G2_0[m*11+c]), g1=ldv(&G2_1[m*11+c]), g2=ldv(&G2_2[m*11+c]);
      p10=PKFMA(g0,e0,p10); p20=PKFMA(g0,SW(e0),p20);
      p11=PKFMA(g0,e1,p11); p21=PKFMA(g0,SW(e1),p21);
      q10=PKFMA(g1,e0,q10); q20=PKFMA(g1,SW(e0),q20);
      q11=PKFMA(g1,e1,q11); q21=PKFMA(g1,SW(e1),q21);
      r10=PKFMA(g2,e0,r10); r20=PKFMA(g2,SW(e0),r20);
      r11=PKFMA(g2,e1,r11); r21=PKFMA(g2,SW(e1),r21);
    }
    int si=(m-1)*12+g;
    S2x0[si]=2.f*(p10.x-p10.y); S2x0[si+1]=2.f*(p11.x-p11.y);
    S2y0[si]=2.f*(p20.x+p20.y); S2y0[si+1]=2.f*(p21.x+p21.y);
    S2x1[si]=2.f*(q10.x-q10.y); S2x1[si+1]=2.f*(q11.x-q11.y);
    S2y1[si]=2.f*(q20.x+q20.y); S2y1[si+1]=2.f*(q21.x+q21.y);
    S2x2[si]=2.f*(r10.x-r10.y); S2x2[si+1]=2.f*(r11.x-r11.y);
    S2y2[si]=2.f*(r20.x+r20.y); S2y2[si+1]=2.f*(r21.x+r21.y);
  } else if(ln<42){
    int g=ln-30;
    float r0=G2_0[5].x, r1=G2_1[5].x, r2=G2_2[5].x;
    #pragma unroll
    for(int n=1;n<6;++n){
      float2 e=TWE12[n*12+g];
      float2 g0=G2_0[5+n], g1=G2_1[5+n], g2=G2_2[5+n];
      r0+=2.f*(g0.x*e.x-g0.y*e.y);
      r1+=2.f*(g1.x*e.x-g1.y*e.y);
      r2+=2.f*(g2.x*e.x-g2.y*e.y);
    }
    T02[g]=r0; T02[12+g]=r1; T02[24+g]=r2;
  }
  WFENCE;
  // C2: 36 items, packed g-pairs, fused relu+integrate, 3 j's
  if(ln<36){
    float w0=WINT[j0], w1=WINT[j1], w2=WINT[j2];
    int a=ln/3, g4=(ln%3)*4;
    v2f iA0={T02[g4]+b2v, T02[g4+1]+b2v},       iB0={T02[g4+2]+b2v, T02[g4+3]+b2v};
    v2f iA1={T02[12+g4]+b2v, T02[12+g4+1]+b2v}, iB1={T02[12+g4+2]+b2v, T02[12+g4+3]+b2v};
    v2f iA2={T02[24+g4]+b2v, T02[24+g4+1]+b2v}, iB2={T02[24+g4+2]+b2v, T02[24+g4+3]+b2v};
    #pragma unroll
    for(int m=1;m<6;++m){
      float2 e=TWE12[a*12+m];
      v2f ex=bc2(e.x), eny=bc2(-e.y);
      int si=(m-1)*12+g4;
      v2f sx, sy;
      sx=*(const v2f*)&S2x0[si];   sy=*(const v2f*)&S2y0[si];
      iA0=PKFMA(ex,sx,iA0); iA0=PKFMA(eny,sy,iA0);
      sx=*(const v2f*)&S2x0[si+2]; sy=*(const v2f*)&S2y0[si+2];
      iB0=PKFMA(ex,sx,iB0); iB0=PKFMA(eny,sy,iB0);
      sx=*(const v2f*)&S2x1[si];   sy=*(const v2f*)&S2y1[si];
      iA1=PKFMA(ex,sx,iA1); iA1=PKFMA(eny,sy,iA1);
      sx=*(const v2f*)&S2x1[si+2]; sy=*(const v2f*)&S2y1[si+2];
      iB1=PKFMA(ex,sx,iB1); iB1=PKFMA(eny,sy,iB1);
      sx=*(const v2f*)&S2x2[si];   sy=*(const v2f*)&S2y2[si];
      iA2=PKFMA(ex,sx,iA2); iA2=PKFMA(eny,sy,iA2);
      sx=*(const v2f*)&S2x2[si+2]; sy=*(const v2f*)&S2y2[si+2];
      iB2=PKFMA(ex,sx,iB2); iB2=PKFMA(eny,sy,iB2);
    }
    v2f z2={0.f,0.f};
    v2f rA0=__builtin_elementwise_max(iA0,z2), rB0=__builtin_elementwise_max(iB0,z2);
    v2f rA1=__builtin_elementwise_max(iA1,z2), rB1=__builtin_elementwise_max(iB1,z2);
    v2f rA2=__builtin_elementwise_max(iA2,z2), rB2=__builtin_elementwise_max(iB2,z2);
    personal += w0*(rA0.x+rA0.y+rB0.x+rB0.y)
              + w1*(rA1.x+rA1.y+rB1.x+rB1.y)
              + w2*(rA2.x+rA2.y+rB2.x+rB2.y);
  }
  redS[t]=personal;
  __syncthreads();
  for(int s=128;s>0;s>>=1){
    if(t<s) redS[t]+=redS[t+s];
    __syncthreads();
  }
  if(t==0) FEAT[b*F2+o]=redS[0];
}

__global__ void head_k(const float* __restrict__ FEAT, const float* __restrict__ w_out,
                       const float* __restrict__ b_lin, float* __restrict__ out){
  int idx=blockIdx.x*blockDim.x+threadIdx.x;
  if(idx>=BATCH*FOUT) return;
  int b=idx/FOUT, q=idx%FOUT;
  float acc=b_lin[q];
  for(int f=0;f<F2;++f) acc += FEAT[b*F2+f]*w_out[q*F2+f];
  out[idx]=acc;
}

extern "C" void kernel_launch(void* const* d_in, const int* in_sizes, int n_in,
                              void* d_out, int out_size, void* d_ws, size_t ws_size,
                              hipStream_t stream) {
  const float* x    =(const float*)d_in[0];
  const float* k1   =(const float*)d_in[1];
  const float* bias1=(const float*)d_in[2];
  const float* k2   =(const float*)d_in[3];
  const float* bias2=(const float*)d_in[4];
  const float* w_out=(const float*)d_in[5];
  const float* b_lin=(const float*)d_in[6];
  float* out=(float*)d_out;

  char* ws=(char*)d_ws;
  float*  A1   =(float* )(ws+0);        //  6000 f
  float*  D1SJ =(float* )(ws+24000);    //  26600 f
  float*  W3H  =(float* )(ws+130400);   //  2920 f
  float*  D2SJ =(float* )(ws+142080);   //  3432 f
  float*  D3_2 =(float* )(ws+155808);   //  858 f (+pad)
  float*  D3_1 =(float* )(ws+159248);   //  300 f
  float*  WINT =(float* )(ws+160448);   //  12 f
  float2* E60  =(float2*)(ws+160496);   //  60 c
  float2* E20  =(float2*)(ws+160976);   //  20 c
  float2* E12  =(float2*)(ws+161136);   //  12 c (+pad)
  unsigned* zLUT=(unsigned*)(ws+161248);//  1330 u32 (+pad)
  unsigned* xh2LUT=(unsigned*)(ws+166576); // 146 u32
  unsigned* h2LUT =(unsigned*)(ws+167160); // 146 u32
  unsigned short* fhLUT=(unsigned short*)(ws+167744); // 146 u16 (+pad)
  unsigned* aLUT =(unsigned*)(ws+168048);  // 181 u32 (+pad)
  float2* XHAT =(float2*)(ws+168784);   //  [b][100] c
  float2* K1H  =(float2*)(ws+271184);   //  [o][100] c
  float2* KA   =(float2*)(ws+287184);   //  153600 c (1.2MB)
  float2* XH2  =(float2*)(ws+1515984);  //  [b][286][20] c
  float2* K2H  =(float2*)(ws+7373264);  //  [o][286][20] c
  float*  FEAT =(float* )(ws+9203664);  //  128*40 f -> 9224144 total

  (void)in_sizes; (void)n_in; (void)out_size; (void)ws_size;

  gen_all<<<104,256,0,stream>>>(A1,D1SJ,W3H,D2SJ,D3_2,D3_1,WINT,E60,E20,E12,
                                zLUT,xh2LUT,h2LUT,fhLUT,aLUT);
  front_k<<<736,256,0,stream>>>(x,k1,k2,E60,A1,D3_1,XHAT,K1H,KA);
  dim3 g1(BATCH,F1);
  fused1<<<g1,512,0,stream>>>(XHAT,K1H,D1SJ,W3H,E20,bias1,zLUT,xh2LUT,fhLUT,aLUT,XH2);
  k2h_k<<<F1*F2,192,0,stream>>>(KA,D3_2,h2LUT,xh2LUT,K2H);
  dim3 g2(BATCH,F2);
  fused2<<<g2,256,0,stream>>>(XH2,K2H,D2SJ,WINT,E12,bias2,h2LUT,xh2LUT,FEAT);
  head_k<<<(BATCH*FOUT+255)/256,256,0,stream>>>(FEAT,w_out,b_lin,out);
}